// Round 9
// baseline (272.374 us; speedup 1.0000x reference)
//
#include <hip/hip_runtime.h>

// TransformerLayer_Combined on gfx950 — bf16 MFMA, swapped-operand epilogues,
// 2-phase prefetch double-buffered staging via global_load_lds.
// S=1024,B=4,H=1024,NH=16,HPH=64,NF=4,DIN=256,DHID=2048. Outputs fp32.

typedef __attribute__((ext_vector_type(8))) short short8;
typedef __attribute__((ext_vector_type(4))) float f32x4;

__device__ __forceinline__ unsigned short f2bf(float f) {
  union { float f; unsigned u; } x; x.f = f;
  unsigned r = x.u + 0x7FFFu + ((x.u >> 16) & 1u);
  return (unsigned short)(r >> 16);
}
__device__ __forceinline__ float bf2f(unsigned short u) {
  union { float f; unsigned u; } x; x.u = ((unsigned)u) << 16;
  return x.f;
}
__device__ __forceinline__ unsigned cvtpk(float a, float b) {  // [lo=a, hi=b]
  unsigned r;
  asm("v_cvt_pk_bf16_f32 %0, %1, %2" : "=v"(r) : "v"(a), "v"(b));
  return r;
}
// async 16B global->LDS (dest = wave-uniform base + lane*16)
__device__ __forceinline__ void gload16(const unsigned short* g, unsigned short* l) {
  __builtin_amdgcn_global_load_lds(
      (const __attribute__((address_space(1))) unsigned int*)g,
      (__attribute__((address_space(3))) unsigned int*)l, 16, 0, 0);
}

// ---------------- LN1 over H=1024: fp32 (residual) + bf16 (GEMM A) --------
__global__ __launch_bounds__(256) void ln1_kernel(
    const float* __restrict__ x, const float* __restrict__ g,
    const float* __restrict__ b, float* __restrict__ y,
    unsigned short* __restrict__ ybf)
{
  const long base = (long)blockIdx.x * 1024;
  const int c = threadIdx.x * 4;
  float4 v = *(const float4*)(x + base + c);
  float s = v.x + v.y + v.z + v.w;
  float ss = v.x*v.x + v.y*v.y + v.z*v.z + v.w*v.w;
  #pragma unroll
  for (int off = 32; off > 0; off >>= 1) {
    s  += __shfl_xor(s, off);
    ss += __shfl_xor(ss, off);
  }
  __shared__ float sw[4], ssw[4];
  const int wave = threadIdx.x >> 6;
  if ((threadIdx.x & 63) == 0) { sw[wave] = s; ssw[wave] = ss; }
  __syncthreads();
  s  = sw[0] + sw[1] + sw[2] + sw[3];
  ss = ssw[0] + ssw[1] + ssw[2] + ssw[3];
  const float mean = s * (1.0f/1024.0f);
  const float var  = ss * (1.0f/1024.0f) - mean*mean;
  const float rs   = rsqrtf(var + 1e-6f);
  const float4 gv = *(const float4*)(g + c);
  const float4 bv = *(const float4*)(b + c);
  float4 o;
  o.x = (v.x - mean) * rs * gv.x + bv.x;
  o.y = (v.y - mean) * rs * gv.y + bv.y;
  o.z = (v.z - mean) * rs * gv.z + bv.z;
  o.w = (v.w - mean) * rs * gv.w + bv.w;
  *(float4*)(y + base + c) = o;
  ushort4 ob;
  ob.x = f2bf(o.x); ob.y = f2bf(o.y); ob.z = f2bf(o.z); ob.w = f2bf(o.w);
  *(ushort4*)(ybf + base + c) = ob;
}

// -------- weight transpose+convert: W [K][N] fp32 -> WT [N][K] bf16 --------
__global__ __launch_bounds__(256) void transpose_w_kernel(
    const float* __restrict__ W, int K, int N, long wgs,
    unsigned short* __restrict__ WT, long wtgs)
{
  __shared__ float T[32][33];
  const float* Wg = W + (long)blockIdx.z * wgs;
  unsigned short* WTg = WT + (long)blockIdx.z * wtgs;
  const int n0 = blockIdx.x * 32, k0 = blockIdx.y * 32;
  const int t = threadIdx.x;
  const int r = t >> 3, c4 = (t & 7) * 4;
  float4 v = *(const float4*)(Wg + (long)(k0 + r) * N + n0 + c4);
  T[r][c4+0] = v.x; T[r][c4+1] = v.y; T[r][c4+2] = v.z; T[r][c4+3] = v.w;
  __syncthreads();
  ushort4 o;
  o.x = f2bf(T[c4+0][r]); o.y = f2bf(T[c4+1][r]);
  o.z = f2bf(T[c4+2][r]); o.w = f2bf(T[c4+3][r]);
  *(ushort4*)(WTg + (long)(n0 + r) * K + k0 + c4) = o;
}

// merged 1024x1024 transposes: z=0..2 -> wqkvT, z=3 -> wdT
__global__ __launch_bounds__(256) void transpose_qkvd_kernel(
    const float* __restrict__ Wq, const float* __restrict__ Wk,
    const float* __restrict__ Wv, const float* __restrict__ Wd,
    unsigned short* __restrict__ wqkvT, unsigned short* __restrict__ wdT)
{
  const int z = blockIdx.z;
  const float* W = (z == 0) ? Wq : (z == 1) ? Wk : (z == 2) ? Wv : Wd;
  unsigned short* WT = (z == 3) ? wdT : wqkvT + (long)z * 1048576;
  __shared__ float T[32][33];
  const int n0 = blockIdx.x * 32, k0 = blockIdx.y * 32;
  const int t = threadIdx.x;
  const int r = t >> 3, c4 = (t & 7) * 4;
  float4 v = *(const float4*)(W + (long)(k0 + r) * 1024 + n0 + c4);
  T[r][c4+0] = v.x; T[r][c4+1] = v.y; T[r][c4+2] = v.z; T[r][c4+3] = v.w;
  __syncthreads();
  ushort4 o;
  o.x = f2bf(T[c4+0][r]); o.y = f2bf(T[c4+1][r]);
  o.z = f2bf(T[c4+2][r]); o.w = f2bf(T[c4+3][r]);
  *(ushort4*)(WT + (long)(n0 + r) * 1024 + k0 + c4) = o;
}

__global__ __launch_bounds__(256) void packb_kernel(
    const float* __restrict__ bq, const float* __restrict__ bk,
    const float* __restrict__ bv, float* __restrict__ qb)
{
  const int i = blockIdx.x * 256 + threadIdx.x;   // 3072
  qb[i] = (i < 1024) ? bq[i] : ((i < 2048) ? bk[i - 1024] : bv[i - 2048]);
}

// ---- bf16 MFMA GEMM, 128x128 tile, dbuf prefetch, swapped epilogue ------
__global__ __launch_bounds__(256) void mfma_gemm_kernel(
    const unsigned short* __restrict__ A, int lda, long agoff,
    const unsigned short* __restrict__ BT, long bgoff, int K,
    const float* __restrict__ bias, int biasoff,
    unsigned short* __restrict__ Cbf, float* __restrict__ Cf,
    int ldc, int cgoff)
{
  const int g = blockIdx.z;
  const unsigned short* Ag = A + (long)g * agoff;
  const unsigned short* Bg = BT + (long)g * bgoff;
  const float* biasg = bias + (long)g * biasoff;
  const int row0 = blockIdx.y * 128, col0 = blockIdx.x * 128;
  __shared__ __align__(16) unsigned short As[2][128 * 32];
  __shared__ __align__(16) unsigned short Bs[2][128 * 32];
  const int tid = threadIdx.x;
  const int w = tid >> 6, l = tid & 63;
  const int ms = (w & 1) << 6, ns = (w >> 1) << 6;
  const int fr = l & 15, fg = l >> 4;
  const int lr = l >> 2;
  const int sslot = (((l & 3) ^ (lr & 3)) << 3);
  const int arow = row0 + (w << 4) + lr;
  const int brow = col0 + (w << 4) + lr;
  const int rsw = fr & 3;
  f32x4 acc[4][4];
  #pragma unroll
  for (int i = 0; i < 4; ++i)
    #pragma unroll
    for (int j = 0; j < 4; ++j) acc[i][j] = (f32x4)0.0f;

  const int nt = K >> 5;
  gload16(Ag + (long)arow * lda + sslot,        &As[0][(w << 4) * 32]);
  gload16(Ag + (long)(arow + 64) * lda + sslot, &As[0][(64 + (w << 4)) * 32]);
  gload16(Bg + (long)brow * K + sslot,          &Bs[0][(w << 4) * 32]);
  gload16(Bg + (long)(brow + 64) * K + sslot,   &Bs[0][(64 + (w << 4)) * 32]);
  __syncthreads();
  int cur = 0;
  for (int t = 0; t < nt; ++t) {
    if (t + 1 < nt) {
      const int k0 = (t + 1) << 5;
      gload16(Ag + (long)arow * lda + k0 + sslot,        &As[cur ^ 1][(w << 4) * 32]);
      gload16(Ag + (long)(arow + 64) * lda + k0 + sslot, &As[cur ^ 1][(64 + (w << 4)) * 32]);
      gload16(Bg + (long)brow * K + k0 + sslot,          &Bs[cur ^ 1][(w << 4) * 32]);
      gload16(Bg + (long)(brow + 64) * K + k0 + sslot,   &Bs[cur ^ 1][(64 + (w << 4)) * 32]);
    }
    short8 af[4], bfr[4];
    #pragma unroll
    for (int i = 0; i < 4; ++i)
      af[i] = *(const short8*)&As[cur][(ms + i*16 + fr) * 32 + ((fg ^ rsw) << 3)];
    #pragma unroll
    for (int j = 0; j < 4; ++j)
      bfr[j] = *(const short8*)&Bs[cur][(ns + j*16 + fr) * 32 + ((fg ^ rsw) << 3)];
    #pragma unroll
    for (int i = 0; i < 4; ++i)
      #pragma unroll
      for (int j = 0; j < 4; ++j)   // swapped: D[n][m]
        acc[i][j] = __builtin_amdgcn_mfma_f32_16x16x32_bf16(bfr[j], af[i], acc[i][j], 0, 0, 0);
    __syncthreads();
    cur ^= 1;
  }

  // epilogue: per lane n = ns+16j+4fg+r4 (consecutive), m = ms+16i+fr
  #pragma unroll
  for (int j = 0; j < 4; ++j) {
    const float4 bj4 = *(const float4*)(biasg + col0 + ns + j*16 + (fg << 2));
    #pragma unroll
    for (int i = 0; i < 4; ++i) {
      const long row = row0 + ms + i*16 + fr;
      const long cb = row * ldc + (long)g * cgoff + col0 + ns + j*16 + (fg << 2);
      const float v0 = acc[i][j][0] + bj4.x, v1 = acc[i][j][1] + bj4.y;
      const float v2 = acc[i][j][2] + bj4.z, v3 = acc[i][j][3] + bj4.w;
      if (Cbf) {
        uint2 pk; pk.x = cvtpk(v0, v1); pk.y = cvtpk(v2, v3);
        *(uint2*)(Cbf + cb) = pk;
      } else {
        f32x4 o = {v0, v1, v2, v3};
        __builtin_nontemporal_store(o, (f32x4*)(Cf + cb));
      }
    }
  }
}

// ---- grouped dense_in + GLU, 128x64 tile, dbuf prefetch, swapped --------
__global__ __launch_bounds__(256) void mfma_glu_kernel(
    const unsigned short* __restrict__ A,   // ctx2 [4096][1024]
    const unsigned short* __restrict__ WT,  // [g][2048][256]
    const float* __restrict__ bin,          // [4][2048]
    unsigned short* __restrict__ H2)        // [4096][4096]
{
  const int g = blockIdx.z;
  const unsigned short* Ag = A + g * 256;
  const unsigned short* Wg = WT + (long)g * 2048 * 256;
  const float* bg = bin + g * 2048;
  const int row0 = blockIdx.y * 128, col0 = blockIdx.x * 64;
  __shared__ __align__(16) unsigned short As[2][128 * 32];
  __shared__ __align__(16) unsigned short Bxs[2][64 * 32];
  __shared__ __align__(16) unsigned short Bys[2][64 * 32];
  const int tid = threadIdx.x;
  const int w = tid >> 6, l = tid & 63;
  const int ms = (w & 1) << 6, ns = (w >> 1) << 5;
  const int fr = l & 15, fg = l >> 4;
  const int lr = l >> 2;
  const int sslot = (((l & 3) ^ (lr & 3)) << 3);
  const int arow = row0 + (w << 4) + lr;
  const int brow = col0 + (w << 4) + lr;
  const int rsw = fr & 3;
  f32x4 ax[4][2], ay[4][2];
  #pragma unroll
  for (int i = 0; i < 4; ++i)
    #pragma unroll
    for (int j = 0; j < 2; ++j) { ax[i][j] = (f32x4)0.0f; ay[i][j] = (f32x4)0.0f; }

  gload16(Ag + (long)arow * 1024 + sslot,         &As[0][(w << 4) * 32]);
  gload16(Ag + (long)(arow + 64) * 1024 + sslot,  &As[0][(64 + (w << 4)) * 32]);
  gload16(Wg + (long)brow * 256 + sslot,          &Bxs[0][(w << 4) * 32]);
  gload16(Wg + (long)(1024 + brow) * 256 + sslot, &Bys[0][(w << 4) * 32]);
  __syncthreads();
  int cur = 0;
  for (int t = 0; t < 8; ++t) {
    if (t + 1 < 8) {
      const int k0 = (t + 1) << 5;
      gload16(Ag + (long)arow * 1024 + k0 + sslot,         &As[cur ^ 1][(w << 4) * 32]);
      gload16(Ag + (long)(arow + 64) * 1024 + k0 + sslot,  &As[cur ^ 1][(64 + (w << 4)) * 32]);
      gload16(Wg + (long)brow * 256 + k0 + sslot,          &Bxs[cur ^ 1][(w << 4) * 32]);
      gload16(Wg + (long)(1024 + brow) * 256 + k0 + sslot, &Bys[cur ^ 1][(w << 4) * 32]);
    }
    short8 af[4], bx[2], by[2];
    #pragma unroll
    for (int i = 0; i < 4; ++i)
      af[i] = *(const short8*)&As[cur][(ms + i*16 + fr) * 32 + ((fg ^ rsw) << 3)];
    #pragma unroll
    for (int j = 0; j < 2; ++j) {
      bx[j] = *(const short8*)&Bxs[cur][(ns + j*16 + fr) * 32 + ((fg ^ rsw) << 3)];
      by[j] = *(const short8*)&Bys[cur][(ns + j*16 + fr) * 32 + ((fg ^ rsw) << 3)];
    }
    #pragma unroll
    for (int i = 0; i < 4; ++i)
      #pragma unroll
      for (int j = 0; j < 2; ++j) {
        ax[i][j] = __builtin_amdgcn_mfma_f32_16x16x32_bf16(bx[j], af[i], ax[i][j], 0, 0, 0);
        ay[i][j] = __builtin_amdgcn_mfma_f32_16x16x32_bf16(by[j], af[i], ay[i][j], 0, 0, 0);
      }
    __syncthreads();
    cur ^= 1;
  }

  #pragma unroll
  for (int j = 0; j < 2; ++j) {
    const float4 bx4 = *(const float4*)(bg + col0 + ns + j*16 + (fg << 2));
    const float4 by4 = *(const float4*)(bg + 1024 + col0 + ns + j*16 + (fg << 2));
    #pragma unroll
    for (int i = 0; i < 4; ++i) {
      const long row = row0 + ms + i*16 + fr;
      const long cb = row * 4096 + g * 1024 + col0 + ns + j*16 + (fg << 2);
      float o4[4];
      const float* bxp = &bx4.x; const float* byp = &by4.x;
      #pragma unroll
      for (int r4 = 0; r4 < 4; ++r4) {
        const float xh = ax[i][j][r4] + bxp[r4];
        const float yh = ay[i][j][r4] + byp[r4];
        o4[r4] = xh * fmaxf(yh, 0.0f);
      }
      uint2 pk; pk.x = cvtpk(o4[0], o4[1]); pk.y = cvtpk(o4[2], o4[3]);
      *(uint2*)(H2 + cb) = pk;
    }
  }
}

// -------- prep: q2/k2 row sums-of-squares + V transpose, per (s-tile, head) --
__global__ __launch_bounds__(256) void prep_attn_kernel(
    const unsigned short* __restrict__ qkv,
    float* __restrict__ q2g, float* __restrict__ k2g,
    unsigned short* __restrict__ vt)
{
  const int n = blockIdx.y, s0 = blockIdx.x * 64;
  const int b = n >> 4, hoff = (n & 15) * 64;
  const int tid = threadIdx.x;
  __shared__ unsigned short T[64][72];
  // stage V rows for transpose
  #pragma unroll
  for (int p = 0; p < 2; ++p) {
    const int r = (tid >> 3) + p * 32, c = (tid & 7) << 3;
    *(short8*)&T[r][c] = *(const short8*)(qkv + ((long)((s0 + r) * 4 + b)) * 3072 + 2048 + hoff + c);
  }
  // q2/k2: row r = tid>>2, 16-d chunk e = tid&3
  {
    const int r = tid >> 2, e = tid & 3;
    const long base = ((long)((s0 + r) * 4 + b)) * 3072 + hoff + (e << 4);
    float sq = 0.f, sk = 0.f;
    #pragma unroll
    for (int ch = 0; ch < 2; ++ch) {
      short8 q8 = *(const short8*)(qkv + base + (ch << 3));
      short8 k8 = *(const short8*)(qkv + base + 1024 + (ch << 3));
      #pragma unroll
      for (int ee = 0; ee < 8; ++ee) {
        float f = bf2f((unsigned short)q8[ee]); sq = fmaf(f, f, sq);
        f = bf2f((unsigned short)k8[ee]); sk = fmaf(f, f, sk);
      }
    }
    sq += __shfl_xor(sq, 1); sq += __shfl_xor(sq, 2);
    sk += __shfl_xor(sk, 1); sk += __shfl_xor(sk, 2);
    if (e == 0) {
      q2g[n * 1024 + s0 + r] = sq;
      k2g[n * 1024 + s0 + r] = sk;
    }
  }
  __syncthreads();
  #pragma unroll
  for (int p = 0; p < 2; ++p) {
    const int d = (tid >> 3) + p * 32, sc = (tid & 7) << 3;
    short8 o;
    #pragma unroll
    for (int j = 0; j < 8; ++j) o[j] = (short)T[sc + j][d];
    *(short8*)(vt + ((long)n * 64 + d) * 1024 + s0 + sc) = o;
  }
}

// ------------- MFMA attention, swapped ops, K/V dbuf prefetch -------------
// grid (16 s-tiles, 64 heads).
__global__ __launch_bounds__(256) void attn_kernel(
    const unsigned short* __restrict__ qkv, const unsigned short* __restrict__ vt,
    const float* __restrict__ q2g, const float* __restrict__ k2g,
    float* __restrict__ ctx, float* __restrict__ scores)
{
  const int n = blockIdx.y;
  const int s0 = blockIdx.x * 64;
  const int b = n >> 4, hoff = (n & 15) * 64;
  __shared__ __align__(16) unsigned short Qs[64][72];
  __shared__ __align__(16) unsigned short Ks[2][64 * 64];
  __shared__ __align__(16) unsigned short VTl[2][64 * 64];
  __shared__ __align__(16) unsigned short Ps[64][72];
  const int tid = threadIdx.x, w = tid >> 6, l = tid & 63;
  const int fr = l & 15, fg = l >> 4;
  const int lr8 = l >> 3, ls8 = l & 7;
  const int sslot = ((ls8 ^ lr8) << 3);
  const int rsw = fr & 7;

  #pragma unroll
  for (int p = 0; p < 2; ++p) {
    const int r = (tid >> 3) + p * 32, c = (tid & 7) << 3;
    *(short8*)&Qs[r][c] = *(const short8*)(qkv + ((long)((s0 + r) * 4 + b)) * 3072 + hoff + c);
  }
  float q2m[4];   // per-lane -q2*0.0625 for srow = s0+16i+fr
  #pragma unroll
  for (int i = 0; i < 4; ++i) q2m[i] = -0.0625f * q2g[n * 1024 + s0 + i*16 + fr];

  // prologue: stage tile 0 into buf 0
  #pragma unroll
  for (int p = 0; p < 2; ++p) {
    const int rowb = p * 32 + w * 8;
    gload16(qkv + ((long)((rowb + lr8) * 4 + b)) * 3072 + 1024 + hoff + sslot, &Ks[0][rowb * 64]);
    gload16(vt + ((long)n * 64 + rowb + lr8) * 1024 + sslot,                   &VTl[0][rowb * 64]);
  }
  __syncthreads();

  f32x4 o[4];
  #pragma unroll
  for (int i = 0; i < 4; ++i) o[i] = (f32x4)0.0f;

  int cur = 0;
  for (int t0 = 0; t0 < 1024; t0 += 64) {
    if (t0 + 64 < 1024) {   // prefetch next K/V tile into other buffer
      #pragma unroll
      for (int p = 0; p < 2; ++p) {
        const int rowb = p * 32 + w * 8;
        gload16(qkv + ((long)((t0 + 64 + rowb + lr8) * 4 + b)) * 3072 + 1024 + hoff + sslot,
                &Ks[cur ^ 1][rowb * 64]);
        gload16(vt + ((long)n * 64 + rowb + lr8) * 1024 + t0 + 64 + sslot,
                &VTl[cur ^ 1][rowb * 64]);
      }
    }
    const float4 k2v4 = *(const float4*)(k2g + n * 1024 + t0 + (w << 4) + (fg << 2));
    const float k2m[4] = {-0.0625f*k2v4.x, -0.0625f*k2v4.y, -0.0625f*k2v4.z, -0.0625f*k2v4.w};

    // QK^T swapped: D[t][srow]; lane: srow = 16i+fr, t = 16w+4fg+r4
    f32x4 c4[4];
    #pragma unroll
    for (int i = 0; i < 4; ++i) c4[i] = (f32x4)0.0f;
    #pragma unroll
    for (int ks = 0; ks < 2; ++ks) {
      const short8 kf = *(const short8*)&Ks[cur][((w << 4) + fr) * 64 + ((((ks << 2) + fg) ^ rsw) << 3)];
      #pragma unroll
      for (int i = 0; i < 4; ++i) {
        const short8 qf = *(const short8*)&Qs[i*16 + fr][(ks << 5) + (fg << 3)];
        c4[i] = __builtin_amdgcn_mfma_f32_16x16x32_bf16(kf, qf, c4[i], 0, 0, 0);
      }
    }
    #pragma unroll
    for (int i = 0; i < 4; ++i) {
      f32x4 sc;
      float pe[4];
      #pragma unroll
      for (int r4 = 0; r4 < 4; ++r4) {
        const float m = fmaf(c4[i][r4], 0.125f, q2m[i] + k2m[r4]);
        sc[r4] = m;
        pe[r4] = __expf(m);
      }
      __builtin_nontemporal_store(sc,
          (f32x4*)(scores + (long)n * 1048576 + (long)(s0 + i*16 + fr) * 1024 + t0 + (w << 4) + (fg << 2)));
      uint2 pk; pk.x = cvtpk(pe[0], pe[1]); pk.y = cvtpk(pe[2], pe[3]);
      *(uint2*)&Ps[i*16 + fr][(w << 4) + (fg << 2)] = pk;
    }
    __syncthreads();

    // PV swapped: D[d][srow]; lane: srow = 16i+fr, d = 16w+4fg+r4
    #pragma unroll
    for (int ks = 0; ks < 2; ++ks) {
      const short8 vb = *(const short8*)&VTl[cur][((w << 4) + fr) * 64 + ((((ks << 2) + fg) ^ rsw) << 3)];
      #pragma unroll
      for (int i = 0; i < 4; ++i) {
        const short8 pf = *(const short8*)&Ps[i*16 + fr][(ks << 5) + (fg << 3)];
        o[i] = __builtin_amdgcn_mfma_f32_16x16x32_bf16(vb, pf, o[i], 0, 0, 0);
      }
    }
    __syncthreads();
    cur ^= 1;
  }

  #pragma unroll
  for (int i = 0; i < 4; ++i) {
    const float4 ov = make_float4(o[i][0], o[i][1], o[i][2], o[i][3]);
    *(float4*)(ctx + ((long)((s0 + i*16 + fr) * 4 + b)) * 1024 + hoff + (w << 4) + (fg << 2)) = ov;
  }
}

// -------- residual + per-head LN2 -> bf16 ctx2 -----------------------------
__global__ __launch_bounds__(256) void ln2res_kernel(
    const float* __restrict__ xln, const float* __restrict__ ctx,
    const float* __restrict__ g2, const float* __restrict__ b2,
    unsigned short* __restrict__ ctx2)
{
  const int lane = threadIdx.x & 63;
  const long row = (long)blockIdx.x * 4 + (threadIdx.x >> 6);
  const long idx = row * 64 + lane;
  const float v = xln[idx] + ctx[idx];
  float s = v, ss = v * v;
  #pragma unroll
  for (int off = 32; off > 0; off >>= 1) {
    s  += __shfl_xor(s, off);
    ss += __shfl_xor(ss, off);
  }
  const float mean = s * (1.0f/64.0f);
  const float var  = ss * (1.0f/64.0f) - mean*mean;
  const float rs   = rsqrtf(var + 1e-6f);
  ctx2[idx] = f2bf((v - mean) * rs * g2[lane] + b2[lane]);
}

extern "C" void kernel_launch(void* const* d_in, const int* in_sizes, int n_in,
                              void* d_out, int out_size, void* d_ws, size_t ws_size,
                              hipStream_t stream) {
  const float* hs   = (const float*)d_in[0];
  const float* g1   = (const float*)d_in[1];
  const float* b1   = (const float*)d_in[2];
  const float* g2   = (const float*)d_in[3];
  const float* b2   = (const float*)d_in[4];
  const float* Wq   = (const float*)d_in[5];
  const float* bq   = (const float*)d_in[6];
  const float* Wk   = (const float*)d_in[7];
  const float* bk   = (const float*)d_in[8];
  const float* Wv   = (const float*)d_in[9];
  const float* bv   = (const float*)d_in[10];
  const float* Win  = (const float*)d_in[11];
  const float* bin  = (const float*)d_in[12];
  const float* Wout = (const float*)d_in[13];
  const float* bout = (const float*)d_in[14];
  const float* Wd   = (const float*)d_in[15];
  const float* bd   = (const float*)d_in[16];

  // ws layout (bytes), ~99 MB total. Overlays: h2 over xbf+qkv, og over xln.
  char* ws = (char*)d_ws;
  float*          xln   = (float*)(ws + 0);                 // [4096][1024] f32
  unsigned short* xbf   = (unsigned short*)(ws + 16777216); // [4096][1024] bf16
  unsigned short* qkv   = (unsigned short*)(ws + 25165824); // [4096][3072] bf16
  float*          ctx   = (float*)(ws + 50331648);          // [4096][1024] f32
  unsigned short* ctx2  = (unsigned short*)(ws + 67108864); // [4096][1024] bf16
  unsigned short* wqkvT = (unsigned short*)(ws + 75497472); // [3072][1024] bf16
  unsigned short* winT  = (unsigned short*)(ws + 81788928); // [4][2048][256]
  unsigned short* woutT = (unsigned short*)(ws + 85983232); // [4][256][1024]
  unsigned short* wdT   = (unsigned short*)(ws + 88080384); // [1024][1024]
  float*          qkvb  = (float*)(ws + 90177536);          // [3072] f32
  unsigned short* vt    = (unsigned short*)(ws + 90189824); // [64][64][1024] bf16
  float*          q2g   = (float*)(ws + 98578432);          // [64][1024] f32
  float*          k2g   = (float*)(ws + 98840576);          // [64][1024] f32
  unsigned short* h2    = (unsigned short*)(ws + 16777216); // [4096][4096] bf16
  unsigned short* og    = (unsigned short*)(ws + 0);        // [4096][1024] bf16

  float* out0 = (float*)d_out;           // [S,B,H]
  float* out1 = out0 + 4194304;          // [64,1024,1024]

  ln1_kernel<<<4096, 256, 0, stream>>>(hs, g1, b1, xln, xbf);

  transpose_qkvd_kernel<<<dim3(32,32,4), 256, 0, stream>>>(Wq, Wk, Wv, Wd, wqkvT, wdT);
  transpose_w_kernel<<<dim3(64,8,4), 256, 0, stream>>>(Win, 256, 2048, 524288, winT, 524288);
  transpose_w_kernel<<<dim3(8,32,4), 256, 0, stream>>>(Wout, 1024, 256, 262144, woutT, 262144);
  packb_kernel<<<12, 256, 0, stream>>>(bq, bk, bv, qkvb);

  // QKV: [4096,1024]@[1024,3072] -> qkv bf16
  mfma_gemm_kernel<<<dim3(24,32,1), 256, 0, stream>>>(
      xbf, 1024, 0, wqkvT, 0, 1024, qkvb, 0, qkv, nullptr, 3072, 0);

  prep_attn_kernel<<<dim3(16,64), 256, 0, stream>>>(qkv, q2g, k2g, vt);

  attn_kernel<<<dim3(16,64), 256, 0, stream>>>(qkv, vt, q2g, k2g, ctx, out1);

  ln2res_kernel<<<16384, 256, 0, stream>>>(xln, ctx, g2, b2, ctx2);

  mfma_glu_kernel<<<dim3(16,32,4), 256, 0, stream>>>(ctx2, winT, bin, h2);

  // FFN-out: per group [4096,1024]@[1024,256] -> og bf16
  mfma_gemm_kernel<<<dim3(2,32,4), 256, 0, stream>>>(
      h2, 4096, 1024, woutT, 262144, 1024, bout, 256, og, nullptr, 1024, 256);

  // dense: [4096,1024]@[1024,1024] -> out0 fp32 (NT store)
  mfma_gemm_kernel<<<dim3(8,32,1), 256, 0, stream>>>(
      og, 1024, 0, wdT, 0, 1024, bd, 0, nullptr, out0, 1024, 0);
}

// Round 10
// 254.153 us; speedup vs baseline: 1.0717x; 1.0717x over previous
//
#include <hip/hip_runtime.h>

// TransformerLayer_Combined on gfx950 — bf16 MFMA pipeline.
// BK=64 single-buffered GEMMs (fewer barrier drains), swapped-operand
// epilogues, attn with fused residual+LN2. Outputs fp32.

typedef __attribute__((ext_vector_type(8))) short short8;
typedef __attribute__((ext_vector_type(4))) float f32x4;

__device__ __forceinline__ unsigned short f2bf(float f) {
  union { float f; unsigned u; } x; x.f = f;
  unsigned r = x.u + 0x7FFFu + ((x.u >> 16) & 1u);
  return (unsigned short)(r >> 16);
}
__device__ __forceinline__ float bf2f(unsigned short u) {
  union { float f; unsigned u; } x; x.u = ((unsigned)u) << 16;
  return x.f;
}
__device__ __forceinline__ unsigned cvtpk(float a, float b) {  // [lo=a, hi=b]
  unsigned r;
  asm("v_cvt_pk_bf16_f32 %0, %1, %2" : "=v"(r) : "v"(a), "v"(b));
  return r;
}
// async 16B global->LDS (dest = wave-uniform base + lane*16)
__device__ __forceinline__ void gload16(const unsigned short* g, unsigned short* l) {
  __builtin_amdgcn_global_load_lds(
      (const __attribute__((address_space(1))) unsigned int*)g,
      (__attribute__((address_space(3))) unsigned int*)l, 16, 0, 0);
}

// ---------------- LN1 over H=1024: fp32 (residual) + bf16 (GEMM A) --------
__global__ __launch_bounds__(256) void ln1_kernel(
    const float* __restrict__ x, const float* __restrict__ g,
    const float* __restrict__ b, float* __restrict__ y,
    unsigned short* __restrict__ ybf)
{
  const long base = (long)blockIdx.x * 1024;
  const int c = threadIdx.x * 4;
  float4 v = *(const float4*)(x + base + c);
  float s = v.x + v.y + v.z + v.w;
  float ss = v.x*v.x + v.y*v.y + v.z*v.z + v.w*v.w;
  #pragma unroll
  for (int off = 32; off > 0; off >>= 1) {
    s  += __shfl_xor(s, off);
    ss += __shfl_xor(ss, off);
  }
  __shared__ float sw[4], ssw[4];
  const int wave = threadIdx.x >> 6;
  if ((threadIdx.x & 63) == 0) { sw[wave] = s; ssw[wave] = ss; }
  __syncthreads();
  s  = sw[0] + sw[1] + sw[2] + sw[3];
  ss = ssw[0] + ssw[1] + ssw[2] + ssw[3];
  const float mean = s * (1.0f/1024.0f);
  const float var  = ss * (1.0f/1024.0f) - mean*mean;
  const float rs   = rsqrtf(var + 1e-6f);
  const float4 gv = *(const float4*)(g + c);
  const float4 bv = *(const float4*)(b + c);
  float4 o;
  o.x = (v.x - mean) * rs * gv.x + bv.x;
  o.y = (v.y - mean) * rs * gv.y + bv.y;
  o.z = (v.z - mean) * rs * gv.z + bv.z;
  o.w = (v.w - mean) * rs * gv.w + bv.w;
  *(float4*)(y + base + c) = o;
  ushort4 ob;
  ob.x = f2bf(o.x); ob.y = f2bf(o.y); ob.z = f2bf(o.z); ob.w = f2bf(o.w);
  *(ushort4*)(ybf + base + c) = ob;
}

// -------- weight transpose+convert: W [K][N] fp32 -> WT [N][K] bf16 --------
__global__ __launch_bounds__(256) void transpose_w_kernel(
    const float* __restrict__ W, int K, int N, long wgs,
    unsigned short* __restrict__ WT, long wtgs)
{
  __shared__ float T[32][33];
  const float* Wg = W + (long)blockIdx.z * wgs;
  unsigned short* WTg = WT + (long)blockIdx.z * wtgs;
  const int n0 = blockIdx.x * 32, k0 = blockIdx.y * 32;
  const int t = threadIdx.x;
  const int r = t >> 3, c4 = (t & 7) * 4;
  float4 v = *(const float4*)(Wg + (long)(k0 + r) * N + n0 + c4);
  T[r][c4+0] = v.x; T[r][c4+1] = v.y; T[r][c4+2] = v.z; T[r][c4+3] = v.w;
  __syncthreads();
  ushort4 o;
  o.x = f2bf(T[c4+0][r]); o.y = f2bf(T[c4+1][r]);
  o.z = f2bf(T[c4+2][r]); o.w = f2bf(T[c4+3][r]);
  *(ushort4*)(WTg + (long)(n0 + r) * K + k0 + c4) = o;
}

// merged 1024x1024 transposes: z=0..2 -> wqkvT, z=3 -> wdT
__global__ __launch_bounds__(256) void transpose_qkvd_kernel(
    const float* __restrict__ Wq, const float* __restrict__ Wk,
    const float* __restrict__ Wv, const float* __restrict__ Wd,
    unsigned short* __restrict__ wqkvT, unsigned short* __restrict__ wdT)
{
  const int z = blockIdx.z;
  const float* W = (z == 0) ? Wq : (z == 1) ? Wk : (z == 2) ? Wv : Wd;
  unsigned short* WT = (z == 3) ? wdT : wqkvT + (long)z * 1048576;
  __shared__ float T[32][33];
  const int n0 = blockIdx.x * 32, k0 = blockIdx.y * 32;
  const int t = threadIdx.x;
  const int r = t >> 3, c4 = (t & 7) * 4;
  float4 v = *(const float4*)(W + (long)(k0 + r) * 1024 + n0 + c4);
  T[r][c4+0] = v.x; T[r][c4+1] = v.y; T[r][c4+2] = v.z; T[r][c4+3] = v.w;
  __syncthreads();
  ushort4 o;
  o.x = f2bf(T[c4+0][r]); o.y = f2bf(T[c4+1][r]);
  o.z = f2bf(T[c4+2][r]); o.w = f2bf(T[c4+3][r]);
  *(ushort4*)(WT + (long)(n0 + r) * 1024 + k0 + c4) = o;
}

__global__ __launch_bounds__(256) void packb_kernel(
    const float* __restrict__ bq, const float* __restrict__ bk,
    const float* __restrict__ bv, float* __restrict__ qb)
{
  const int i = blockIdx.x * 256 + threadIdx.x;   // 3072
  qb[i] = (i < 1024) ? bq[i] : ((i < 2048) ? bk[i - 1024] : bv[i - 2048]);
}

// ---- bf16 MFMA GEMM, 128x128 tile, BK=64 single buffer, swapped epi ----
// LDS [row][64 shorts]; logical 16B-slot s of row r stored at s^(r&7).
__global__ __launch_bounds__(256) void mfma_gemm_kernel(
    const unsigned short* __restrict__ A, int lda, long agoff,
    const unsigned short* __restrict__ BT, long bgoff, int K,
    const float* __restrict__ bias, int biasoff,
    unsigned short* __restrict__ Cbf, float* __restrict__ Cf,
    int ldc, int cgoff)
{
  const int g = blockIdx.z;
  const unsigned short* Ag = A + (long)g * agoff;
  const unsigned short* Bg = BT + (long)g * bgoff;
  const float* biasg = bias + (long)g * biasoff;
  const int row0 = blockIdx.y * 128, col0 = blockIdx.x * 128;
  __shared__ __align__(16) unsigned short As[128 * 64];
  __shared__ __align__(16) unsigned short Bs[128 * 64];
  const int tid = threadIdx.x;
  const int w = tid >> 6, l = tid & 63;
  const int ms = (w & 1) << 6, ns = (w >> 1) << 6;
  const int fr = l & 15, fg = l >> 4;
  const int lr8 = l >> 3, ls8 = l & 7;
  const int scol = (ls8 ^ lr8) << 3;   // pre-swizzled source col (shorts)
  const int rsw = fr & 7;
  f32x4 acc[4][4];
  #pragma unroll
  for (int i = 0; i < 4; ++i)
    #pragma unroll
    for (int j = 0; j < 4; ++j) acc[i][j] = (f32x4)0.0f;

  for (int k0 = 0; k0 < K; k0 += 64) {
    #pragma unroll
    for (int g8 = 0; g8 < 4; ++g8) {
      const int r = (w << 5) + (g8 << 3);
      gload16(Ag + (long)(row0 + r + lr8) * lda + k0 + scol, &As[r * 64]);
      gload16(Bg + (long)(col0 + r + lr8) * K  + k0 + scol, &Bs[r * 64]);
    }
    __syncthreads();
    #pragma unroll
    for (int ks = 0; ks < 2; ++ks) {
      const int rslot = (((ks << 2) + fg) ^ rsw) << 3;
      short8 af[4], bfr[4];
      #pragma unroll
      for (int i = 0; i < 4; ++i)
        af[i] = *(const short8*)&As[(ms + i*16 + fr) * 64 + rslot];
      #pragma unroll
      for (int j = 0; j < 4; ++j)
        bfr[j] = *(const short8*)&Bs[(ns + j*16 + fr) * 64 + rslot];
      #pragma unroll
      for (int i = 0; i < 4; ++i)
        #pragma unroll
        for (int j = 0; j < 4; ++j)   // swapped: D[n][m]
          acc[i][j] = __builtin_amdgcn_mfma_f32_16x16x32_bf16(bfr[j], af[i], acc[i][j], 0, 0, 0);
    }
    __syncthreads();
  }

  // epilogue: per lane n = ns+16j+4fg+r4 (consecutive), m = ms+16i+fr
  #pragma unroll
  for (int j = 0; j < 4; ++j) {
    const float4 bj4 = *(const float4*)(biasg + col0 + ns + j*16 + (fg << 2));
    #pragma unroll
    for (int i = 0; i < 4; ++i) {
      const long row = row0 + ms + i*16 + fr;
      const long cb = row * ldc + (long)g * cgoff + col0 + ns + j*16 + (fg << 2);
      const float v0 = acc[i][j][0] + bj4.x, v1 = acc[i][j][1] + bj4.y;
      const float v2 = acc[i][j][2] + bj4.z, v3 = acc[i][j][3] + bj4.w;
      if (Cbf) {
        uint2 pk; pk.x = cvtpk(v0, v1); pk.y = cvtpk(v2, v3);
        *(uint2*)(Cbf + cb) = pk;
      } else {
        f32x4 o = {v0, v1, v2, v3};
        __builtin_nontemporal_store(o, (f32x4*)(Cf + cb));
      }
    }
  }
}

// ---- grouped dense_in + GLU, 128x64 tile, BK=64 single buffer ----------
__global__ __launch_bounds__(256) void mfma_glu_kernel(
    const unsigned short* __restrict__ A,   // ctx2 [4096][1024]
    const unsigned short* __restrict__ WT,  // [g][2048][256]
    const float* __restrict__ bin,          // [4][2048]
    unsigned short* __restrict__ H2)        // [4096][4096]
{
  const int g = blockIdx.z;
  const unsigned short* Ag = A + g * 256;
  const unsigned short* Wg = WT + (long)g * 2048 * 256;
  const float* bg = bin + g * 2048;
  const int row0 = blockIdx.y * 128, col0 = blockIdx.x * 64;
  __shared__ __align__(16) unsigned short As[128 * 64];
  __shared__ __align__(16) unsigned short Bxs[64 * 64];
  __shared__ __align__(16) unsigned short Bys[64 * 64];
  const int tid = threadIdx.x;
  const int w = tid >> 6, l = tid & 63;
  const int ms = (w & 1) << 6, ns = (w >> 1) << 5;
  const int fr = l & 15, fg = l >> 4;
  const int lr8 = l >> 3, ls8 = l & 7;
  const int scol = (ls8 ^ lr8) << 3;
  const int rsw = fr & 7;
  f32x4 ax[4][2], ay[4][2];
  #pragma unroll
  for (int i = 0; i < 4; ++i)
    #pragma unroll
    for (int j = 0; j < 2; ++j) { ax[i][j] = (f32x4)0.0f; ay[i][j] = (f32x4)0.0f; }

  for (int k0 = 0; k0 < 256; k0 += 64) {
    #pragma unroll
    for (int g8 = 0; g8 < 4; ++g8) {
      const int r = (w << 5) + (g8 << 3);
      gload16(Ag + (long)(row0 + r + lr8) * 1024 + k0 + scol, &As[r * 64]);
    }
    #pragma unroll
    for (int g8 = 0; g8 < 2; ++g8) {
      const int r = (w << 4) + (g8 << 3);
      gload16(Wg + (long)(col0 + r + lr8) * 256 + k0 + scol,          &Bxs[r * 64]);
      gload16(Wg + (long)(1024 + col0 + r + lr8) * 256 + k0 + scol,   &Bys[r * 64]);
    }
    __syncthreads();
    #pragma unroll
    for (int ks = 0; ks < 2; ++ks) {
      const int rslot = (((ks << 2) + fg) ^ rsw) << 3;
      short8 af[4], bx[2], by[2];
      #pragma unroll
      for (int i = 0; i < 4; ++i)
        af[i] = *(const short8*)&As[(ms + i*16 + fr) * 64 + rslot];
      #pragma unroll
      for (int j = 0; j < 2; ++j) {
        bx[j] = *(const short8*)&Bxs[(ns + j*16 + fr) * 64 + rslot];
        by[j] = *(const short8*)&Bys[(ns + j*16 + fr) * 64 + rslot];
      }
      #pragma unroll
      for (int i = 0; i < 4; ++i)
        #pragma unroll
        for (int j = 0; j < 2; ++j) {
          ax[i][j] = __builtin_amdgcn_mfma_f32_16x16x32_bf16(bx[j], af[i], ax[i][j], 0, 0, 0);
          ay[i][j] = __builtin_amdgcn_mfma_f32_16x16x32_bf16(by[j], af[i], ay[i][j], 0, 0, 0);
        }
    }
    __syncthreads();
  }

  #pragma unroll
  for (int j = 0; j < 2; ++j) {
    const float4 bx4 = *(const float4*)(bg + col0 + ns + j*16 + (fg << 2));
    const float4 by4 = *(const float4*)(bg + 1024 + col0 + ns + j*16 + (fg << 2));
    #pragma unroll
    for (int i = 0; i < 4; ++i) {
      const long row = row0 + ms + i*16 + fr;
      const long cb = row * 4096 + g * 1024 + col0 + ns + j*16 + (fg << 2);
      float o4[4];
      const float* bxp = &bx4.x; const float* byp = &by4.x;
      #pragma unroll
      for (int r4 = 0; r4 < 4; ++r4) {
        const float xh = ax[i][j][r4] + bxp[r4];
        const float yh = ay[i][j][r4] + byp[r4];
        o4[r4] = xh * fmaxf(yh, 0.0f);
      }
      uint2 pk; pk.x = cvtpk(o4[0], o4[1]); pk.y = cvtpk(o4[2], o4[3]);
      *(uint2*)(H2 + cb) = pk;
    }
  }
}

// -------- prep: q2/k2 row sums-of-squares + V transpose ------------------
__global__ __launch_bounds__(256) void prep_attn_kernel(
    const unsigned short* __restrict__ qkv,
    float* __restrict__ q2g, float* __restrict__ k2g,
    unsigned short* __restrict__ vt)
{
  const int n = blockIdx.y, s0 = blockIdx.x * 64;
  const int b = n >> 4, hoff = (n & 15) * 64;
  const int tid = threadIdx.x;
  __shared__ unsigned short T[64][72];
  #pragma unroll
  for (int p = 0; p < 2; ++p) {
    const int r = (tid >> 3) + p * 32, c = (tid & 7) << 3;
    *(short8*)&T[r][c] = *(const short8*)(qkv + ((long)((s0 + r) * 4 + b)) * 3072 + 2048 + hoff + c);
  }
  {
    const int r = tid >> 2, e = tid & 3;
    const long base = ((long)((s0 + r) * 4 + b)) * 3072 + hoff + (e << 4);
    float sq = 0.f, sk = 0.f;
    #pragma unroll
    for (int ch = 0; ch < 2; ++ch) {
      short8 q8 = *(const short8*)(qkv + base + (ch << 3));
      short8 k8 = *(const short8*)(qkv + base + 1024 + (ch << 3));
      #pragma unroll
      for (int ee = 0; ee < 8; ++ee) {
        float f = bf2f((unsigned short)q8[ee]); sq = fmaf(f, f, sq);
        f = bf2f((unsigned short)k8[ee]); sk = fmaf(f, f, sk);
      }
    }
    sq += __shfl_xor(sq, 1); sq += __shfl_xor(sq, 2);
    sk += __shfl_xor(sk, 1); sk += __shfl_xor(sk, 2);
    if (e == 0) {
      q2g[n * 1024 + s0 + r] = sq;
      k2g[n * 1024 + s0 + r] = sk;
    }
  }
  __syncthreads();
  #pragma unroll
  for (int p = 0; p < 2; ++p) {
    const int d = (tid >> 3) + p * 32, sc = (tid & 7) << 3;
    short8 o;
    #pragma unroll
    for (int j = 0; j < 8; ++j) o[j] = (short)T[sc + j][d];
    *(short8*)(vt + ((long)n * 64 + d) * 1024 + s0 + sc) = o;
  }
}

// --- MFMA attention + fused residual + per-head LN2 -> ctx2 bf16 ---------
// grid (16 s-tiles, 64 heads).
__global__ __launch_bounds__(256) void attn_kernel(
    const unsigned short* __restrict__ qkv, const unsigned short* __restrict__ vt,
    const float* __restrict__ q2g, const float* __restrict__ k2g,
    const float* __restrict__ xln, const float* __restrict__ g2,
    const float* __restrict__ b2,
    unsigned short* __restrict__ ctx2, float* __restrict__ scores)
{
  const int n = blockIdx.y;
  const int s0 = blockIdx.x * 64;
  const int b = n >> 4, hoff = (n & 15) * 64;
  __shared__ __align__(16) unsigned short Qs[64][72];
  __shared__ __align__(16) unsigned short Ks[2][64 * 64];
  __shared__ __align__(16) unsigned short VTl[2][64 * 64];
  __shared__ __align__(16) unsigned short Ps[64][72];
  const int tid = threadIdx.x, w = tid >> 6, l = tid & 63;
  const int fr = l & 15, fg = l >> 4;
  const int lr8 = l >> 3, ls8 = l & 7;
  const int sslot = ((ls8 ^ lr8) << 3);
  const int rsw = fr & 7;

  #pragma unroll
  for (int p = 0; p < 2; ++p) {
    const int r = (tid >> 3) + p * 32, c = (tid & 7) << 3;
    *(short8*)&Qs[r][c] = *(const short8*)(qkv + ((long)((s0 + r) * 4 + b)) * 3072 + hoff + c);
  }
  float q2m[4];   // per-lane -q2*0.0625 for srow = s0+16i+fr
  #pragma unroll
  for (int i = 0; i < 4; ++i) q2m[i] = -0.0625f * q2g[n * 1024 + s0 + i*16 + fr];

  // prologue: stage tile 0 into buf 0
  #pragma unroll
  for (int p = 0; p < 2; ++p) {
    const int rowb = p * 32 + w * 8;
    gload16(qkv + ((long)((rowb + lr8) * 4 + b)) * 3072 + 1024 + hoff + sslot, &Ks[0][rowb * 64]);
    gload16(vt + ((long)n * 64 + rowb + lr8) * 1024 + sslot,                   &VTl[0][rowb * 64]);
  }
  __syncthreads();

  f32x4 o[4];
  #pragma unroll
  for (int i = 0; i < 4; ++i) o[i] = (f32x4)0.0f;

  int cur = 0;
  for (int t0 = 0; t0 < 1024; t0 += 64) {
    if (t0 + 64 < 1024) {
      #pragma unroll
      for (int p = 0; p < 2; ++p) {
        const int rowb = p * 32 + w * 8;
        gload16(qkv + ((long)((t0 + 64 + rowb + lr8) * 4 + b)) * 3072 + 1024 + hoff + sslot,
                &Ks[cur ^ 1][rowb * 64]);
        gload16(vt + ((long)n * 64 + rowb + lr8) * 1024 + t0 + 64 + sslot,
                &VTl[cur ^ 1][rowb * 64]);
      }
    }
    const float4 k2v4 = *(const float4*)(k2g + n * 1024 + t0 + (w << 4) + (fg << 2));
    const float k2m[4] = {-0.0625f*k2v4.x, -0.0625f*k2v4.y, -0.0625f*k2v4.z, -0.0625f*k2v4.w};

    // QK^T swapped: lane: srow = 16i+fr, t = 16w+4fg+r4
    f32x4 c4[4];
    #pragma unroll
    for (int i = 0; i < 4; ++i) c4[i] = (f32x4)0.0f;
    #pragma unroll
    for (int ks = 0; ks < 2; ++ks) {
      const short8 kf = *(const short8*)&Ks[cur][((w << 4) + fr) * 64 + ((((ks << 2) + fg) ^ rsw) << 3)];
      #pragma unroll
      for (int i = 0; i < 4; ++i) {
        const short8 qf = *(const short8*)&Qs[i*16 + fr][(ks << 5) + (fg << 3)];
        c4[i] = __builtin_amdgcn_mfma_f32_16x16x32_bf16(kf, qf, c4[i], 0, 0, 0);
      }
    }
    #pragma unroll
    for (int i = 0; i < 4; ++i) {
      f32x4 sc;
      float pe[4];
      #pragma unroll
      for (int r4 = 0; r4 < 4; ++r4) {
        const float m = fmaf(c4[i][r4], 0.125f, q2m[i] + k2m[r4]);
        sc[r4] = m;
        pe[r4] = __expf(m);
      }
      __builtin_nontemporal_store(sc,
          (f32x4*)(scores + (long)n * 1048576 + (long)(s0 + i*16 + fr) * 1024 + t0 + (w << 4) + (fg << 2)));
      uint2 pk; pk.x = cvtpk(pe[0], pe[1]); pk.y = cvtpk(pe[2], pe[3]);
      *(uint2*)&Ps[i*16 + fr][(w << 4) + (fg << 2)] = pk;
    }
    __syncthreads();

    // PV swapped: lane: srow = 16i+fr, d = 16w+4fg+r4
    #pragma unroll
    for (int ks = 0; ks < 2; ++ks) {
      const short8 vb = *(const short8*)&VTl[cur][((w << 4) + fr) * 64 + ((((ks << 2) + fg) ^ rsw) << 3)];
      #pragma unroll
      for (int i = 0; i < 4; ++i) {
        const short8 pf = *(const short8*)&Ps[i*16 + fr][(ks << 5) + (fg << 3)];
        o[i] = __builtin_amdgcn_mfma_f32_16x16x32_bf16(vb, pf, o[i], 0, 0, 0);
      }
    }
    __syncthreads();
    cur ^= 1;
  }

  // ---- fused residual + per-head LN2 -> ctx2 bf16 ----
  const int dbase = (w << 4) + (fg << 2);
  float4 xl4[4];
  #pragma unroll
  for (int i = 0; i < 4; ++i)
    xl4[i] = *(const float4*)(xln + ((long)((s0 + i*16 + fr) * 4 + b)) * 1024 + hoff + dbase);

  float* redbuf = (float*)&Ps[0][0];   // overlay (Ps dead): [64][16] sum + [64][16] sumsq
  const int slot = (w << 2) + fg;
  #pragma unroll
  for (int i = 0; i < 4; ++i) {
    float s = 0.f, ss = 0.f;
    const float* xp = &xl4[i].x;
    #pragma unroll
    for (int r4 = 0; r4 < 4; ++r4) {
      const float v = o[i][r4] + xp[r4];
      s += v; ss = fmaf(v, v, ss);
    }
    redbuf[(i*16 + fr) * 16 + slot] = s;
    redbuf[1024 + (i*16 + fr) * 16 + slot] = ss;
  }
  __syncthreads();
  float* statbuf = (float*)&Qs[0][0];  // overlay (Qs dead): mean[64], rs[64]
  {
    const int row = tid >> 2, q4 = tid & 3;
    float s = 0.f, ss = 0.f;
    #pragma unroll
    for (int k = 0; k < 4; ++k) {
      s  += redbuf[row * 16 + q4 * 4 + k];
      ss += redbuf[1024 + row * 16 + q4 * 4 + k];
    }
    s  += __shfl_xor(s, 1);  s  += __shfl_xor(s, 2);
    ss += __shfl_xor(ss, 1); ss += __shfl_xor(ss, 2);
    if (q4 == 0) {
      const float mean = s * (1.0f/64.0f);
      const float var  = ss * (1.0f/64.0f) - mean * mean;
      statbuf[row] = mean;
      statbuf[64 + row] = rsqrtf(var + 1e-6f);
    }
  }
  __syncthreads();
  const float4 g2v = *(const float4*)(g2 + dbase);
  const float4 b2v = *(const float4*)(b2 + dbase);
  const float* gp = &g2v.x; const float* bp = &b2v.x;
  #pragma unroll
  for (int i = 0; i < 4; ++i) {
    const float mean = statbuf[i*16 + fr];
    const float rs   = statbuf[64 + i*16 + fr];
    const float* xp = &xl4[i].x;
    float vo[4];
    #pragma unroll
    for (int r4 = 0; r4 < 4; ++r4)
      vo[r4] = (o[i][r4] + xp[r4] - mean) * rs * gp[r4] + bp[r4];
    uint2 pk; pk.x = cvtpk(vo[0], vo[1]); pk.y = cvtpk(vo[2], vo[3]);
    *(uint2*)(ctx2 + ((long)((s0 + i*16 + fr) * 4 + b)) * 1024 + hoff + dbase) = pk;
  }
}

extern "C" void kernel_launch(void* const* d_in, const int* in_sizes, int n_in,
                              void* d_out, int out_size, void* d_ws, size_t ws_size,
                              hipStream_t stream) {
  const float* hs   = (const float*)d_in[0];
  const float* g1   = (const float*)d_in[1];
  const float* b1   = (const float*)d_in[2];
  const float* g2   = (const float*)d_in[3];
  const float* b2   = (const float*)d_in[4];
  const float* Wq   = (const float*)d_in[5];
  const float* bq   = (const float*)d_in[6];
  const float* Wk   = (const float*)d_in[7];
  const float* bk   = (const float*)d_in[8];
  const float* Wv   = (const float*)d_in[9];
  const float* bv   = (const float*)d_in[10];
  const float* Win  = (const float*)d_in[11];
  const float* bin  = (const float*)d_in[12];
  const float* Wout = (const float*)d_in[13];
  const float* bout = (const float*)d_in[14];
  const float* Wd   = (const float*)d_in[15];
  const float* bd   = (const float*)d_in[16];

  // ws layout (bytes), ~99 MB total. Overlays: h2 over xbf+qkv, og over xln.
  char* ws = (char*)d_ws;
  float*          xln   = (float*)(ws + 0);                 // [4096][1024] f32
  unsigned short* xbf   = (unsigned short*)(ws + 16777216); // [4096][1024] bf16
  unsigned short* qkv   = (unsigned short*)(ws + 25165824); // [4096][3072] bf16
  unsigned short* ctx2  = (unsigned short*)(ws + 67108864); // [4096][1024] bf16
  unsigned short* wqkvT = (unsigned short*)(ws + 75497472); // [3072][1024] bf16
  unsigned short* winT  = (unsigned short*)(ws + 81788928); // [4][2048][256]
  unsigned short* woutT = (unsigned short*)(ws + 85983232); // [4][256][1024]
  unsigned short* wdT   = (unsigned short*)(ws + 88080384); // [1024][1024]
  float*          qkvb  = (float*)(ws + 90177536);          // [3072] f32
  unsigned short* vt    = (unsigned short*)(ws + 90189824); // [64][64][1024] bf16
  float*          q2g   = (float*)(ws + 98578432);          // [64][1024] f32
  float*          k2g   = (float*)(ws + 98840576);          // [64][1024] f32
  unsigned short* h2    = (unsigned short*)(ws + 16777216); // [4096][4096] bf16
  unsigned short* og    = (unsigned short*)(ws + 0);        // [4096][1024] bf16

  float* out0 = (float*)d_out;           // [S,B,H]
  float* out1 = out0 + 4194304;          // [64,1024,1024]

  ln1_kernel<<<4096, 256, 0, stream>>>(hs, g1, b1, xln, xbf);

  transpose_qkvd_kernel<<<dim3(32,32,4), 256, 0, stream>>>(Wq, Wk, Wv, Wd, wqkvT, wdT);
  transpose_w_kernel<<<dim3(64,8,4), 256, 0, stream>>>(Win, 256, 2048, 524288, winT, 524288);
  transpose_w_kernel<<<dim3(8,32,4), 256, 0, stream>>>(Wout, 1024, 256, 262144, woutT, 262144);
  packb_kernel<<<12, 256, 0, stream>>>(bq, bk, bv, qkvb);

  // QKV: [4096,1024]@[1024,3072] -> qkv bf16
  mfma_gemm_kernel<<<dim3(24,32,1), 256, 0, stream>>>(
      xbf, 1024, 0, wqkvT, 0, 1024, qkvb, 0, qkv, nullptr, 3072, 0);

  prep_attn_kernel<<<dim3(16,64), 256, 0, stream>>>(qkv, q2g, k2g, vt);

  attn_kernel<<<dim3(16,64), 256, 0, stream>>>(qkv, vt, q2g, k2g, xln, g2, b2, ctx2, out1);

  mfma_glu_kernel<<<dim3(16,32,4), 256, 0, stream>>>(ctx2, winT, bin, h2);

  // FFN-out: per group [4096,1024]@[1024,256] -> og bf16
  mfma_gemm_kernel<<<dim3(2,32,4), 256, 0, stream>>>(
      h2, 4096, 1024, woutT, 262144, 1024, bout, 256, og, nullptr, 1024, 256);

  // dense: [4096,1024]@[1024,1024] -> out0 fp32 (NT store)
  mfma_gemm_kernel<<<dim3(8,32,1), 256, 0, stream>>>(
      og, 1024, 0, wdT, 0, 1024, bd, 0, nullptr, out0, 1024, 0);
}

// Round 11
// 246.487 us; speedup vs baseline: 1.1050x; 1.0311x over previous
//
#include <hip/hip_runtime.h>

// TransformerLayer_Combined on gfx950 — bf16 MFMA pipeline.
// BK=64 single-buffered GEMMs; BN=64 tiles for 1-block/CU GEMMs (dense,
// FFN-out) to restore inter-block overlap; merged weight-prep kernel;
// attn with fused residual+LN2. Outputs fp32.

typedef __attribute__((ext_vector_type(8))) short short8;
typedef __attribute__((ext_vector_type(4))) float f32x4;

__device__ __forceinline__ unsigned short f2bf(float f) {
  union { float f; unsigned u; } x; x.f = f;
  unsigned r = x.u + 0x7FFFu + ((x.u >> 16) & 1u);
  return (unsigned short)(r >> 16);
}
__device__ __forceinline__ float bf2f(unsigned short u) {
  union { float f; unsigned u; } x; x.u = ((unsigned)u) << 16;
  return x.f;
}
__device__ __forceinline__ unsigned cvtpk(float a, float b) {  // [lo=a, hi=b]
  unsigned r;
  asm("v_cvt_pk_bf16_f32 %0, %1, %2" : "=v"(r) : "v"(a), "v"(b));
  return r;
}
// async 16B global->LDS (dest = wave-uniform base + lane*16)
__device__ __forceinline__ void gload16(const unsigned short* g, unsigned short* l) {
  __builtin_amdgcn_global_load_lds(
      (const __attribute__((address_space(1))) unsigned int*)g,
      (__attribute__((address_space(3))) unsigned int*)l, 16, 0, 0);
}

// ---------------- LN1 over H=1024: fp32 (residual) + bf16 (GEMM A) --------
__global__ __launch_bounds__(256) void ln1_kernel(
    const float* __restrict__ x, const float* __restrict__ g,
    const float* __restrict__ b, float* __restrict__ y,
    unsigned short* __restrict__ ybf)
{
  const long base = (long)blockIdx.x * 1024;
  const int c = threadIdx.x * 4;
  float4 v = *(const float4*)(x + base + c);
  float s = v.x + v.y + v.z + v.w;
  float ss = v.x*v.x + v.y*v.y + v.z*v.z + v.w*v.w;
  #pragma unroll
  for (int off = 32; off > 0; off >>= 1) {
    s  += __shfl_xor(s, off);
    ss += __shfl_xor(ss, off);
  }
  __shared__ float sw[4], ssw[4];
  const int wave = threadIdx.x >> 6;
  if ((threadIdx.x & 63) == 0) { sw[wave] = s; ssw[wave] = ss; }
  __syncthreads();
  s  = sw[0] + sw[1] + sw[2] + sw[3];
  ss = ssw[0] + ssw[1] + ssw[2] + ssw[3];
  const float mean = s * (1.0f/1024.0f);
  const float var  = ss * (1.0f/1024.0f) - mean*mean;
  const float rs   = rsqrtf(var + 1e-6f);
  const float4 gv = *(const float4*)(g + c);
  const float4 bv = *(const float4*)(b + c);
  float4 o;
  o.x = (v.x - mean) * rs * gv.x + bv.x;
  o.y = (v.y - mean) * rs * gv.y + bv.y;
  o.z = (v.z - mean) * rs * gv.z + bv.z;
  o.w = (v.w - mean) * rs * gv.w + bv.w;
  *(float4*)(y + base + c) = o;
  ushort4 ob;
  ob.x = f2bf(o.x); ob.y = f2bf(o.y); ob.z = f2bf(o.z); ob.w = f2bf(o.w);
  *(ushort4*)(ybf + base + c) = ob;
}

// ---- merged weight prep: all transposes + bias pack in one launch --------
// flat grid: [0,4096) qkv/d transposes; [4096,6144) Win; [6144,7168) Wout;
// [7168,7180) packb.
__device__ __forceinline__ void transpose_body(
    const float* __restrict__ Wg, unsigned short* __restrict__ WTg,
    int K, int N, int bx, int by, int tid)
{
  __shared__ float T[32][33];
  const int n0 = bx * 32, k0 = by * 32;
  const int r = tid >> 3, c4 = (tid & 7) * 4;
  float4 v = *(const float4*)(Wg + (long)(k0 + r) * N + n0 + c4);
  T[r][c4+0] = v.x; T[r][c4+1] = v.y; T[r][c4+2] = v.z; T[r][c4+3] = v.w;
  __syncthreads();
  ushort4 o;
  o.x = f2bf(T[c4+0][r]); o.y = f2bf(T[c4+1][r]);
  o.z = f2bf(T[c4+2][r]); o.w = f2bf(T[c4+3][r]);
  *(ushort4*)(WTg + (long)(n0 + r) * K + k0 + c4) = o;
}

__global__ __launch_bounds__(256) void prep_weights_kernel(
    const float* __restrict__ Wq, const float* __restrict__ Wk,
    const float* __restrict__ Wv, const float* __restrict__ Wd,
    const float* __restrict__ Win, const float* __restrict__ Wout,
    const float* __restrict__ bq, const float* __restrict__ bk,
    const float* __restrict__ bv,
    unsigned short* __restrict__ wqkvT, unsigned short* __restrict__ wdT,
    unsigned short* __restrict__ winT, unsigned short* __restrict__ woutT,
    float* __restrict__ qkvb)
{
  const int idx = blockIdx.x;
  const int tid = threadIdx.x;
  if (idx < 4096) {               // Wq/Wk/Wv/Wd 1024x1024
    const int z = idx >> 10, rem = idx & 1023;
    const float* W = (z == 0) ? Wq : (z == 1) ? Wk : (z == 2) ? Wv : Wd;
    unsigned short* WT = (z == 3) ? wdT : wqkvT + (long)z * 1048576;
    transpose_body(W, WT, 1024, 1024, rem & 31, rem >> 5, tid);
  } else if (idx < 6144) {        // Win [4][256][2048]
    const int rem = idx - 4096;
    const int z = rem >> 9, r2 = rem & 511;
    transpose_body(Win + (long)z * 524288, winT + (long)z * 524288,
                   256, 2048, r2 & 63, r2 >> 6, tid);
  } else if (idx < 7168) {        // Wout [4][1024][256]
    const int rem = idx - 6144;
    const int z = rem >> 8, r2 = rem & 255;
    transpose_body(Wout + (long)z * 262144, woutT + (long)z * 262144,
                   1024, 256, r2 & 7, r2 >> 3, tid);
  } else {                        // packb (12 blocks x 256)
    const int i = (idx - 7168) * 256 + tid;
    qkvb[i] = (i < 1024) ? bq[i] : ((i < 2048) ? bk[i - 1024] : bv[i - 2048]);
  }
}

// ---- bf16 MFMA GEMM, 128x128 tile, BK=64 single buffer, swapped epi ----
// LDS [row][64 shorts]; logical 16B-slot s of row r stored at s^(r&7).
__global__ __launch_bounds__(256) void mfma_gemm_kernel(
    const unsigned short* __restrict__ A, int lda, long agoff,
    const unsigned short* __restrict__ BT, long bgoff, int K,
    const float* __restrict__ bias, int biasoff,
    unsigned short* __restrict__ Cbf, float* __restrict__ Cf,
    int ldc, int cgoff)
{
  const int g = blockIdx.z;
  const unsigned short* Ag = A + (long)g * agoff;
  const unsigned short* Bg = BT + (long)g * bgoff;
  const float* biasg = bias + (long)g * biasoff;
  const int row0 = blockIdx.y * 128, col0 = blockIdx.x * 128;
  __shared__ __align__(16) unsigned short As[128 * 64];
  __shared__ __align__(16) unsigned short Bs[128 * 64];
  const int tid = threadIdx.x;
  const int w = tid >> 6, l = tid & 63;
  const int ms = (w & 1) << 6, ns = (w >> 1) << 6;
  const int fr = l & 15, fg = l >> 4;
  const int lr8 = l >> 3, ls8 = l & 7;
  const int scol = (ls8 ^ lr8) << 3;   // pre-swizzled source col (shorts)
  const int rsw = fr & 7;
  f32x4 acc[4][4];
  #pragma unroll
  for (int i = 0; i < 4; ++i)
    #pragma unroll
    for (int j = 0; j < 4; ++j) acc[i][j] = (f32x4)0.0f;

  for (int k0 = 0; k0 < K; k0 += 64) {
    #pragma unroll
    for (int g8 = 0; g8 < 4; ++g8) {
      const int r = (w << 5) + (g8 << 3);
      gload16(Ag + (long)(row0 + r + lr8) * lda + k0 + scol, &As[r * 64]);
      gload16(Bg + (long)(col0 + r + lr8) * K  + k0 + scol, &Bs[r * 64]);
    }
    __syncthreads();
    #pragma unroll
    for (int ks = 0; ks < 2; ++ks) {
      const int rslot = (((ks << 2) + fg) ^ rsw) << 3;
      short8 af[4], bfr[4];
      #pragma unroll
      for (int i = 0; i < 4; ++i)
        af[i] = *(const short8*)&As[(ms + i*16 + fr) * 64 + rslot];
      #pragma unroll
      for (int j = 0; j < 4; ++j)
        bfr[j] = *(const short8*)&Bs[(ns + j*16 + fr) * 64 + rslot];
      #pragma unroll
      for (int i = 0; i < 4; ++i)
        #pragma unroll
        for (int j = 0; j < 4; ++j)   // swapped: D[n][m]
          acc[i][j] = __builtin_amdgcn_mfma_f32_16x16x32_bf16(bfr[j], af[i], acc[i][j], 0, 0, 0);
    }
    __syncthreads();
  }

  #pragma unroll
  for (int j = 0; j < 4; ++j) {
    const float4 bj4 = *(const float4*)(biasg + col0 + ns + j*16 + (fg << 2));
    #pragma unroll
    for (int i = 0; i < 4; ++i) {
      const long row = row0 + ms + i*16 + fr;
      const long cb = row * ldc + (long)g * cgoff + col0 + ns + j*16 + (fg << 2);
      const float v0 = acc[i][j][0] + bj4.x, v1 = acc[i][j][1] + bj4.y;
      const float v2 = acc[i][j][2] + bj4.z, v3 = acc[i][j][3] + bj4.w;
      if (Cbf) {
        uint2 pk; pk.x = cvtpk(v0, v1); pk.y = cvtpk(v2, v3);
        *(uint2*)(Cbf + cb) = pk;
      } else {
        f32x4 o = {v0, v1, v2, v3};
        __builtin_nontemporal_store(o, (f32x4*)(Cf + cb));
      }
    }
  }
}

// ---- bf16 MFMA GEMM, 128x64 tile (for low-block-count GEMMs) -----------
__global__ __launch_bounds__(256) void mfma_gemm64_kernel(
    const unsigned short* __restrict__ A, int lda, long agoff,
    const unsigned short* __restrict__ BT, long bgoff, int K,
    const float* __restrict__ bias, int biasoff,
    unsigned short* __restrict__ Cbf, float* __restrict__ Cf,
    int ldc, int cgoff)
{
  const int g = blockIdx.z;
  const unsigned short* Ag = A + (long)g * agoff;
  const unsigned short* Bg = BT + (long)g * bgoff;
  const float* biasg = bias + (long)g * biasoff;
  const int row0 = blockIdx.y * 128, col0 = blockIdx.x * 64;
  __shared__ __align__(16) unsigned short As[128 * 64];
  __shared__ __align__(16) unsigned short Bs[64 * 64];
  const int tid = threadIdx.x;
  const int w = tid >> 6, l = tid & 63;
  const int ms = (w & 1) << 6, ns = (w >> 1) << 5;
  const int fr = l & 15, fg = l >> 4;
  const int lr8 = l >> 3, ls8 = l & 7;
  const int scol = (ls8 ^ lr8) << 3;
  const int rsw = fr & 7;
  f32x4 acc[4][2];
  #pragma unroll
  for (int i = 0; i < 4; ++i)
    #pragma unroll
    for (int j = 0; j < 2; ++j) acc[i][j] = (f32x4)0.0f;

  for (int k0 = 0; k0 < K; k0 += 64) {
    #pragma unroll
    for (int g8 = 0; g8 < 4; ++g8) {
      const int r = (w << 5) + (g8 << 3);
      gload16(Ag + (long)(row0 + r + lr8) * lda + k0 + scol, &As[r * 64]);
    }
    #pragma unroll
    for (int g8 = 0; g8 < 2; ++g8) {
      const int r = (w << 4) + (g8 << 3);
      gload16(Bg + (long)(col0 + r + lr8) * K + k0 + scol, &Bs[r * 64]);
    }
    __syncthreads();
    #pragma unroll
    for (int ks = 0; ks < 2; ++ks) {
      const int rslot = (((ks << 2) + fg) ^ rsw) << 3;
      short8 af[4], bfr[2];
      #pragma unroll
      for (int i = 0; i < 4; ++i)
        af[i] = *(const short8*)&As[(ms + i*16 + fr) * 64 + rslot];
      #pragma unroll
      for (int j = 0; j < 2; ++j)
        bfr[j] = *(const short8*)&Bs[(ns + j*16 + fr) * 64 + rslot];
      #pragma unroll
      for (int i = 0; i < 4; ++i)
        #pragma unroll
        for (int j = 0; j < 2; ++j)
          acc[i][j] = __builtin_amdgcn_mfma_f32_16x16x32_bf16(bfr[j], af[i], acc[i][j], 0, 0, 0);
    }
    __syncthreads();
  }

  #pragma unroll
  for (int j = 0; j < 2; ++j) {
    const float4 bj4 = *(const float4*)(biasg + col0 + ns + j*16 + (fg << 2));
    #pragma unroll
    for (int i = 0; i < 4; ++i) {
      const long row = row0 + ms + i*16 + fr;
      const long cb = row * ldc + (long)g * cgoff + col0 + ns + j*16 + (fg << 2);
      const float v0 = acc[i][j][0] + bj4.x, v1 = acc[i][j][1] + bj4.y;
      const float v2 = acc[i][j][2] + bj4.z, v3 = acc[i][j][3] + bj4.w;
      if (Cbf) {
        uint2 pk; pk.x = cvtpk(v0, v1); pk.y = cvtpk(v2, v3);
        *(uint2*)(Cbf + cb) = pk;
      } else {
        f32x4 o = {v0, v1, v2, v3};
        __builtin_nontemporal_store(o, (f32x4*)(Cf + cb));
      }
    }
  }
}

// ---- grouped dense_in + GLU, 128x64 tile, BK=64 single buffer ----------
__global__ __launch_bounds__(256) void mfma_glu_kernel(
    const unsigned short* __restrict__ A,   // ctx2 [4096][1024]
    const unsigned short* __restrict__ WT,  // [g][2048][256]
    const float* __restrict__ bin,          // [4][2048]
    unsigned short* __restrict__ H2)        // [4096][4096]
{
  const int g = blockIdx.z;
  const unsigned short* Ag = A + g * 256;
  const unsigned short* Wg = WT + (long)g * 2048 * 256;
  const float* bg = bin + g * 2048;
  const int row0 = blockIdx.y * 128, col0 = blockIdx.x * 64;
  __shared__ __align__(16) unsigned short As[128 * 64];
  __shared__ __align__(16) unsigned short Bxs[64 * 64];
  __shared__ __align__(16) unsigned short Bys[64 * 64];
  const int tid = threadIdx.x;
  const int w = tid >> 6, l = tid & 63;
  const int ms = (w & 1) << 6, ns = (w >> 1) << 5;
  const int fr = l & 15, fg = l >> 4;
  const int lr8 = l >> 3, ls8 = l & 7;
  const int scol = (ls8 ^ lr8) << 3;
  const int rsw = fr & 7;
  f32x4 ax[4][2], ay[4][2];
  #pragma unroll
  for (int i = 0; i < 4; ++i)
    #pragma unroll
    for (int j = 0; j < 2; ++j) { ax[i][j] = (f32x4)0.0f; ay[i][j] = (f32x4)0.0f; }

  for (int k0 = 0; k0 < 256; k0 += 64) {
    #pragma unroll
    for (int g8 = 0; g8 < 4; ++g8) {
      const int r = (w << 5) + (g8 << 3);
      gload16(Ag + (long)(row0 + r + lr8) * 1024 + k0 + scol, &As[r * 64]);
    }
    #pragma unroll
    for (int g8 = 0; g8 < 2; ++g8) {
      const int r = (w << 4) + (g8 << 3);
      gload16(Wg + (long)(col0 + r + lr8) * 256 + k0 + scol,          &Bxs[r * 64]);
      gload16(Wg + (long)(1024 + col0 + r + lr8) * 256 + k0 + scol,   &Bys[r * 64]);
    }
    __syncthreads();
    #pragma unroll
    for (int ks = 0; ks < 2; ++ks) {
      const int rslot = (((ks << 2) + fg) ^ rsw) << 3;
      short8 af[4], bx[2], by[2];
      #pragma unroll
      for (int i = 0; i < 4; ++i)
        af[i] = *(const short8*)&As[(ms + i*16 + fr) * 64 + rslot];
      #pragma unroll
      for (int j = 0; j < 2; ++j) {
        bx[j] = *(const short8*)&Bxs[(ns + j*16 + fr) * 64 + rslot];
        by[j] = *(const short8*)&Bys[(ns + j*16 + fr) * 64 + rslot];
      }
      #pragma unroll
      for (int i = 0; i < 4; ++i)
        #pragma unroll
        for (int j = 0; j < 2; ++j) {
          ax[i][j] = __builtin_amdgcn_mfma_f32_16x16x32_bf16(bx[j], af[i], ax[i][j], 0, 0, 0);
          ay[i][j] = __builtin_amdgcn_mfma_f32_16x16x32_bf16(by[j], af[i], ay[i][j], 0, 0, 0);
        }
    }
    __syncthreads();
  }

  #pragma unroll
  for (int j = 0; j < 2; ++j) {
    const float4 bx4 = *(const float4*)(bg + col0 + ns + j*16 + (fg << 2));
    const float4 by4 = *(const float4*)(bg + 1024 + col0 + ns + j*16 + (fg << 2));
    #pragma unroll
    for (int i = 0; i < 4; ++i) {
      const long row = row0 + ms + i*16 + fr;
      const long cb = row * 4096 + g * 1024 + col0 + ns + j*16 + (fg << 2);
      float o4[4];
      const float* bxp = &bx4.x; const float* byp = &by4.x;
      #pragma unroll
      for (int r4 = 0; r4 < 4; ++r4) {
        const float xh = ax[i][j][r4] + bxp[r4];
        const float yh = ay[i][j][r4] + byp[r4];
        o4[r4] = xh * fmaxf(yh, 0.0f);
      }
      uint2 pk; pk.x = cvtpk(o4[0], o4[1]); pk.y = cvtpk(o4[2], o4[3]);
      *(uint2*)(H2 + cb) = pk;
    }
  }
}

// -------- prep: q2/k2 row sums-of-squares + V transpose ------------------
__global__ __launch_bounds__(256) void prep_attn_kernel(
    const unsigned short* __restrict__ qkv,
    float* __restrict__ q2g, float* __restrict__ k2g,
    unsigned short* __restrict__ vt)
{
  const int n = blockIdx.y, s0 = blockIdx.x * 64;
  const int b = n >> 4, hoff = (n & 15) * 64;
  const int tid = threadIdx.x;
  __shared__ unsigned short T[64][72];
  #pragma unroll
  for (int p = 0; p < 2; ++p) {
    const int r = (tid >> 3) + p * 32, c = (tid & 7) << 3;
    *(short8*)&T[r][c] = *(const short8*)(qkv + ((long)((s0 + r) * 4 + b)) * 3072 + 2048 + hoff + c);
  }
  {
    const int r = tid >> 2, e = tid & 3;
    const long base = ((long)((s0 + r) * 4 + b)) * 3072 + hoff + (e << 4);
    float sq = 0.f, sk = 0.f;
    #pragma unroll
    for (int ch = 0; ch < 2; ++ch) {
      short8 q8 = *(const short8*)(qkv + base + (ch << 3));
      short8 k8 = *(const short8*)(qkv + base + 1024 + (ch << 3));
      #pragma unroll
      for (int ee = 0; ee < 8; ++ee) {
        float f = bf2f((unsigned short)q8[ee]); sq = fmaf(f, f, sq);
        f = bf2f((unsigned short)k8[ee]); sk = fmaf(f, f, sk);
      }
    }
    sq += __shfl_xor(sq, 1); sq += __shfl_xor(sq, 2);
    sk += __shfl_xor(sk, 1); sk += __shfl_xor(sk, 2);
    if (e == 0) {
      q2g[n * 1024 + s0 + r] = sq;
      k2g[n * 1024 + s0 + r] = sk;
    }
  }
  __syncthreads();
  #pragma unroll
  for (int p = 0; p < 2; ++p) {
    const int d = (tid >> 3) + p * 32, sc = (tid & 7) << 3;
    short8 o;
    #pragma unroll
    for (int j = 0; j < 8; ++j) o[j] = (short)T[sc + j][d];
    *(short8*)(vt + ((long)n * 64 + d) * 1024 + s0 + sc) = o;
  }
}

// --- MFMA attention + fused residual + per-head LN2 -> ctx2 bf16 ---------
// grid (16 s-tiles, 64 heads).
__global__ __launch_bounds__(256) void attn_kernel(
    const unsigned short* __restrict__ qkv, const unsigned short* __restrict__ vt,
    const float* __restrict__ q2g, const float* __restrict__ k2g,
    const float* __restrict__ xln, const float* __restrict__ g2,
    const float* __restrict__ b2,
    unsigned short* __restrict__ ctx2, float* __restrict__ scores)
{
  const int n = blockIdx.y;
  const int s0 = blockIdx.x * 64;
  const int b = n >> 4, hoff = (n & 15) * 64;
  __shared__ __align__(16) unsigned short Qs[64][72];
  __shared__ __align__(16) unsigned short Ks[2][64 * 64];
  __shared__ __align__(16) unsigned short VTl[2][64 * 64];
  __shared__ __align__(16) unsigned short Ps[64][72];
  const int tid = threadIdx.x, w = tid >> 6, l = tid & 63;
  const int fr = l & 15, fg = l >> 4;
  const int lr8 = l >> 3, ls8 = l & 7;
  const int sslot = ((ls8 ^ lr8) << 3);
  const int rsw = fr & 7;

  #pragma unroll
  for (int p = 0; p < 2; ++p) {
    const int r = (tid >> 3) + p * 32, c = (tid & 7) << 3;
    *(short8*)&Qs[r][c] = *(const short8*)(qkv + ((long)((s0 + r) * 4 + b)) * 3072 + hoff + c);
  }
  float q2m[4];   // per-lane -q2*0.0625 for srow = s0+16i+fr
  #pragma unroll
  for (int i = 0; i < 4; ++i) q2m[i] = -0.0625f * q2g[n * 1024 + s0 + i*16 + fr];

  #pragma unroll
  for (int p = 0; p < 2; ++p) {
    const int rowb = p * 32 + w * 8;
    gload16(qkv + ((long)((rowb + lr8) * 4 + b)) * 3072 + 1024 + hoff + sslot, &Ks[0][rowb * 64]);
    gload16(vt + ((long)n * 64 + rowb + lr8) * 1024 + sslot,                   &VTl[0][rowb * 64]);
  }
  __syncthreads();

  f32x4 o[4];
  #pragma unroll
  for (int i = 0; i < 4; ++i) o[i] = (f32x4)0.0f;

  int cur = 0;
  for (int t0 = 0; t0 < 1024; t0 += 64) {
    if (t0 + 64 < 1024) {
      #pragma unroll
      for (int p = 0; p < 2; ++p) {
        const int rowb = p * 32 + w * 8;
        gload16(qkv + ((long)((t0 + 64 + rowb + lr8) * 4 + b)) * 3072 + 1024 + hoff + sslot,
                &Ks[cur ^ 1][rowb * 64]);
        gload16(vt + ((long)n * 64 + rowb + lr8) * 1024 + t0 + 64 + sslot,
                &VTl[cur ^ 1][rowb * 64]);
      }
    }
    const float4 k2v4 = *(const float4*)(k2g + n * 1024 + t0 + (w << 4) + (fg << 2));
    const float k2m[4] = {-0.0625f*k2v4.x, -0.0625f*k2v4.y, -0.0625f*k2v4.z, -0.0625f*k2v4.w};

    // QK^T swapped: lane: srow = 16i+fr, t = 16w+4fg+r4
    f32x4 c4[4];
    #pragma unroll
    for (int i = 0; i < 4; ++i) c4[i] = (f32x4)0.0f;
    #pragma unroll
    for (int ks = 0; ks < 2; ++ks) {
      const short8 kf = *(const short8*)&Ks[cur][((w << 4) + fr) * 64 + ((((ks << 2) + fg) ^ rsw) << 3)];
      #pragma unroll
      for (int i = 0; i < 4; ++i) {
        const short8 qf = *(const short8*)&Qs[i*16 + fr][(ks << 5) + (fg << 3)];
        c4[i] = __builtin_amdgcn_mfma_f32_16x16x32_bf16(kf, qf, c4[i], 0, 0, 0);
      }
    }
    #pragma unroll
    for (int i = 0; i < 4; ++i) {
      f32x4 sc;
      float pe[4];
      #pragma unroll
      for (int r4 = 0; r4 < 4; ++r4) {
        const float m = fmaf(c4[i][r4], 0.125f, q2m[i] + k2m[r4]);
        sc[r4] = m;
        pe[r4] = __expf(m);
      }
      __builtin_nontemporal_store(sc,
          (f32x4*)(scores + (long)n * 1048576 + (long)(s0 + i*16 + fr) * 1024 + t0 + (w << 4) + (fg << 2)));
      uint2 pk; pk.x = cvtpk(pe[0], pe[1]); pk.y = cvtpk(pe[2], pe[3]);
      *(uint2*)&Ps[i*16 + fr][(w << 4) + (fg << 2)] = pk;
    }
    __syncthreads();

    // PV swapped: lane: srow = 16i+fr, d = 16w+4fg+r4
    #pragma unroll
    for (int ks = 0; ks < 2; ++ks) {
      const short8 vb = *(const short8*)&VTl[cur][((w << 4) + fr) * 64 + ((((ks << 2) + fg) ^ rsw) << 3)];
      #pragma unroll
      for (int i = 0; i < 4; ++i) {
        const short8 pf = *(const short8*)&Ps[i*16 + fr][(ks << 5) + (fg << 3)];
        o[i] = __builtin_amdgcn_mfma_f32_16x16x32_bf16(vb, pf, o[i], 0, 0, 0);
      }
    }
    __syncthreads();
    cur ^= 1;
  }

  // ---- fused residual + per-head LN2 -> ctx2 bf16 ----
  const int dbase = (w << 4) + (fg << 2);
  float4 xl4[4];
  #pragma unroll
  for (int i = 0; i < 4; ++i)
    xl4[i] = *(const float4*)(xln + ((long)((s0 + i*16 + fr) * 4 + b)) * 1024 + hoff + dbase);

  float* redbuf = (float*)&Ps[0][0];   // overlay (Ps dead)
  const int slot = (w << 2) + fg;
  #pragma unroll
  for (int i = 0; i < 4; ++i) {
    float s = 0.f, ss = 0.f;
    const float* xp = &xl4[i].x;
    #pragma unroll
    for (int r4 = 0; r4 < 4; ++r4) {
      const float v = o[i][r4] + xp[r4];
      s += v; ss = fmaf(v, v, ss);
    }
    redbuf[(i*16 + fr) * 16 + slot] = s;
    redbuf[1024 + (i*16 + fr) * 16 + slot] = ss;
  }
  __syncthreads();
  float* statbuf = (float*)&Qs[0][0];  // overlay (Qs dead)
  {
    const int row = tid >> 2, q4 = tid & 3;
    float s = 0.f, ss = 0.f;
    #pragma unroll
    for (int k = 0; k < 4; ++k) {
      s  += redbuf[row * 16 + q4 * 4 + k];
      ss += redbuf[1024 + row * 16 + q4 * 4 + k];
    }
    s  += __shfl_xor(s, 1);  s  += __shfl_xor(s, 2);
    ss += __shfl_xor(ss, 1); ss += __shfl_xor(ss, 2);
    if (q4 == 0) {
      const float mean = s * (1.0f/64.0f);
      const float var  = ss * (1.0f/64.0f) - mean * mean;
      statbuf[row] = mean;
      statbuf[64 + row] = rsqrtf(var + 1e-6f);
    }
  }
  __syncthreads();
  const float4 g2v = *(const float4*)(g2 + dbase);
  const float4 b2v = *(const float4*)(b2 + dbase);
  const float* gp = &g2v.x; const float* bp = &b2v.x;
  #pragma unroll
  for (int i = 0; i < 4; ++i) {
    const float mean = statbuf[i*16 + fr];
    const float rs   = statbuf[64 + i*16 + fr];
    const float* xp = &xl4[i].x;
    float vo[4];
    #pragma unroll
    for (int r4 = 0; r4 < 4; ++r4)
      vo[r4] = (o[i][r4] + xp[r4] - mean) * rs * gp[r4] + bp[r4];
    uint2 pk; pk.x = cvtpk(vo[0], vo[1]); pk.y = cvtpk(vo[2], vo[3]);
    *(uint2*)(ctx2 + ((long)((s0 + i*16 + fr) * 4 + b)) * 1024 + hoff + dbase) = pk;
  }
}

extern "C" void kernel_launch(void* const* d_in, const int* in_sizes, int n_in,
                              void* d_out, int out_size, void* d_ws, size_t ws_size,
                              hipStream_t stream) {
  const float* hs   = (const float*)d_in[0];
  const float* g1   = (const float*)d_in[1];
  const float* b1   = (const float*)d_in[2];
  const float* g2   = (const float*)d_in[3];
  const float* b2   = (const float*)d_in[4];
  const float* Wq   = (const float*)d_in[5];
  const float* bq   = (const float*)d_in[6];
  const float* Wk   = (const float*)d_in[7];
  const float* bk   = (const float*)d_in[8];
  const float* Wv   = (const float*)d_in[9];
  const float* bv   = (const float*)d_in[10];
  const float* Win  = (const float*)d_in[11];
  const float* bin  = (const float*)d_in[12];
  const float* Wout = (const float*)d_in[13];
  const float* bout = (const float*)d_in[14];
  const float* Wd   = (const float*)d_in[15];
  const float* bd   = (const float*)d_in[16];

  // ws layout (bytes), ~99 MB total. Overlays: h2 over xbf+qkv, og over xln.
  char* ws = (char*)d_ws;
  float*          xln   = (float*)(ws + 0);                 // [4096][1024] f32
  unsigned short* xbf   = (unsigned short*)(ws + 16777216); // [4096][1024] bf16
  unsigned short* qkv   = (unsigned short*)(ws + 25165824); // [4096][3072] bf16
  unsigned short* ctx2  = (unsigned short*)(ws + 67108864); // [4096][1024] bf16
  unsigned short* wqkvT = (unsigned short*)(ws + 75497472); // [3072][1024] bf16
  unsigned short* winT  = (unsigned short*)(ws + 81788928); // [4][2048][256]
  unsigned short* woutT = (unsigned short*)(ws + 85983232); // [4][256][1024]
  unsigned short* wdT   = (unsigned short*)(ws + 88080384); // [1024][1024]
  float*          qkvb  = (float*)(ws + 90177536);          // [3072] f32
  unsigned short* vt    = (unsigned short*)(ws + 90189824); // [64][64][1024] bf16
  float*          q2g   = (float*)(ws + 98578432);          // [64][1024] f32
  float*          k2g   = (float*)(ws + 98840576);          // [64][1024] f32
  unsigned short* h2    = (unsigned short*)(ws + 16777216); // [4096][4096] bf16
  unsigned short* og    = (unsigned short*)(ws + 0);        // [4096][1024] bf16

  float* out0 = (float*)d_out;           // [S,B,H]
  float* out1 = out0 + 4194304;          // [64,1024,1024]

  ln1_kernel<<<4096, 256, 0, stream>>>(hs, g1, b1, xln, xbf);

  prep_weights_kernel<<<7180, 256, 0, stream>>>(
      Wq, Wk, Wv, Wd, Win, Wout, bq, bk, bv, wqkvT, wdT, winT, woutT, qkvb);

  // QKV: [4096,1024]@[1024,3072] -> qkv bf16
  mfma_gemm_kernel<<<dim3(24,32,1), 256, 0, stream>>>(
      xbf, 1024, 0, wqkvT, 0, 1024, qkvb, 0, qkv, nullptr, 3072, 0);

  prep_attn_kernel<<<dim3(16,64), 256, 0, stream>>>(qkv, q2g, k2g, vt);

  attn_kernel<<<dim3(16,64), 256, 0, stream>>>(qkv, vt, q2g, k2g, xln, g2, b2, ctx2, out1);

  mfma_glu_kernel<<<dim3(16,32,4), 256, 0, stream>>>(ctx2, winT, bin, h2);

  // FFN-out: per group [4096,4096sub1024]@[1024,256] -> og bf16 (2 blocks/CU)
  mfma_gemm64_kernel<<<dim3(4,32,4), 256, 0, stream>>>(
      h2, 4096, 1024, woutT, 262144, 1024, bout, 256, og, nullptr, 1024, 256);

  // dense: [4096,1024]@[1024,1024] -> out0 fp32 (2 blocks/CU, NT store)
  mfma_gemm64_kernel<<<dim3(16,32,1), 256, 0, stream>>>(
      og, 1024, 0, wdT, 0, 1024, bd, 0, nullptr, out0, 1024, 0);
}

// Round 12
// 243.826 us; speedup vs baseline: 1.1171x; 1.0109x over previous
//
#include <hip/hip_runtime.h>

// TransformerLayer_Combined on gfx950 — bf16 MFMA pipeline.
// GEMMs: depth-2 software pipeline with COUNTED vmcnt + raw s_barrier
// (T3/T4: loads stay in flight across barriers, hidden under MFMA).
// attn with fused residual+LN2. Outputs fp32.

typedef __attribute__((ext_vector_type(8))) short short8;
typedef __attribute__((ext_vector_type(4))) float f32x4;

__device__ __forceinline__ unsigned short f2bf(float f) {
  union { float f; unsigned u; } x; x.f = f;
  unsigned r = x.u + 0x7FFFu + ((x.u >> 16) & 1u);
  return (unsigned short)(r >> 16);
}
__device__ __forceinline__ float bf2f(unsigned short u) {
  union { float f; unsigned u; } x; x.u = ((unsigned)u) << 16;
  return x.f;
}
__device__ __forceinline__ unsigned cvtpk(float a, float b) {  // [lo=a, hi=b]
  unsigned r;
  asm("v_cvt_pk_bf16_f32 %0, %1, %2" : "=v"(r) : "v"(a), "v"(b));
  return r;
}
// async 16B global->LDS (dest = wave-uniform base + lane*16)
__device__ __forceinline__ void gload16(const unsigned short* g, unsigned short* l) {
  __builtin_amdgcn_global_load_lds(
      (const __attribute__((address_space(1))) unsigned int*)g,
      (__attribute__((address_space(3))) unsigned int*)l, 16, 0, 0);
}

// ---------------- LN1 over H=1024: fp32 (residual) + bf16 (GEMM A) --------
__global__ __launch_bounds__(256) void ln1_kernel(
    const float* __restrict__ x, const float* __restrict__ g,
    const float* __restrict__ b, float* __restrict__ y,
    unsigned short* __restrict__ ybf)
{
  const long base = (long)blockIdx.x * 1024;
  const int c = threadIdx.x * 4;
  float4 v = *(const float4*)(x + base + c);
  float s = v.x + v.y + v.z + v.w;
  float ss = v.x*v.x + v.y*v.y + v.z*v.z + v.w*v.w;
  #pragma unroll
  for (int off = 32; off > 0; off >>= 1) {
    s  += __shfl_xor(s, off);
    ss += __shfl_xor(ss, off);
  }
  __shared__ float sw[4], ssw[4];
  const int wave = threadIdx.x >> 6;
  if ((threadIdx.x & 63) == 0) { sw[wave] = s; ssw[wave] = ss; }
  __syncthreads();
  s  = sw[0] + sw[1] + sw[2] + sw[3];
  ss = ssw[0] + ssw[1] + ssw[2] + ssw[3];
  const float mean = s * (1.0f/1024.0f);
  const float var  = ss * (1.0f/1024.0f) - mean*mean;
  const float rs   = rsqrtf(var + 1e-6f);
  const float4 gv = *(const float4*)(g + c);
  const float4 bv = *(const float4*)(b + c);
  float4 o;
  o.x = (v.x - mean) * rs * gv.x + bv.x;
  o.y = (v.y - mean) * rs * gv.y + bv.y;
  o.z = (v.z - mean) * rs * gv.z + bv.z;
  o.w = (v.w - mean) * rs * gv.w + bv.w;
  *(float4*)(y + base + c) = o;
  ushort4 ob;
  ob.x = f2bf(o.x); ob.y = f2bf(o.y); ob.z = f2bf(o.z); ob.w = f2bf(o.w);
  *(ushort4*)(ybf + base + c) = ob;
}

// ---- merged weight prep: all transposes + bias pack in one launch --------
__device__ __forceinline__ void transpose_body(
    const float* __restrict__ Wg, unsigned short* __restrict__ WTg,
    int K, int N, int bx, int by, int tid)
{
  __shared__ float T[32][33];
  const int n0 = bx * 32, k0 = by * 32;
  const int r = tid >> 3, c4 = (tid & 7) * 4;
  float4 v = *(const float4*)(Wg + (long)(k0 + r) * N + n0 + c4);
  T[r][c4+0] = v.x; T[r][c4+1] = v.y; T[r][c4+2] = v.z; T[r][c4+3] = v.w;
  __syncthreads();
  ushort4 o;
  o.x = f2bf(T[c4+0][r]); o.y = f2bf(T[c4+1][r]);
  o.z = f2bf(T[c4+2][r]); o.w = f2bf(T[c4+3][r]);
  *(ushort4*)(WTg + (long)(n0 + r) * K + k0 + c4) = o;
}

__global__ __launch_bounds__(256) void prep_weights_kernel(
    const float* __restrict__ Wq, const float* __restrict__ Wk,
    const float* __restrict__ Wv, const float* __restrict__ Wd,
    const float* __restrict__ Win, const float* __restrict__ Wout,
    const float* __restrict__ bq, const float* __restrict__ bk,
    const float* __restrict__ bv,
    unsigned short* __restrict__ wqkvT, unsigned short* __restrict__ wdT,
    unsigned short* __restrict__ winT, unsigned short* __restrict__ woutT,
    float* __restrict__ qkvb)
{
  const int idx = blockIdx.x;
  const int tid = threadIdx.x;
  if (idx < 4096) {               // Wq/Wk/Wv/Wd 1024x1024
    const int z = idx >> 10, rem = idx & 1023;
    const float* W = (z == 0) ? Wq : (z == 1) ? Wk : (z == 2) ? Wv : Wd;
    unsigned short* WT = (z == 3) ? wdT : wqkvT + (long)z * 1048576;
    transpose_body(W, WT, 1024, 1024, rem & 31, rem >> 5, tid);
  } else if (idx < 6144) {        // Win [4][256][2048]
    const int rem = idx - 4096;
    const int z = rem >> 9, r2 = rem & 511;
    transpose_body(Win + (long)z * 524288, winT + (long)z * 524288,
                   256, 2048, r2 & 63, r2 >> 6, tid);
  } else if (idx < 7168) {        // Wout [4][1024][256]
    const int rem = idx - 6144;
    const int z = rem >> 8, r2 = rem & 255;
    transpose_body(Wout + (long)z * 262144, woutT + (long)z * 262144,
                   1024, 256, r2 & 7, r2 >> 3, tid);
  } else {                        // packb (12 blocks x 256)
    const int i = (idx - 7168) * 256 + tid;
    qkvb[i] = (i < 1024) ? bq[i] : ((i < 2048) ? bk[i - 1024] : bv[i - 2048]);
  }
}

// ---- bf16 MFMA GEMM, 128x128 tile, depth-2 counted-vmcnt pipeline ------
// LDS [buf][row][64 shorts]; slot s of row r stored at s^(r&7).
// Per-wave stage = 8 gload16 (4 A + 4 B). Steady-state vmcnt(8).
__global__ __launch_bounds__(256) void mfma_gemm_kernel(
    const unsigned short* __restrict__ A, int lda, long agoff,
    const unsigned short* __restrict__ BT, long bgoff, int K,
    const float* __restrict__ bias, int biasoff,
    unsigned short* __restrict__ Cbf, float* __restrict__ Cf,
    int ldc, int cgoff)
{
  const int g = blockIdx.z;
  const unsigned short* Ag = A + (long)g * agoff;
  const unsigned short* Bg = BT + (long)g * bgoff;
  const float* biasg = bias + (long)g * biasoff;
  const int row0 = blockIdx.y * 128, col0 = blockIdx.x * 128;
  __shared__ __align__(16) unsigned short As[2][128 * 64];
  __shared__ __align__(16) unsigned short Bs[2][128 * 64];
  const int tid = threadIdx.x;
  const int w = tid >> 6, l = tid & 63;
  const int ms = (w & 1) << 6, ns = (w >> 1) << 6;
  const int fr = l & 15, fg = l >> 4;
  const int lr8 = l >> 3, ls8 = l & 7;
  const int scol = (ls8 ^ lr8) << 3;
  const int rsw = fr & 7;
  f32x4 acc[4][4];
  #pragma unroll
  for (int i = 0; i < 4; ++i)
    #pragma unroll
    for (int j = 0; j < 4; ++j) acc[i][j] = (f32x4)0.0f;

  const int nt = K >> 6;   // requires K >= 128
  #pragma unroll
  for (int sidx = 0; sidx < 2; ++sidx) {   // stage tiles 0,1
    const int k0 = sidx << 6;
    #pragma unroll
    for (int g8 = 0; g8 < 4; ++g8) {
      const int r = (w << 5) + (g8 << 3);
      gload16(Ag + (long)(row0 + r + lr8) * lda + k0 + scol, &As[sidx][r * 64]);
      gload16(Bg + (long)(col0 + r + lr8) * K  + k0 + scol, &Bs[sidx][r * 64]);
    }
  }
  int cur = 0;
  for (int t = 0; t < nt; ++t) {
    if (t + 1 < nt) asm volatile("s_waitcnt vmcnt(8)" ::: "memory");
    else            asm volatile("s_waitcnt vmcnt(0)" ::: "memory");
    __builtin_amdgcn_s_barrier();
    __builtin_amdgcn_sched_barrier(0);
    short8 af[2][4], bfr[2][4];
    #pragma unroll
    for (int ks = 0; ks < 2; ++ks) {
      const int rslot = (((ks << 2) + fg) ^ rsw) << 3;
      #pragma unroll
      for (int i = 0; i < 4; ++i) {
        af[ks][i]  = *(const short8*)&As[cur][(ms + i*16 + fr) * 64 + rslot];
        bfr[ks][i] = *(const short8*)&Bs[cur][(ns + i*16 + fr) * 64 + rslot];
      }
    }
    asm volatile("s_waitcnt lgkmcnt(0)" ::: "memory");
    __builtin_amdgcn_sched_barrier(0);
    __builtin_amdgcn_s_barrier();       // all waves done reading buf[cur]
    if (t + 2 < nt) {                   // refill buf[cur] for tile t+2
      const int k0 = (t + 2) << 6;
      #pragma unroll
      for (int g8 = 0; g8 < 4; ++g8) {
        const int r = (w << 5) + (g8 << 3);
        gload16(Ag + (long)(row0 + r + lr8) * lda + k0 + scol, &As[cur][r * 64]);
        gload16(Bg + (long)(col0 + r + lr8) * K  + k0 + scol, &Bs[cur][r * 64]);
      }
    }
    __builtin_amdgcn_s_setprio(1);
    #pragma unroll
    for (int ks = 0; ks < 2; ++ks)
      #pragma unroll
      for (int i = 0; i < 4; ++i)
        #pragma unroll
        for (int j = 0; j < 4; ++j)
          acc[i][j] = __builtin_amdgcn_mfma_f32_16x16x32_bf16(bfr[ks][j], af[ks][i], acc[i][j], 0, 0, 0);
    __builtin_amdgcn_s_setprio(0);
    cur ^= 1;
  }

  #pragma unroll
  for (int j = 0; j < 4; ++j) {
    const float4 bj4 = *(const float4*)(biasg + col0 + ns + j*16 + (fg << 2));
    #pragma unroll
    for (int i = 0; i < 4; ++i) {
      const long row = row0 + ms + i*16 + fr;
      const long cb = row * ldc + (long)g * cgoff + col0 + ns + j*16 + (fg << 2);
      const float v0 = acc[i][j][0] + bj4.x, v1 = acc[i][j][1] + bj4.y;
      const float v2 = acc[i][j][2] + bj4.z, v3 = acc[i][j][3] + bj4.w;
      if (Cbf) {
        uint2 pk; pk.x = cvtpk(v0, v1); pk.y = cvtpk(v2, v3);
        *(uint2*)(Cbf + cb) = pk;
      } else {
        f32x4 o = {v0, v1, v2, v3};
        __builtin_nontemporal_store(o, (f32x4*)(Cf + cb));
      }
    }
  }
}

// ---- bf16 MFMA GEMM, 128x64 tile, depth-2 pipeline (stage = 6 loads) ----
__global__ __launch_bounds__(256) void mfma_gemm64_kernel(
    const unsigned short* __restrict__ A, int lda, long agoff,
    const unsigned short* __restrict__ BT, long bgoff, int K,
    const float* __restrict__ bias, int biasoff,
    unsigned short* __restrict__ Cbf, float* __restrict__ Cf,
    int ldc, int cgoff)
{
  const int g = blockIdx.z;
  const unsigned short* Ag = A + (long)g * agoff;
  const unsigned short* Bg = BT + (long)g * bgoff;
  const float* biasg = bias + (long)g * biasoff;
  const int row0 = blockIdx.y * 128, col0 = blockIdx.x * 64;
  __shared__ __align__(16) unsigned short As[2][128 * 64];
  __shared__ __align__(16) unsigned short Bs[2][64 * 64];
  const int tid = threadIdx.x;
  const int w = tid >> 6, l = tid & 63;
  const int ms = (w & 1) << 6, ns = (w >> 1) << 5;
  const int fr = l & 15, fg = l >> 4;
  const int lr8 = l >> 3, ls8 = l & 7;
  const int scol = (ls8 ^ lr8) << 3;
  const int rsw = fr & 7;
  f32x4 acc[4][2];
  #pragma unroll
  for (int i = 0; i < 4; ++i)
    #pragma unroll
    for (int j = 0; j < 2; ++j) acc[i][j] = (f32x4)0.0f;

  const int nt = K >> 6;
  #pragma unroll
  for (int sidx = 0; sidx < 2; ++sidx) {
    const int k0 = sidx << 6;
    #pragma unroll
    for (int g8 = 0; g8 < 4; ++g8) {
      const int r = (w << 5) + (g8 << 3);
      gload16(Ag + (long)(row0 + r + lr8) * lda + k0 + scol, &As[sidx][r * 64]);
    }
    #pragma unroll
    for (int g8 = 0; g8 < 2; ++g8) {
      const int r = (w << 4) + (g8 << 3);
      gload16(Bg + (long)(col0 + r + lr8) * K + k0 + scol, &Bs[sidx][r * 64]);
    }
  }
  int cur = 0;
  for (int t = 0; t < nt; ++t) {
    if (t + 1 < nt) asm volatile("s_waitcnt vmcnt(6)" ::: "memory");
    else            asm volatile("s_waitcnt vmcnt(0)" ::: "memory");
    __builtin_amdgcn_s_barrier();
    __builtin_amdgcn_sched_barrier(0);
    short8 af[2][4], bfr[2][2];
    #pragma unroll
    for (int ks = 0; ks < 2; ++ks) {
      const int rslot = (((ks << 2) + fg) ^ rsw) << 3;
      #pragma unroll
      for (int i = 0; i < 4; ++i)
        af[ks][i] = *(const short8*)&As[cur][(ms + i*16 + fr) * 64 + rslot];
      #pragma unroll
      for (int j = 0; j < 2; ++j)
        bfr[ks][j] = *(const short8*)&Bs[cur][(ns + j*16 + fr) * 64 + rslot];
    }
    asm volatile("s_waitcnt lgkmcnt(0)" ::: "memory");
    __builtin_amdgcn_sched_barrier(0);
    __builtin_amdgcn_s_barrier();
    if (t + 2 < nt) {
      const int k0 = (t + 2) << 6;
      #pragma unroll
      for (int g8 = 0; g8 < 4; ++g8) {
        const int r = (w << 5) + (g8 << 3);
        gload16(Ag + (long)(row0 + r + lr8) * lda + k0 + scol, &As[cur][r * 64]);
      }
      #pragma unroll
      for (int g8 = 0; g8 < 2; ++g8) {
        const int r = (w << 4) + (g8 << 3);
        gload16(Bg + (long)(col0 + r + lr8) * K + k0 + scol, &Bs[cur][r * 64]);
      }
    }
    __builtin_amdgcn_s_setprio(1);
    #pragma unroll
    for (int ks = 0; ks < 2; ++ks)
      #pragma unroll
      for (int i = 0; i < 4; ++i)
        #pragma unroll
        for (int j = 0; j < 2; ++j)
          acc[i][j] = __builtin_amdgcn_mfma_f32_16x16x32_bf16(bfr[ks][j], af[ks][i], acc[i][j], 0, 0, 0);
    __builtin_amdgcn_s_setprio(0);
    cur ^= 1;
  }

  #pragma unroll
  for (int j = 0; j < 2; ++j) {
    const float4 bj4 = *(const float4*)(biasg + col0 + ns + j*16 + (fg << 2));
    #pragma unroll
    for (int i = 0; i < 4; ++i) {
      const long row = row0 + ms + i*16 + fr;
      const long cb = row * ldc + (long)g * cgoff + col0 + ns + j*16 + (fg << 2);
      const float v0 = acc[i][j][0] + bj4.x, v1 = acc[i][j][1] + bj4.y;
      const float v2 = acc[i][j][2] + bj4.z, v3 = acc[i][j][3] + bj4.w;
      if (Cbf) {
        uint2 pk; pk.x = cvtpk(v0, v1); pk.y = cvtpk(v2, v3);
        *(uint2*)(Cbf + cb) = pk;
      } else {
        f32x4 o = {v0, v1, v2, v3};
        __builtin_nontemporal_store(o, (f32x4*)(Cf + cb));
      }
    }
  }
}

// ---- grouped dense_in + GLU, 128x64 tile, depth-2 pipeline (stage=8) ----
__global__ __launch_bounds__(256) void mfma_glu_kernel(
    const unsigned short* __restrict__ A,   // ctx2 [4096][1024]
    const unsigned short* __restrict__ WT,  // [g][2048][256]
    const float* __restrict__ bin,          // [4][2048]
    unsigned short* __restrict__ H2)        // [4096][4096]
{
  const int g = blockIdx.z;
  const unsigned short* Ag = A + g * 256;
  const unsigned short* Wg = WT + (long)g * 2048 * 256;
  const float* bg = bin + g * 2048;
  const int row0 = blockIdx.y * 128, col0 = blockIdx.x * 64;
  __shared__ __align__(16) unsigned short As[2][128 * 64];
  __shared__ __align__(16) unsigned short Bxs[2][64 * 64];
  __shared__ __align__(16) unsigned short Bys[2][64 * 64];
  const int tid = threadIdx.x;
  const int w = tid >> 6, l = tid & 63;
  const int ms = (w & 1) << 6, ns = (w >> 1) << 5;
  const int fr = l & 15, fg = l >> 4;
  const int lr8 = l >> 3, ls8 = l & 7;
  const int scol = (ls8 ^ lr8) << 3;
  const int rsw = fr & 7;
  f32x4 ax[4][2], ay[4][2];
  #pragma unroll
  for (int i = 0; i < 4; ++i)
    #pragma unroll
    for (int j = 0; j < 2; ++j) { ax[i][j] = (f32x4)0.0f; ay[i][j] = (f32x4)0.0f; }

  #pragma unroll
  for (int sidx = 0; sidx < 2; ++sidx) {   // K=256 -> nt=4 >= 2
    const int k0 = sidx << 6;
    #pragma unroll
    for (int g8 = 0; g8 < 4; ++g8) {
      const int r = (w << 5) + (g8 << 3);
      gload16(Ag + (long)(row0 + r + lr8) * 1024 + k0 + scol, &As[sidx][r * 64]);
    }
    #pragma unroll
    for (int g8 = 0; g8 < 2; ++g8) {
      const int r = (w << 4) + (g8 << 3);
      gload16(Wg + (long)(col0 + r + lr8) * 256 + k0 + scol,        &Bxs[sidx][r * 64]);
      gload16(Wg + (long)(1024 + col0 + r + lr8) * 256 + k0 + scol, &Bys[sidx][r * 64]);
    }
  }
  int cur = 0;
  for (int t = 0; t < 4; ++t) {
    if (t + 1 < 4) asm volatile("s_waitcnt vmcnt(8)" ::: "memory");
    else           asm volatile("s_waitcnt vmcnt(0)" ::: "memory");
    __builtin_amdgcn_s_barrier();
    __builtin_amdgcn_sched_barrier(0);
    short8 af[2][4], bx[2][2], by[2][2];
    #pragma unroll
    for (int ks = 0; ks < 2; ++ks) {
      const int rslot = (((ks << 2) + fg) ^ rsw) << 3;
      #pragma unroll
      for (int i = 0; i < 4; ++i)
        af[ks][i] = *(const short8*)&As[cur][(ms + i*16 + fr) * 64 + rslot];
      #pragma unroll
      for (int j = 0; j < 2; ++j) {
        bx[ks][j] = *(const short8*)&Bxs[cur][(ns + j*16 + fr) * 64 + rslot];
        by[ks][j] = *(const short8*)&Bys[cur][(ns + j*16 + fr) * 64 + rslot];
      }
    }
    asm volatile("s_waitcnt lgkmcnt(0)" ::: "memory");
    __builtin_amdgcn_sched_barrier(0);
    __builtin_amdgcn_s_barrier();
    if (t + 2 < 4) {
      const int k0 = (t + 2) << 6;
      #pragma unroll
      for (int g8 = 0; g8 < 4; ++g8) {
        const int r = (w << 5) + (g8 << 3);
        gload16(Ag + (long)(row0 + r + lr8) * 1024 + k0 + scol, &As[cur][r * 64]);
      }
      #pragma unroll
      for (int g8 = 0; g8 < 2; ++g8) {
        const int r = (w << 4) + (g8 << 3);
        gload16(Wg + (long)(col0 + r + lr8) * 256 + k0 + scol,        &Bxs[cur][r * 64]);
        gload16(Wg + (long)(1024 + col0 + r + lr8) * 256 + k0 + scol, &Bys[cur][r * 64]);
      }
    }
    __builtin_amdgcn_s_setprio(1);
    #pragma unroll
    for (int ks = 0; ks < 2; ++ks)
      #pragma unroll
      for (int i = 0; i < 4; ++i)
        #pragma unroll
        for (int j = 0; j < 2; ++j) {
          ax[i][j] = __builtin_amdgcn_mfma_f32_16x16x32_bf16(bx[ks][j], af[ks][i], ax[i][j], 0, 0, 0);
          ay[i][j] = __builtin_amdgcn_mfma_f32_16x16x32_bf16(by[ks][j], af[ks][i], ay[i][j], 0, 0, 0);
        }
    __builtin_amdgcn_s_setprio(0);
    cur ^= 1;
  }

  #pragma unroll
  for (int j = 0; j < 2; ++j) {
    const float4 bx4 = *(const float4*)(bg + col0 + ns + j*16 + (fg << 2));
    const float4 by4 = *(const float4*)(bg + 1024 + col0 + ns + j*16 + (fg << 2));
    #pragma unroll
    for (int i = 0; i < 4; ++i) {
      const long row = row0 + ms + i*16 + fr;
      const long cb = row * 4096 + g * 1024 + col0 + ns + j*16 + (fg << 2);
      float o4[4];
      const float* bxp = &bx4.x; const float* byp = &by4.x;
      #pragma unroll
      for (int r4 = 0; r4 < 4; ++r4) {
        const float xh = ax[i][j][r4] + bxp[r4];
        const float yh = ay[i][j][r4] + byp[r4];
        o4[r4] = xh * fmaxf(yh, 0.0f);
      }
      uint2 pk; pk.x = cvtpk(o4[0], o4[1]); pk.y = cvtpk(o4[2], o4[3]);
      *(uint2*)(H2 + cb) = pk;
    }
  }
}

// -------- prep: q2/k2 row sums-of-squares + V transpose ------------------
__global__ __launch_bounds__(256) void prep_attn_kernel(
    const unsigned short* __restrict__ qkv,
    float* __restrict__ q2g, float* __restrict__ k2g,
    unsigned short* __restrict__ vt)
{
  const int n = blockIdx.y, s0 = blockIdx.x * 64;
  const int b = n >> 4, hoff = (n & 15) * 64;
  const int tid = threadIdx.x;
  __shared__ unsigned short T[64][72];
  #pragma unroll
  for (int p = 0; p < 2; ++p) {
    const int r = (tid >> 3) + p * 32, c = (tid & 7) << 3;
    *(short8*)&T[r][c] = *(const short8*)(qkv + ((long)((s0 + r) * 4 + b)) * 3072 + 2048 + hoff + c);
  }
  {
    const int r = tid >> 2, e = tid & 3;
    const long base = ((long)((s0 + r) * 4 + b)) * 3072 + hoff + (e << 4);
    float sq = 0.f, sk = 0.f;
    #pragma unroll
    for (int ch = 0; ch < 2; ++ch) {
      short8 q8 = *(const short8*)(qkv + base + (ch << 3));
      short8 k8 = *(const short8*)(qkv + base + 1024 + (ch << 3));
      #pragma unroll
      for (int ee = 0; ee < 8; ++ee) {
        float f = bf2f((unsigned short)q8[ee]); sq = fmaf(f, f, sq);
        f = bf2f((unsigned short)k8[ee]); sk = fmaf(f, f, sk);
      }
    }
    sq += __shfl_xor(sq, 1); sq += __shfl_xor(sq, 2);
    sk += __shfl_xor(sk, 1); sk += __shfl_xor(sk, 2);
    if (e == 0) {
      q2g[n * 1024 + s0 + r] = sq;
      k2g[n * 1024 + s0 + r] = sk;
    }
  }
  __syncthreads();
  #pragma unroll
  for (int p = 0; p < 2; ++p) {
    const int d = (tid >> 3) + p * 32, sc = (tid & 7) << 3;
    short8 o;
    #pragma unroll
    for (int j = 0; j < 8; ++j) o[j] = (short)T[sc + j][d];
    *(short8*)(vt + ((long)n * 64 + d) * 1024 + s0 + sc) = o;
  }
}

// --- MFMA attention + fused residual + per-head LN2 -> ctx2 bf16 ---------
// grid (16 s-tiles, 64 heads).
__global__ __launch_bounds__(256) void attn_kernel(
    const unsigned short* __restrict__ qkv, const unsigned short* __restrict__ vt,
    const float* __restrict__ q2g, const float* __restrict__ k2g,
    const float* __restrict__ xln, const float* __restrict__ g2,
    const float* __restrict__ b2,
    unsigned short* __restrict__ ctx2, float* __restrict__ scores)
{
  const int n = blockIdx.y;
  const int s0 = blockIdx.x * 64;
  const int b = n >> 4, hoff = (n & 15) * 64;
  __shared__ __align__(16) unsigned short Qs[64][72];
  __shared__ __align__(16) unsigned short Ks[2][64 * 64];
  __shared__ __align__(16) unsigned short VTl[2][64 * 64];
  __shared__ __align__(16) unsigned short Ps[64][72];
  const int tid = threadIdx.x, w = tid >> 6, l = tid & 63;
  const int fr = l & 15, fg = l >> 4;
  const int lr8 = l >> 3, ls8 = l & 7;
  const int sslot = ((ls8 ^ lr8) << 3);
  const int rsw = fr & 7;

  #pragma unroll
  for (int p = 0; p < 2; ++p) {
    const int r = (tid >> 3) + p * 32, c = (tid & 7) << 3;
    *(short8*)&Qs[r][c] = *(const short8*)(qkv + ((long)((s0 + r) * 4 + b)) * 3072 + hoff + c);
  }
  float q2m[4];   // per-lane -q2*0.0625 for srow = s0+16i+fr
  #pragma unroll
  for (int i = 0; i < 4; ++i) q2m[i] = -0.0625f * q2g[n * 1024 + s0 + i*16 + fr];

  #pragma unroll
  for (int p = 0; p < 2; ++p) {
    const int rowb = p * 32 + w * 8;
    gload16(qkv + ((long)((rowb + lr8) * 4 + b)) * 3072 + 1024 + hoff + sslot, &Ks[0][rowb * 64]);
    gload16(vt + ((long)n * 64 + rowb + lr8) * 1024 + sslot,                   &VTl[0][rowb * 64]);
  }
  __syncthreads();

  f32x4 o[4];
  #pragma unroll
  for (int i = 0; i < 4; ++i) o[i] = (f32x4)0.0f;

  int cur = 0;
  for (int t0 = 0; t0 < 1024; t0 += 64) {
    if (t0 + 64 < 1024) {
      #pragma unroll
      for (int p = 0; p < 2; ++p) {
        const int rowb = p * 32 + w * 8;
        gload16(qkv + ((long)((t0 + 64 + rowb + lr8) * 4 + b)) * 3072 + 1024 + hoff + sslot,
                &Ks[cur ^ 1][rowb * 64]);
        gload16(vt + ((long)n * 64 + rowb + lr8) * 1024 + t0 + 64 + sslot,
                &VTl[cur ^ 1][rowb * 64]);
      }
    }
    const float4 k2v4 = *(const float4*)(k2g + n * 1024 + t0 + (w << 4) + (fg << 2));
    const float k2m[4] = {-0.0625f*k2v4.x, -0.0625f*k2v4.y, -0.0625f*k2v4.z, -0.0625f*k2v4.w};

    // QK^T swapped: lane: srow = 16i+fr, t = 16w+4fg+r4
    f32x4 c4[4];
    #pragma unroll
    for (int i = 0; i < 4; ++i) c4[i] = (f32x4)0.0f;
    #pragma unroll
    for (int ks = 0; ks < 2; ++ks) {
      const short8 kf = *(const short8*)&Ks[cur][((w << 4) + fr) * 64 + ((((ks << 2) + fg) ^ rsw) << 3)];
      #pragma unroll
      for (int i = 0; i < 4; ++i) {
        const short8 qf = *(const short8*)&Qs[i*16 + fr][(ks << 5) + (fg << 3)];
        c4[i] = __builtin_amdgcn_mfma_f32_16x16x32_bf16(kf, qf, c4[i], 0, 0, 0);
      }
    }
    #pragma unroll
    for (int i = 0; i < 4; ++i) {
      f32x4 sc;
      float pe[4];
      #pragma unroll
      for (int r4 = 0; r4 < 4; ++r4) {
        const float m = fmaf(c4[i][r4], 0.125f, q2m[i] + k2m[r4]);
        sc[r4] = m;
        pe[r4] = __expf(m);
      }
      __builtin_nontemporal_store(sc,
          (f32x4*)(scores + (long)n * 1048576 + (long)(s0 + i*16 + fr) * 1024 + t0 + (w << 4) + (fg << 2)));
      uint2 pk; pk.x = cvtpk(pe[0], pe[1]); pk.y = cvtpk(pe[2], pe[3]);
      *(uint2*)&Ps[i*16 + fr][(w << 4) + (fg << 2)] = pk;
    }
    __syncthreads();

    // PV swapped: lane: srow = 16i+fr, d = 16w+4fg+r4
    #pragma unroll
    for (int ks = 0; ks < 2; ++ks) {
      const short8 vb = *(const short8*)&VTl[cur][((w << 4) + fr) * 64 + ((((ks << 2) + fg) ^ rsw) << 3)];
      #pragma unroll
      for (int i = 0; i < 4; ++i) {
        const short8 pf = *(const short8*)&Ps[i*16 + fr][(ks << 5) + (fg << 3)];
        o[i] = __builtin_amdgcn_mfma_f32_16x16x32_bf16(vb, pf, o[i], 0, 0, 0);
      }
    }
    __syncthreads();
    cur ^= 1;
  }

  // ---- fused residual + per-head LN2 -> ctx2 bf16 ----
  const int dbase = (w << 4) + (fg << 2);
  float4 xl4[4];
  #pragma unroll
  for (int i = 0; i < 4; ++i)
    xl4[i] = *(const float4*)(xln + ((long)((s0 + i*16 + fr) * 4 + b)) * 1024 + hoff + dbase);

  float* redbuf = (float*)&Ps[0][0];   // overlay (Ps dead)
  const int slot = (w << 2) + fg;
  #pragma unroll
  for (int i = 0; i < 4; ++i) {
    float s = 0.f, ss = 0.f;
    const float* xp = &xl4[i].x;
    #pragma unroll
    for (int r4 = 0; r4 < 4; ++r4) {
      const float v = o[i][r4] + xp[r4];
      s += v; ss = fmaf(v, v, ss);
    }
    redbuf[(i*16 + fr) * 16 + slot] = s;
    redbuf[1024 + (i*16 + fr) * 16 + slot] = ss;
  }
  __syncthreads();
  float* statbuf = (float*)&Qs[0][0];  // overlay (Qs dead)
  {
    const int row = tid >> 2, q4 = tid & 3;
    float s = 0.f, ss = 0.f;
    #pragma unroll
    for (int k = 0; k < 4; ++k) {
      s  += redbuf[row * 16 + q4 * 4 + k];
      ss += redbuf[1024 + row * 16 + q4 * 4 + k];
    }
    s  += __shfl_xor(s, 1);  s  += __shfl_xor(s, 2);
    ss += __shfl_xor(ss, 1); ss += __shfl_xor(ss, 2);
    if (q4 == 0) {
      const float mean = s * (1.0f/64.0f);
      const float var  = ss * (1.0f/64.0f) - mean * mean;
      statbuf[row] = mean;
      statbuf[64 + row] = rsqrtf(var + 1e-6f);
    }
  }
  __syncthreads();
  const float4 g2v = *(const float4*)(g2 + dbase);
  const float4 b2v = *(const float4*)(b2 + dbase);
  const float* gp = &g2v.x; const float* bp = &b2v.x;
  #pragma unroll
  for (int i = 0; i < 4; ++i) {
    const float mean = statbuf[i*16 + fr];
    const float rs   = statbuf[64 + i*16 + fr];
    const float* xp = &xl4[i].x;
    float vo[4];
    #pragma unroll
    for (int r4 = 0; r4 < 4; ++r4)
      vo[r4] = (o[i][r4] + xp[r4] - mean) * rs * gp[r4] + bp[r4];
    uint2 pk; pk.x = cvtpk(vo[0], vo[1]); pk.y = cvtpk(vo[2], vo[3]);
    *(uint2*)(ctx2 + ((long)((s0 + i*16 + fr) * 4 + b)) * 1024 + hoff + dbase) = pk;
  }
}

extern "C" void kernel_launch(void* const* d_in, const int* in_sizes, int n_in,
                              void* d_out, int out_size, void* d_ws, size_t ws_size,
                              hipStream_t stream) {
  const float* hs   = (const float*)d_in[0];
  const float* g1   = (const float*)d_in[1];
  const float* b1   = (const float*)d_in[2];
  const float* g2   = (const float*)d_in[3];
  const float* b2   = (const float*)d_in[4];
  const float* Wq   = (const float*)d_in[5];
  const float* bq   = (const float*)d_in[6];
  const float* Wk   = (const float*)d_in[7];
  const float* bk   = (const float*)d_in[8];
  const float* Wv   = (const float*)d_in[9];
  const float* bv   = (const float*)d_in[10];
  const float* Win  = (const float*)d_in[11];
  const float* bin  = (const float*)d_in[12];
  const float* Wout = (const float*)d_in[13];
  const float* bout = (const float*)d_in[14];
  const float* Wd   = (const float*)d_in[15];
  const float* bd   = (const float*)d_in[16];

  // ws layout (bytes), ~99 MB total. Overlays: h2 over xbf+qkv, og over xln.
  char* ws = (char*)d_ws;
  float*          xln   = (float*)(ws + 0);                 // [4096][1024] f32
  unsigned short* xbf   = (unsigned short*)(ws + 16777216); // [4096][1024] bf16
  unsigned short* qkv   = (unsigned short*)(ws + 25165824); // [4096][3072] bf16
  unsigned short* ctx2  = (unsigned short*)(ws + 67108864); // [4096][1024] bf16
  unsigned short* wqkvT = (unsigned short*)(ws + 75497472); // [3072][1024] bf16
  unsigned short* winT  = (unsigned short*)(ws + 81788928); // [4][2048][256]
  unsigned short* woutT = (unsigned short*)(ws + 85983232); // [4][256][1024]
  unsigned short* wdT   = (unsigned short*)(ws + 88080384); // [1024][1024]
  float*          qkvb  = (float*)(ws + 90177536);          // [3072] f32
  unsigned short* vt    = (unsigned short*)(ws + 90189824); // [64][64][1024] bf16
  float*          q2g   = (float*)(ws + 98578432);          // [64][1024] f32
  float*          k2g   = (float*)(ws + 98840576);          // [64][1024] f32
  unsigned short* h2    = (unsigned short*)(ws + 16777216); // [4096][4096] bf16
  unsigned short* og    = (unsigned short*)(ws + 0);        // [4096][1024] bf16

  float* out0 = (float*)d_out;           // [S,B,H]
  float* out1 = out0 + 4194304;          // [64,1024,1024]

  ln1_kernel<<<4096, 256, 0, stream>>>(hs, g1, b1, xln, xbf);

  prep_weights_kernel<<<7180, 256, 0, stream>>>(
      Wq, Wk, Wv, Wd, Win, Wout, bq, bk, bv, wqkvT, wdT, winT, woutT, qkvb);

  // QKV: [4096,1024]@[1024,3072] -> qkv bf16
  mfma_gemm_kernel<<<dim3(24,32,1), 256, 0, stream>>>(
      xbf, 1024, 0, wqkvT, 0, 1024, qkvb, 0, qkv, nullptr, 3072, 0);

  prep_attn_kernel<<<dim3(16,64), 256, 0, stream>>>(qkv, q2g, k2g, vt);

  attn_kernel<<<dim3(16,64), 256, 0, stream>>>(qkv, vt, q2g, k2g, xln, g2, b2, ctx2, out1);

  mfma_glu_kernel<<<dim3(16,32,4), 256, 0, stream>>>(ctx2, winT, bin, h2);

  // FFN-out: per group -> og bf16
  mfma_gemm64_kernel<<<dim3(4,32,4), 256, 0, stream>>>(
      h2, 4096, 1024, woutT, 262144, 1024, bout, 256, og, nullptr, 1024, 256);

  // dense: [4096,1024]@[1024,1024] -> out0 fp32 (NT store)
  mfma_gemm64_kernel<<<dim3(16,32,1), 256, 0, stream>>>(
      og, 1024, 0, wdT, 0, 1024, bd, 0, nullptr, out0, 1024, 0);
}

// Round 13
// 233.455 us; speedup vs baseline: 1.1667x; 1.0444x over previous
//
#include <hip/hip_runtime.h>

// TransformerLayer_Combined on gfx950 — bf16 MFMA pipeline.
// GEMMs + ATTN: depth-2 software pipeline with COUNTED vmcnt + raw s_barrier.
// q2/k2 fused into QKV epilogue; attn fuses residual+LN2. Outputs fp32.

typedef __attribute__((ext_vector_type(8))) short short8;
typedef __attribute__((ext_vector_type(4))) float f32x4;

__device__ __forceinline__ unsigned short f2bf(float f) {
  union { float f; unsigned u; } x; x.f = f;
  unsigned r = x.u + 0x7FFFu + ((x.u >> 16) & 1u);
  return (unsigned short)(r >> 16);
}
__device__ __forceinline__ float bf2f(unsigned short u) {
  union { float f; unsigned u; } x; x.u = ((unsigned)u) << 16;
  return x.f;
}
__device__ __forceinline__ unsigned cvtpk(float a, float b) {  // [lo=a, hi=b]
  unsigned r;
  asm("v_cvt_pk_bf16_f32 %0, %1, %2" : "=v"(r) : "v"(a), "v"(b));
  return r;
}
// async 16B global->LDS (dest = wave-uniform base + lane*16)
__device__ __forceinline__ void gload16(const unsigned short* g, unsigned short* l) {
  __builtin_amdgcn_global_load_lds(
      (const __attribute__((address_space(1))) unsigned int*)g,
      (__attribute__((address_space(3))) unsigned int*)l, 16, 0, 0);
}

// ---- merged LN1 + weight prep, one launch --------------------------------
__device__ __forceinline__ void ln1_body(
    const float* __restrict__ x, const float* __restrict__ g,
    const float* __restrict__ b, float* __restrict__ y,
    unsigned short* __restrict__ ybf, int row, int tid)
{
  const long base = (long)row * 1024;
  const int c = tid * 4;
  float4 v = *(const float4*)(x + base + c);
  float s = v.x + v.y + v.z + v.w;
  float ss = v.x*v.x + v.y*v.y + v.z*v.z + v.w*v.w;
  #pragma unroll
  for (int off = 32; off > 0; off >>= 1) {
    s  += __shfl_xor(s, off);
    ss += __shfl_xor(ss, off);
  }
  __shared__ float sw[4], ssw[4];
  const int wave = tid >> 6;
  if ((tid & 63) == 0) { sw[wave] = s; ssw[wave] = ss; }
  __syncthreads();
  s  = sw[0] + sw[1] + sw[2] + sw[3];
  ss = ssw[0] + ssw[1] + ssw[2] + ssw[3];
  const float mean = s * (1.0f/1024.0f);
  const float var  = ss * (1.0f/1024.0f) - mean*mean;
  const float rs   = rsqrtf(var + 1e-6f);
  const float4 gv = *(const float4*)(g + c);
  const float4 bv = *(const float4*)(b + c);
  float4 o;
  o.x = (v.x - mean) * rs * gv.x + bv.x;
  o.y = (v.y - mean) * rs * gv.y + bv.y;
  o.z = (v.z - mean) * rs * gv.z + bv.z;
  o.w = (v.w - mean) * rs * gv.w + bv.w;
  *(float4*)(y + base + c) = o;
  ushort4 ob;
  ob.x = f2bf(o.x); ob.y = f2bf(o.y); ob.z = f2bf(o.z); ob.w = f2bf(o.w);
  *(ushort4*)(ybf + base + c) = ob;
}

__device__ __forceinline__ void transpose_body(
    const float* __restrict__ Wg, unsigned short* __restrict__ WTg,
    int K, int N, int bx, int by, int tid)
{
  __shared__ float T[32][33];
  const int n0 = bx * 32, k0 = by * 32;
  const int r = tid >> 3, c4 = (tid & 7) * 4;
  float4 v = *(const float4*)(Wg + (long)(k0 + r) * N + n0 + c4);
  T[r][c4+0] = v.x; T[r][c4+1] = v.y; T[r][c4+2] = v.z; T[r][c4+3] = v.w;
  __syncthreads();
  ushort4 o;
  o.x = f2bf(T[c4+0][r]); o.y = f2bf(T[c4+1][r]);
  o.z = f2bf(T[c4+2][r]); o.w = f2bf(T[c4+3][r]);
  *(ushort4*)(WTg + (long)(n0 + r) * K + k0 + c4) = o;
}

__global__ __launch_bounds__(256) void prep_all_kernel(
    const float* __restrict__ hs, const float* __restrict__ g1,
    const float* __restrict__ b1, float* __restrict__ xln,
    unsigned short* __restrict__ xbf,
    const float* __restrict__ Wq, const float* __restrict__ Wk,
    const float* __restrict__ Wv, const float* __restrict__ Wd,
    const float* __restrict__ Win, const float* __restrict__ Wout,
    const float* __restrict__ bq, const float* __restrict__ bk,
    const float* __restrict__ bv,
    unsigned short* __restrict__ wqkvT, unsigned short* __restrict__ wdT,
    unsigned short* __restrict__ winT, unsigned short* __restrict__ woutT,
    float* __restrict__ qkvb)
{
  const int bid = blockIdx.x;
  const int tid = threadIdx.x;
  if (bid < 4096) {               // LN1 rows
    ln1_body(hs, g1, b1, xln, xbf, bid, tid);
  } else if (bid < 8192) {        // Wq/Wk/Wv/Wd 1024x1024
    const int idx = bid - 4096;
    const int z = idx >> 10, rem = idx & 1023;
    const float* W = (z == 0) ? Wq : (z == 1) ? Wk : (z == 2) ? Wv : Wd;
    unsigned short* WT = (z == 3) ? wdT : wqkvT + (long)z * 1048576;
    transpose_body(W, WT, 1024, 1024, rem & 31, rem >> 5, tid);
  } else if (bid < 10240) {       // Win [4][256][2048]
    const int rem = bid - 8192;
    const int z = rem >> 9, r2 = rem & 511;
    transpose_body(Win + (long)z * 524288, winT + (long)z * 524288,
                   256, 2048, r2 & 63, r2 >> 6, tid);
  } else if (bid < 11264) {       // Wout [4][1024][256]
    const int rem = bid - 10240;
    const int z = rem >> 8, r2 = rem & 255;
    transpose_body(Wout + (long)z * 262144, woutT + (long)z * 262144,
                   1024, 256, r2 & 7, r2 >> 3, tid);
  } else {                        // packb (12 blocks x 256)
    const int i = (bid - 11264) * 256 + tid;
    qkvb[i] = (i < 1024) ? bq[i] : ((i < 2048) ? bk[i - 1024] : bv[i - 2048]);
  }
}

// ---- bf16 MFMA GEMM, 128x128 tile, depth-2 counted-vmcnt pipeline ------
// Optional fused q2/k2 row sum-of-squares (QKV call only).
__global__ __launch_bounds__(256) void mfma_gemm_kernel(
    const unsigned short* __restrict__ A, int lda, long agoff,
    const unsigned short* __restrict__ BT, long bgoff, int K,
    const float* __restrict__ bias, int biasoff,
    unsigned short* __restrict__ Cbf, float* __restrict__ Cf,
    int ldc, int cgoff,
    float* __restrict__ q2g, float* __restrict__ k2g)
{
  const int g = blockIdx.z;
  const unsigned short* Ag = A + (long)g * agoff;
  const unsigned short* Bg = BT + (long)g * bgoff;
  const float* biasg = bias + (long)g * biasoff;
  const int row0 = blockIdx.y * 128, col0 = blockIdx.x * 128;
  __shared__ __align__(16) unsigned short As[2][128 * 64];
  __shared__ __align__(16) unsigned short Bs[2][128 * 64];
  const int tid = threadIdx.x;
  const int w = tid >> 6, l = tid & 63;
  const int ms = (w & 1) << 6, ns = (w >> 1) << 6;
  const int fr = l & 15, fg = l >> 4;
  const int lr8 = l >> 3, ls8 = l & 7;
  const int scol = (ls8 ^ lr8) << 3;
  const int rsw = fr & 7;
  f32x4 acc[4][4];
  #pragma unroll
  for (int i = 0; i < 4; ++i)
    #pragma unroll
    for (int j = 0; j < 4; ++j) acc[i][j] = (f32x4)0.0f;

  const int nt = K >> 6;   // requires K >= 128
  #pragma unroll
  for (int sidx = 0; sidx < 2; ++sidx) {
    const int k0 = sidx << 6;
    #pragma unroll
    for (int g8 = 0; g8 < 4; ++g8) {
      const int r = (w << 5) + (g8 << 3);
      gload16(Ag + (long)(row0 + r + lr8) * lda + k0 + scol, &As[sidx][r * 64]);
      gload16(Bg + (long)(col0 + r + lr8) * K  + k0 + scol, &Bs[sidx][r * 64]);
    }
  }
  int cur = 0;
  for (int t = 0; t < nt; ++t) {
    if (t + 1 < nt) asm volatile("s_waitcnt vmcnt(8)" ::: "memory");
    else            asm volatile("s_waitcnt vmcnt(0)" ::: "memory");
    __builtin_amdgcn_s_barrier();
    __builtin_amdgcn_sched_barrier(0);
    short8 af[2][4], bfr[2][4];
    #pragma unroll
    for (int ks = 0; ks < 2; ++ks) {
      const int rslot = (((ks << 2) + fg) ^ rsw) << 3;
      #pragma unroll
      for (int i = 0; i < 4; ++i) {
        af[ks][i]  = *(const short8*)&As[cur][(ms + i*16 + fr) * 64 + rslot];
        bfr[ks][i] = *(const short8*)&Bs[cur][(ns + i*16 + fr) * 64 + rslot];
      }
    }
    asm volatile("s_waitcnt lgkmcnt(0)" ::: "memory");
    __builtin_amdgcn_sched_barrier(0);
    __builtin_amdgcn_s_barrier();
    if (t + 2 < nt) {
      const int k0 = (t + 2) << 6;
      #pragma unroll
      for (int g8 = 0; g8 < 4; ++g8) {
        const int r = (w << 5) + (g8 << 3);
        gload16(Ag + (long)(row0 + r + lr8) * lda + k0 + scol, &As[cur][r * 64]);
        gload16(Bg + (long)(col0 + r + lr8) * K  + k0 + scol, &Bs[cur][r * 64]);
      }
    }
    __builtin_amdgcn_s_setprio(1);
    #pragma unroll
    for (int ks = 0; ks < 2; ++ks)
      #pragma unroll
      for (int i = 0; i < 4; ++i)
        #pragma unroll
        for (int j = 0; j < 4; ++j)
          acc[i][j] = __builtin_amdgcn_mfma_f32_16x16x32_bf16(bfr[ks][j], af[ks][i], acc[i][j], 0, 0, 0);
    __builtin_amdgcn_s_setprio(0);
    cur ^= 1;
  }

  float s2[4] = {0.f, 0.f, 0.f, 0.f};
  #pragma unroll
  for (int j = 0; j < 4; ++j) {
    const float4 bj4 = *(const float4*)(biasg + col0 + ns + j*16 + (fg << 2));
    #pragma unroll
    for (int i = 0; i < 4; ++i) {
      const long row = row0 + ms + i*16 + fr;
      const long cb = row * ldc + (long)g * cgoff + col0 + ns + j*16 + (fg << 2);
      const float v0 = acc[i][j][0] + bj4.x, v1 = acc[i][j][1] + bj4.y;
      const float v2 = acc[i][j][2] + bj4.z, v3 = acc[i][j][3] + bj4.w;
      s2[i] += v0*v0 + v1*v1 + v2*v2 + v3*v3;
      if (Cbf) {
        uint2 pk; pk.x = cvtpk(v0, v1); pk.y = cvtpk(v2, v3);
        *(uint2*)(Cbf + cb) = pk;
      } else {
        f32x4 o = {v0, v1, v2, v3};
        __builtin_nontemporal_store(o, (f32x4*)(Cf + cb));
      }
    }
  }
  // fused q2/k2 (QKV only): n-range [col0+ns, col0+ns+64) = one head's d.
  if (q2g && col0 < 2048) {
    const int nsAbs = col0 + ns;
    const bool isQ = nsAbs < 1024;
    float* outp = isQ ? q2g : k2g;
    const int head = (isQ ? nsAbs : nsAbs - 1024) >> 6;
    #pragma unroll
    for (int i = 0; i < 4; ++i) {
      float s = s2[i];
      s += __shfl_xor(s, 16);
      s += __shfl_xor(s, 32);
      if (fg == 0) {
        const int gr = row0 + ms + i*16 + fr;          // s*4+b
        outp[((gr & 3) * 16 + head) * 1024 + (gr >> 2)] = s;
      }
    }
  }
}

// ---- bf16 MFMA GEMM, 128x64 tile, depth-2 pipeline (stage = 6 loads) ----
__global__ __launch_bounds__(256) void mfma_gemm64_kernel(
    const unsigned short* __restrict__ A, int lda, long agoff,
    const unsigned short* __restrict__ BT, long bgoff, int K,
    const float* __restrict__ bias, int biasoff,
    unsigned short* __restrict__ Cbf, float* __restrict__ Cf,
    int ldc, int cgoff)
{
  const int g = blockIdx.z;
  const unsigned short* Ag = A + (long)g * agoff;
  const unsigned short* Bg = BT + (long)g * bgoff;
  const float* biasg = bias + (long)g * biasoff;
  const int row0 = blockIdx.y * 128, col0 = blockIdx.x * 64;
  __shared__ __align__(16) unsigned short As[2][128 * 64];
  __shared__ __align__(16) unsigned short Bs[2][64 * 64];
  const int tid = threadIdx.x;
  const int w = tid >> 6, l = tid & 63;
  const int ms = (w & 1) << 6, ns = (w >> 1) << 5;
  const int fr = l & 15, fg = l >> 4;
  const int lr8 = l >> 3, ls8 = l & 7;
  const int scol = (ls8 ^ lr8) << 3;
  const int rsw = fr & 7;
  f32x4 acc[4][2];
  #pragma unroll
  for (int i = 0; i < 4; ++i)
    #pragma unroll
    for (int j = 0; j < 2; ++j) acc[i][j] = (f32x4)0.0f;

  const int nt = K >> 6;
  #pragma unroll
  for (int sidx = 0; sidx < 2; ++sidx) {
    const int k0 = sidx << 6;
    #pragma unroll
    for (int g8 = 0; g8 < 4; ++g8) {
      const int r = (w << 5) + (g8 << 3);
      gload16(Ag + (long)(row0 + r + lr8) * lda + k0 + scol, &As[sidx][r * 64]);
    }
    #pragma unroll
    for (int g8 = 0; g8 < 2; ++g8) {
      const int r = (w << 4) + (g8 << 3);
      gload16(Bg + (long)(col0 + r + lr8) * K + k0 + scol, &Bs[sidx][r * 64]);
    }
  }
  int cur = 0;
  for (int t = 0; t < nt; ++t) {
    if (t + 1 < nt) asm volatile("s_waitcnt vmcnt(6)" ::: "memory");
    else            asm volatile("s_waitcnt vmcnt(0)" ::: "memory");
    __builtin_amdgcn_s_barrier();
    __builtin_amdgcn_sched_barrier(0);
    short8 af[2][4], bfr[2][2];
    #pragma unroll
    for (int ks = 0; ks < 2; ++ks) {
      const int rslot = (((ks << 2) + fg) ^ rsw) << 3;
      #pragma unroll
      for (int i = 0; i < 4; ++i)
        af[ks][i] = *(const short8*)&As[cur][(ms + i*16 + fr) * 64 + rslot];
      #pragma unroll
      for (int j = 0; j < 2; ++j)
        bfr[ks][j] = *(const short8*)&Bs[cur][(ns + j*16 + fr) * 64 + rslot];
    }
    asm volatile("s_waitcnt lgkmcnt(0)" ::: "memory");
    __builtin_amdgcn_sched_barrier(0);
    __builtin_amdgcn_s_barrier();
    if (t + 2 < nt) {
      const int k0 = (t + 2) << 6;
      #pragma unroll
      for (int g8 = 0; g8 < 4; ++g8) {
        const int r = (w << 5) + (g8 << 3);
        gload16(Ag + (long)(row0 + r + lr8) * lda + k0 + scol, &As[cur][r * 64]);
      }
      #pragma unroll
      for (int g8 = 0; g8 < 2; ++g8) {
        const int r = (w << 4) + (g8 << 3);
        gload16(Bg + (long)(col0 + r + lr8) * K + k0 + scol, &Bs[cur][r * 64]);
      }
    }
    __builtin_amdgcn_s_setprio(1);
    #pragma unroll
    for (int ks = 0; ks < 2; ++ks)
      #pragma unroll
      for (int i = 0; i < 4; ++i)
        #pragma unroll
        for (int j = 0; j < 2; ++j)
          acc[i][j] = __builtin_amdgcn_mfma_f32_16x16x32_bf16(bfr[ks][j], af[ks][i], acc[i][j], 0, 0, 0);
    __builtin_amdgcn_s_setprio(0);
    cur ^= 1;
  }

  #pragma unroll
  for (int j = 0; j < 2; ++j) {
    const float4 bj4 = *(const float4*)(biasg + col0 + ns + j*16 + (fg << 2));
    #pragma unroll
    for (int i = 0; i < 4; ++i) {
      const long row = row0 + ms + i*16 + fr;
      const long cb = row * ldc + (long)g * cgoff + col0 + ns + j*16 + (fg << 2);
      const float v0 = acc[i][j][0] + bj4.x, v1 = acc[i][j][1] + bj4.y;
      const float v2 = acc[i][j][2] + bj4.z, v3 = acc[i][j][3] + bj4.w;
      if (Cbf) {
        uint2 pk; pk.x = cvtpk(v0, v1); pk.y = cvtpk(v2, v3);
        *(uint2*)(Cbf + cb) = pk;
      } else {
        f32x4 o = {v0, v1, v2, v3};
        __builtin_nontemporal_store(o, (f32x4*)(Cf + cb));
      }
    }
  }
}

// ---- grouped dense_in + GLU, 128x64 tile, depth-2 pipeline (stage=8) ----
__global__ __launch_bounds__(256) void mfma_glu_kernel(
    const unsigned short* __restrict__ A,   // ctx2 [4096][1024]
    const unsigned short* __restrict__ WT,  // [g][2048][256]
    const float* __restrict__ bin,          // [4][2048]
    unsigned short* __restrict__ H2)        // [4096][4096]
{
  const int g = blockIdx.z;
  const unsigned short* Ag = A + g * 256;
  const unsigned short* Wg = WT + (long)g * 2048 * 256;
  const float* bg = bin + g * 2048;
  const int row0 = blockIdx.y * 128, col0 = blockIdx.x * 64;
  __shared__ __align__(16) unsigned short As[2][128 * 64];
  __shared__ __align__(16) unsigned short Bxs[2][64 * 64];
  __shared__ __align__(16) unsigned short Bys[2][64 * 64];
  const int tid = threadIdx.x;
  const int w = tid >> 6, l = tid & 63;
  const int ms = (w & 1) << 6, ns = (w >> 1) << 5;
  const int fr = l & 15, fg = l >> 4;
  const int lr8 = l >> 3, ls8 = l & 7;
  const int scol = (ls8 ^ lr8) << 3;
  const int rsw = fr & 7;
  f32x4 ax[4][2], ay[4][2];
  #pragma unroll
  for (int i = 0; i < 4; ++i)
    #pragma unroll
    for (int j = 0; j < 2; ++j) { ax[i][j] = (f32x4)0.0f; ay[i][j] = (f32x4)0.0f; }

  #pragma unroll
  for (int sidx = 0; sidx < 2; ++sidx) {
    const int k0 = sidx << 6;
    #pragma unroll
    for (int g8 = 0; g8 < 4; ++g8) {
      const int r = (w << 5) + (g8 << 3);
      gload16(Ag + (long)(row0 + r + lr8) * 1024 + k0 + scol, &As[sidx][r * 64]);
    }
    #pragma unroll
    for (int g8 = 0; g8 < 2; ++g8) {
      const int r = (w << 4) + (g8 << 3);
      gload16(Wg + (long)(col0 + r + lr8) * 256 + k0 + scol,        &Bxs[sidx][r * 64]);
      gload16(Wg + (long)(1024 + col0 + r + lr8) * 256 + k0 + scol, &Bys[sidx][r * 64]);
    }
  }
  int cur = 0;
  for (int t = 0; t < 4; ++t) {
    if (t + 1 < 4) asm volatile("s_waitcnt vmcnt(8)" ::: "memory");
    else           asm volatile("s_waitcnt vmcnt(0)" ::: "memory");
    __builtin_amdgcn_s_barrier();
    __builtin_amdgcn_sched_barrier(0);
    short8 af[2][4], bx[2][2], by[2][2];
    #pragma unroll
    for (int ks = 0; ks < 2; ++ks) {
      const int rslot = (((ks << 2) + fg) ^ rsw) << 3;
      #pragma unroll
      for (int i = 0; i < 4; ++i)
        af[ks][i] = *(const short8*)&As[cur][(ms + i*16 + fr) * 64 + rslot];
      #pragma unroll
      for (int j = 0; j < 2; ++j) {
        bx[ks][j] = *(const short8*)&Bxs[cur][(ns + j*16 + fr) * 64 + rslot];
        by[ks][j] = *(const short8*)&Bys[cur][(ns + j*16 + fr) * 64 + rslot];
      }
    }
    asm volatile("s_waitcnt lgkmcnt(0)" ::: "memory");
    __builtin_amdgcn_sched_barrier(0);
    __builtin_amdgcn_s_barrier();
    if (t + 2 < 4) {
      const int k0 = (t + 2) << 6;
      #pragma unroll
      for (int g8 = 0; g8 < 4; ++g8) {
        const int r = (w << 5) + (g8 << 3);
        gload16(Ag + (long)(row0 + r + lr8) * 1024 + k0 + scol, &As[cur][r * 64]);
      }
      #pragma unroll
      for (int g8 = 0; g8 < 2; ++g8) {
        const int r = (w << 4) + (g8 << 3);
        gload16(Wg + (long)(col0 + r + lr8) * 256 + k0 + scol,        &Bxs[cur][r * 64]);
        gload16(Wg + (long)(1024 + col0 + r + lr8) * 256 + k0 + scol, &Bys[cur][r * 64]);
      }
    }
    __builtin_amdgcn_s_setprio(1);
    #pragma unroll
    for (int ks = 0; ks < 2; ++ks)
      #pragma unroll
      for (int i = 0; i < 4; ++i)
        #pragma unroll
        for (int j = 0; j < 2; ++j) {
          ax[i][j] = __builtin_amdgcn_mfma_f32_16x16x32_bf16(bx[ks][j], af[ks][i], ax[i][j], 0, 0, 0);
          ay[i][j] = __builtin_amdgcn_mfma_f32_16x16x32_bf16(by[ks][j], af[ks][i], ay[i][j], 0, 0, 0);
        }
    __builtin_amdgcn_s_setprio(0);
    cur ^= 1;
  }

  #pragma unroll
  for (int j = 0; j < 2; ++j) {
    const float4 bx4 = *(const float4*)(bg + col0 + ns + j*16 + (fg << 2));
    const float4 by4 = *(const float4*)(bg + 1024 + col0 + ns + j*16 + (fg << 2));
    #pragma unroll
    for (int i = 0; i < 4; ++i) {
      const long row = row0 + ms + i*16 + fr;
      const long cb = row * 4096 + g * 1024 + col0 + ns + j*16 + (fg << 2);
      float o4[4];
      const float* bxp = &bx4.x; const float* byp = &by4.x;
      #pragma unroll
      for (int r4 = 0; r4 < 4; ++r4) {
        const float xh = ax[i][j][r4] + bxp[r4];
        const float yh = ay[i][j][r4] + byp[r4];
        o4[r4] = xh * fmaxf(yh, 0.0f);
      }
      uint2 pk; pk.x = cvtpk(o4[0], o4[1]); pk.y = cvtpk(o4[2], o4[3]);
      *(uint2*)(H2 + cb) = pk;
    }
  }
}

// -------- V transpose only: qkv v-part [s*4+b][.] -> vt [n][d][s] ---------
__global__ __launch_bounds__(256) void vtrans_kernel(
    const unsigned short* __restrict__ qkv, unsigned short* __restrict__ vt)
{
  __shared__ unsigned short T[64][72];
  const int n = blockIdx.y, s0 = blockIdx.x * 64;
  const int b = n >> 4, hoff = (n & 15) * 64;
  const int tid = threadIdx.x;
  #pragma unroll
  for (int p = 0; p < 2; ++p) {
    const int r = (tid >> 3) + p * 32, c = (tid & 7) << 3;
    *(short8*)&T[r][c] = *(const short8*)(qkv + ((long)((s0 + r) * 4 + b)) * 3072 + 2048 + hoff + c);
  }
  __syncthreads();
  #pragma unroll
  for (int p = 0; p < 2; ++p) {
    const int d = (tid >> 3) + p * 32, sc = (tid & 7) << 3;
    short8 o;
    #pragma unroll
    for (int j = 0; j < 8; ++j) o[j] = (short)T[sc + j][d];
    *(short8*)(vt + ((long)n * 64 + d) * 1024 + s0 + sc) = o;
  }
}

// --- MFMA attention, counted-vmcnt K/V pipeline, fused residual+LN2 ------
// grid (16 s-tiles, 64 heads). Qs/Ps XOR-swizzled [64*64]; LDS 52 KB.
__global__ __launch_bounds__(256) void attn_kernel(
    const unsigned short* __restrict__ qkv, const unsigned short* __restrict__ vt,
    const float* __restrict__ q2g, const float* __restrict__ k2g,
    const float* __restrict__ xln, const float* __restrict__ g2,
    const float* __restrict__ b2,
    unsigned short* __restrict__ ctx2, float* __restrict__ scores)
{
  const int n = blockIdx.y;
  const int s0 = blockIdx.x * 64;
  const int b = n >> 4, hoff = (n & 15) * 64;
  __shared__ __align__(16) unsigned short Qs[64 * 64];
  __shared__ __align__(16) unsigned short Ks[2][64 * 64];
  __shared__ __align__(16) unsigned short VTl[2][64 * 64];
  __shared__ __align__(16) unsigned short Ps[64 * 64];
  __shared__ float k2s[1024];
  const int tid = threadIdx.x, w = tid >> 6, l = tid & 63;
  const int fr = l & 15, fg = l >> 4;
  const int lr8 = l >> 3, ls8 = l & 7;
  const int sslot = ((ls8 ^ lr8) << 3);
  const int rsw = fr & 7;

  // Qs stage (swizzled: row r, slot s stored at s^(r&7))
  #pragma unroll
  for (int p = 0; p < 2; ++p) {
    const int r = (tid >> 3) + p * 32, cs = tid & 7;
    *(short8*)&Qs[r * 64 + ((cs ^ (r & 7)) << 3)] =
        *(const short8*)(qkv + ((long)((s0 + r) * 4 + b)) * 3072 + hoff + (cs << 3));
  }
  // k2 row -> LDS (one float4 per thread)
  *(float4*)&k2s[tid << 2] = *(const float4*)(k2g + n * 1024 + (tid << 2));
  float q2m[4];
  #pragma unroll
  for (int i = 0; i < 4; ++i) q2m[i] = -0.0625f * q2g[n * 1024 + s0 + i*16 + fr];
  // stage K/V tile 0
  #pragma unroll
  for (int p = 0; p < 2; ++p) {
    const int rowb = p * 32 + w * 8;
    gload16(qkv + ((long)((rowb + lr8) * 4 + b)) * 3072 + 1024 + hoff + sslot, &Ks[0][rowb * 64]);
    gload16(vt + ((long)n * 64 + rowb + lr8) * 1024 + sslot,                   &VTl[0][rowb * 64]);
  }
  __syncthreads();   // full drain at t=0 (loads + ds_writes)

  f32x4 o[4];
  #pragma unroll
  for (int i = 0; i < 4; ++i) o[i] = (f32x4)0.0f;

  int cur = 0;
  for (int t0 = 0; t0 < 1024; t0 += 64) {
    if (t0 > 0) {   // own prefetch (oldest 4 vmem ops) retired, then barrier
      asm volatile("s_waitcnt vmcnt(4)" ::: "memory");
      __builtin_amdgcn_sched_barrier(0);
      __builtin_amdgcn_s_barrier();
    }
    // QK^T swapped: lane: srow = 16i+fr, t = 16w+4fg+r4
    f32x4 c4[4];
    #pragma unroll
    for (int i = 0; i < 4; ++i) c4[i] = (f32x4)0.0f;
    #pragma unroll
    for (int ks = 0; ks < 2; ++ks) {
      const short8 kf = *(const short8*)&Ks[cur][((w << 4) + fr) * 64 + ((((ks << 2) + fg) ^ rsw) << 3)];
      #pragma unroll
      for (int i = 0; i < 4; ++i) {
        const short8 qf = *(const short8*)&Qs[(i*16 + fr) * 64 + ((((ks << 2) + fg) ^ rsw) << 3)];
        c4[i] = __builtin_amdgcn_mfma_f32_16x16x32_bf16(kf, qf, c4[i], 0, 0, 0);
      }
    }
    // prefetch next K/V tile BEFORE the score stores (FIFO: loads oldest)
    if (t0 + 64 < 1024) {
      #pragma unroll
      for (int p = 0; p < 2; ++p) {
        const int rowb = p * 32 + w * 8;
        gload16(qkv + ((long)((t0 + 64 + rowb + lr8) * 4 + b)) * 3072 + 1024 + hoff + sslot,
                &Ks[cur ^ 1][rowb * 64]);
        gload16(vt + ((long)n * 64 + rowb + lr8) * 1024 + t0 + 64 + sslot,
                &VTl[cur ^ 1][rowb * 64]);
      }
    }
    const float4 k2v4 = *(const float4*)&k2s[t0 + (w << 4) + (fg << 2)];
    const float k2m[4] = {-0.0625f*k2v4.x, -0.0625f*k2v4.y, -0.0625f*k2v4.z, -0.0625f*k2v4.w};
    #pragma unroll
    for (int i = 0; i < 4; ++i) {
      f32x4 sc;
      float pe[4];
      #pragma unroll
      for (int r4 = 0; r4 < 4; ++r4) {
        const float m = fmaf(c4[i][r4], 0.125f, q2m[i] + k2m[r4]);
        sc[r4] = m;
        pe[r4] = __expf(m);
      }
      __builtin_nontemporal_store(sc,
          (f32x4*)(scores + (long)n * 1048576 + (long)(s0 + i*16 + fr) * 1024 + t0 + (w << 4) + (fg << 2)));
      // Ps write (swizzled, uint2 granule): logical col = w*16 + fg*4
      const int slot = (w << 1) + (fg >> 1);
      const int pc = ((slot ^ (fr & 7)) << 3) + ((fg & 1) << 2);
      uint2 pk; pk.x = cvtpk(pe[0], pe[1]); pk.y = cvtpk(pe[2], pe[3]);
      *(uint2*)&Ps[(i*16 + fr) * 64 + pc] = pk;
    }
    asm volatile("s_waitcnt lgkmcnt(0)" ::: "memory");
    __builtin_amdgcn_sched_barrier(0);
    __builtin_amdgcn_s_barrier();
    // PV swapped: lane: srow = 16i+fr, d = 16w+4fg+r4
    #pragma unroll
    for (int ks = 0; ks < 2; ++ks) {
      const short8 vb = *(const short8*)&VTl[cur][((w << 4) + fr) * 64 + ((((ks << 2) + fg) ^ rsw) << 3)];
      #pragma unroll
      for (int i = 0; i < 4; ++i) {
        const short8 pf = *(const short8*)&Ps[(i*16 + fr) * 64 + ((((ks << 2) + fg) ^ rsw) << 3)];
        o[i] = __builtin_amdgcn_mfma_f32_16x16x32_bf16(vb, pf, o[i], 0, 0, 0);
      }
    }
    asm volatile("s_waitcnt lgkmcnt(0)" ::: "memory");
    __builtin_amdgcn_sched_barrier(0);
    __builtin_amdgcn_s_barrier();
    cur ^= 1;
  }

  // ---- fused residual + per-head LN2 -> ctx2 bf16 ----
  const int dbase = (w << 4) + (fg << 2);
  float4 xl4[4];
  #pragma unroll
  for (int i = 0; i < 4; ++i)
    xl4[i] = *(const float4*)(xln + ((long)((s0 + i*16 + fr) * 4 + b)) * 1024 + hoff + dbase);

  float* redbuf = (float*)&Ps[0];   // overlay (Ps dead): 2048 floats
  const int slot = (w << 2) + fg;
  #pragma unroll
  for (int i = 0; i < 4; ++i) {
    float s = 0.f, ss = 0.f;
    const float* xp = &xl4[i].x;
    #pragma unroll
    for (int r4 = 0; r4 < 4; ++r4) {
      const float v = o[i][r4] + xp[r4];
      s += v; ss = fmaf(v, v, ss);
    }
    redbuf[(i*16 + fr) * 16 + slot] = s;
    redbuf[1024 + (i*16 + fr) * 16 + slot] = ss;
  }
  __syncthreads();
  float* statbuf = (float*)&Qs[0];  // overlay (Qs dead)
  {
    const int row = tid >> 2, q4 = tid & 3;
    float s = 0.f, ss = 0.f;
    #pragma unroll
    for (int k = 0; k < 4; ++k) {
      s  += redbuf[row * 16 + q4 * 4 + k];
      ss += redbuf[1024 + row * 16 + q4 * 4 + k];
    }
    s  += __shfl_xor(s, 1);  s  += __shfl_xor(s, 2);
    ss += __shfl_xor(ss, 1); ss += __shfl_xor(ss, 2);
    if (q4 == 0) {
      const float mean = s * (1.0f/64.0f);
      const float var  = ss * (1.0f/64.0f) - mean * mean;
      statbuf[row] = mean;
      statbuf[64 + row] = rsqrtf(var + 1e-6f);
    }
  }
  __syncthreads();
  const float4 g2v = *(const float4*)(g2 + dbase);
  const float4 b2v = *(const float4*)(b2 + dbase);
  const float* gp = &g2v.x; const float* bp = &b2v.x;
  #pragma unroll
  for (int i = 0; i < 4; ++i) {
    const float mean = statbuf[i*16 + fr];
    const float rs   = statbuf[64 + i*16 + fr];
    const float* xp = &xl4[i].x;
    float vo[4];
    #pragma unroll
    for (int r4 = 0; r4 < 4; ++r4)
      vo[r4] = (o[i][r4] + xp[r4] - mean) * rs * gp[r4] + bp[r4];
    uint2 pk; pk.x = cvtpk(vo[0], vo[1]); pk.y = cvtpk(vo[2], vo[3]);
    *(uint2*)(ctx2 + ((long)((s0 + i*16 + fr) * 4 + b)) * 1024 + hoff + dbase) = pk;
  }
}

extern "C" void kernel_launch(void* const* d_in, const int* in_sizes, int n_in,
                              void* d_out, int out_size, void* d_ws, size_t ws_size,
                              hipStream_t stream) {
  const float* hs   = (const float*)d_in[0];
  const float* g1   = (const float*)d_in[1];
  const float* b1   = (const float*)d_in[2];
  const float* g2   = (const float*)d_in[3];
  const float* b2   = (const float*)d_in[4];
  const float* Wq   = (const float*)d_in[5];
  const float* bq   = (const float*)d_in[6];
  const float* Wk   = (const float*)d_in[7];
  const float* bk   = (const float*)d_in[8];
  const float* Wv   = (const float*)d_in[9];
  const float* bv   = (const float*)d_in[10];
  const float* Win  = (const float*)d_in[11];
  const float* bin  = (const float*)d_in[12];
  const float* Wout = (const float*)d_in[13];
  const float* bout = (const float*)d_in[14];
  const float* Wd   = (const float*)d_in[15];
  const float* bd   = (const float*)d_in[16];

  // ws layout (bytes), ~99 MB total. Overlays: h2 over xbf+qkv, og over xln.
  char* ws = (char*)d_ws;
  float*          xln   = (float*)(ws + 0);                 // [4096][1024] f32
  unsigned short* xbf   = (unsigned short*)(ws + 16777216); // [4096][1024] bf16
  unsigned short* qkv   = (unsigned short*)(ws + 25165824); // [4096][3072] bf16
  unsigned short* ctx2  = (unsigned short*)(ws + 67108864); // [4096][1024] bf16
  unsigned short* wqkvT = (unsigned short*)(ws + 75497472); // [3072][1024] bf16
  unsigned short* winT  = (unsigned short*)(ws + 81788928); // [4][2048][256]
  unsigned short* woutT = (unsigned short*)(ws + 85983232); // [4][256][1024]
  unsigned short* wdT   = (unsigned short*)(ws + 88080384); // [1024][1024]
  float*          qkvb  = (float*)(ws + 90177536);          // [3072] f32
  unsigned short* vt    = (unsigned short*)(ws + 90189824); // [64][64][1024] bf16
  float*          q2g   = (float*)(ws + 98578432);          // [64][1024] f32
  float*          k2g   = (float*)(ws + 98840576);          // [64][1024] f32
  unsigned short* h2    = (unsigned short*)(ws + 16777216); // [4096][4096] bf16
  unsigned short* og    = (unsigned short*)(ws + 0);        // [4096][1024] bf16

  float* out0 = (float*)d_out;           // [S,B,H]
  float* out1 = out0 + 4194304;          // [64,1024,1024]

  prep_all_kernel<<<11276, 256, 0, stream>>>(
      hs, g1, b1, xln, xbf,
      Wq, Wk, Wv, Wd, Win, Wout, bq, bk, bv,
      wqkvT, wdT, winT, woutT, qkvb);

  // QKV: [4096,1024]@[1024,3072] -> qkv bf16 (+ fused q2/k2)
  mfma_gemm_kernel<<<dim3(24,32,1), 256, 0, stream>>>(
      xbf, 1024, 0, wqkvT, 0, 1024, qkvb, 0, qkv, nullptr, 3072, 0, q2g, k2g);

  vtrans_kernel<<<dim3(16,64), 256, 0, stream>>>(qkv, vt);

  attn_kernel<<<dim3(16,64), 256, 0, stream>>>(qkv, vt, q2g, k2g, xln, g2, b2, ctx2, out1);

  mfma_glu_kernel<<<dim3(16,32,4), 256, 0, stream>>>(ctx2, winT, bin, h2);

  // FFN-out: per group -> og bf16
  mfma_gemm64_kernel<<<dim3(4,32,4), 256, 0, stream>>>(
      h2, 4096, 1024, woutT, 262144, 1024, bout, 256, og, nullptr, 1024, 256);

  // dense: [4096,1024]@[1024,1024] -> out0 fp32 (NT store)
  mfma_gemm64_kernel<<<dim3(16,32,1), 256, 0, stream>>>(
      og, 1024, 0, wdT, 0, 1024, bd, 0, nullptr, out0, 1024, 0);
}

// Round 16
// 225.028 us; speedup vs baseline: 1.2104x; 1.0374x over previous
//
#include <hip/hip_runtime.h>

// TransformerLayer_Combined on gfx950 — bf16 MFMA pipeline.
// GEMMs + ATTN: depth-2 counted-vmcnt + raw s_barrier pipelines (proven).
// q2/k2 fused into QKV epilogue; attn fuses residual (bf16 x) + LN2.

typedef __attribute__((ext_vector_type(8))) short short8;
typedef __attribute__((ext_vector_type(4))) float f32x4;

__device__ __forceinline__ unsigned short f2bf(float f) {
  union { float f; unsigned u; } x; x.f = f;
  unsigned r = x.u + 0x7FFFu + ((x.u >> 16) & 1u);
  return (unsigned short)(r >> 16);
}
__device__ __forceinline__ float bf2f(unsigned short u) {
  union { float f; unsigned u; } x; x.u = ((unsigned)u) << 16;
  return x.f;
}
__device__ __forceinline__ unsigned cvtpk(float a, float b) {  // [lo=a, hi=b]
  unsigned r;
  asm("v_cvt_pk_bf16_f32 %0, %1, %2" : "=v"(r) : "v"(a), "v"(b));
  return r;
}
// async 16B global->LDS (dest = wave-uniform base + lane*16)
__device__ __forceinline__ void gload16(const unsigned short* g, unsigned short* l) {
  __builtin_amdgcn_global_load_lds(
      (const __attribute__((address_space(1))) unsigned int*)g,
      (__attribute__((address_space(3))) unsigned int*)l, 16, 0, 0);
}

// ---- merged LN1 + weight prep, one launch --------------------------------
__device__ __forceinline__ void ln1_body(
    const float* __restrict__ x, const float* __restrict__ g,
    const float* __restrict__ b,
    unsigned short* __restrict__ ybf, int row, int tid)
{
  const long base = (long)row * 1024;
  const int c = tid * 4;
  float4 v = *(const float4*)(x + base + c);
  float s = v.x + v.y + v.z + v.w;
  float ss = v.x*v.x + v.y*v.y + v.z*v.z + v.w*v.w;
  #pragma unroll
  for (int off = 32; off > 0; off >>= 1) {
    s  += __shfl_xor(s, off);
    ss += __shfl_xor(ss, off);
  }
  __shared__ float sw[4], ssw[4];
  const int wave = tid >> 6;
  if ((tid & 63) == 0) { sw[wave] = s; ssw[wave] = ss; }
  __syncthreads();
  s  = sw[0] + sw[1] + sw[2] + sw[3];
  ss = ssw[0] + ssw[1] + ssw[2] + ssw[3];
  const float mean = s * (1.0f/1024.0f);
  const float var  = ss * (1.0f/1024.0f) - mean*mean;
  const float rs   = rsqrtf(var + 1e-6f);
  const float4 gv = *(const float4*)(g + c);
  const float4 bv = *(const float4*)(b + c);
  const float o0 = (v.x - mean) * rs * gv.x + bv.x;
  const float o1 = (v.y - mean) * rs * gv.y + bv.y;
  const float o2 = (v.z - mean) * rs * gv.z + bv.z;
  const float o3 = (v.w - mean) * rs * gv.w + bv.w;
  uint2 pk; pk.x = cvtpk(o0, o1); pk.y = cvtpk(o2, o3);
  *(uint2*)(ybf + base + c) = pk;
}

__device__ __forceinline__ void transpose_body(
    const float* __restrict__ Wg, unsigned short* __restrict__ WTg,
    int K, int N, int bx, int by, int tid)
{
  __shared__ float T[32][33];
  const int n0 = bx * 32, k0 = by * 32;
  const int r = tid >> 3, c4 = (tid & 7) * 4;
  float4 v = *(const float4*)(Wg + (long)(k0 + r) * N + n0 + c4);
  T[r][c4+0] = v.x; T[r][c4+1] = v.y; T[r][c4+2] = v.z; T[r][c4+3] = v.w;
  __syncthreads();
  ushort4 o;
  o.x = f2bf(T[c4+0][r]); o.y = f2bf(T[c4+1][r]);
  o.z = f2bf(T[c4+2][r]); o.w = f2bf(T[c4+3][r]);
  *(ushort4*)(WTg + (long)(n0 + r) * K + k0 + c4) = o;
}

__global__ __launch_bounds__(256) void prep_all_kernel(
    const float* __restrict__ hs, const float* __restrict__ g1,
    const float* __restrict__ b1,
    unsigned short* __restrict__ xbf,
    const float* __restrict__ Wq, const float* __restrict__ Wk,
    const float* __restrict__ Wv, const float* __restrict__ Wd,
    const float* __restrict__ Win, const float* __restrict__ Wout,
    const float* __restrict__ bq, const float* __restrict__ bk,
    const float* __restrict__ bv,
    unsigned short* __restrict__ wqkvT, unsigned short* __restrict__ wdT,
    unsigned short* __restrict__ winT, unsigned short* __restrict__ woutT,
    float* __restrict__ qkvb)
{
  const int bid = blockIdx.x;
  const int tid = threadIdx.x;
  if (bid < 4096) {               // LN1 rows (bf16 out only)
    ln1_body(hs, g1, b1, xbf, bid, tid);
  } else if (bid < 8192) {        // Wq/Wk/Wv/Wd 1024x1024
    const int idx = bid - 4096;
    const int z = idx >> 10, rem = idx & 1023;
    const float* W = (z == 0) ? Wq : (z == 1) ? Wk : (z == 2) ? Wv : Wd;
    unsigned short* WT = (z == 3) ? wdT : wqkvT + (long)z * 1048576;
    transpose_body(W, WT, 1024, 1024, rem & 31, rem >> 5, tid);
  } else if (bid < 10240) {       // Win [4][256][2048]
    const int rem = bid - 8192;
    const int z = rem >> 9, r2 = rem & 511;
    transpose_body(Win + (long)z * 524288, winT + (long)z * 524288,
                   256, 2048, r2 & 63, r2 >> 6, tid);
  } else if (bid < 11264) {       // Wout [4][1024][256]
    const int rem = bid - 10240;
    const int z = rem >> 8, r2 = rem & 255;
    transpose_body(Wout + (long)z * 262144, woutT + (long)z * 262144,
                   1024, 256, r2 & 7, r2 >> 3, tid);
  } else {                        // packb (12 blocks x 256)
    const int i = (bid - 11264) * 256 + tid;
    qkvb[i] = (i < 1024) ? bq[i] : ((i < 2048) ? bk[i - 1024] : bv[i - 2048]);
  }
}

// ---- bf16 MFMA GEMM, 128x128 tile, depth-2 counted-vmcnt pipeline ------
// Optional fused q2/k2 row sum-of-squares (QKV call only).
__global__ __launch_bounds__(256) void mfma_gemm_kernel(
    const unsigned short* __restrict__ A, int lda, long agoff,
    const unsigned short* __restrict__ BT, long bgoff, int K,
    const float* __restrict__ bias, int biasoff,
    unsigned short* __restrict__ Cbf, float* __restrict__ Cf,
    int ldc, int cgoff,
    float* __restrict__ q2g, float* __restrict__ k2g)
{
  const int g = blockIdx.z;
  const unsigned short* Ag = A + (long)g * agoff;
  const unsigned short* Bg = BT + (long)g * bgoff;
  const float* biasg = bias + (long)g * biasoff;
  const int row0 = blockIdx.y * 128, col0 = blockIdx.x * 128;
  __shared__ __align__(16) unsigned short As[2][128 * 64];
  __shared__ __align__(16) unsigned short Bs[2][128 * 64];
  const int tid = threadIdx.x;
  const int w = tid >> 6, l = tid & 63;
  const int ms = (w & 1) << 6, ns = (w >> 1) << 6;
  const int fr = l & 15, fg = l >> 4;
  const int lr8 = l >> 3, ls8 = l & 7;
  const int scol = (ls8 ^ lr8) << 3;
  const int rsw = fr & 7;
  f32x4 acc[4][4];
  #pragma unroll
  for (int i = 0; i < 4; ++i)
    #pragma unroll
    for (int j = 0; j < 4; ++j) acc[i][j] = (f32x4)0.0f;

  const int nt = K >> 6;   // requires K >= 128
  #pragma unroll
  for (int sidx = 0; sidx < 2; ++sidx) {
    const int k0 = sidx << 6;
    #pragma unroll
    for (int g8 = 0; g8 < 4; ++g8) {
      const int r = (w << 5) + (g8 << 3);
      gload16(Ag + (long)(row0 + r + lr8) * lda + k0 + scol, &As[sidx][r * 64]);
      gload16(Bg + (long)(col0 + r + lr8) * K  + k0 + scol, &Bs[sidx][r * 64]);
    }
  }
  int cur = 0;
  for (int t = 0; t < nt; ++t) {
    if (t + 1 < nt) asm volatile("s_waitcnt vmcnt(8)" ::: "memory");
    else            asm volatile("s_waitcnt vmcnt(0)" ::: "memory");
    __builtin_amdgcn_s_barrier();
    __builtin_amdgcn_sched_barrier(0);
    short8 af[2][4], bfr[2][4];
    #pragma unroll
    for (int ks = 0; ks < 2; ++ks) {
      const int rslot = (((ks << 2) + fg) ^ rsw) << 3;
      #pragma unroll
      for (int i = 0; i < 4; ++i) {
        af[ks][i]  = *(const short8*)&As[cur][(ms + i*16 + fr) * 64 + rslot];
        bfr[ks][i] = *(const short8*)&Bs[cur][(ns + i*16 + fr) * 64 + rslot];
      }
    }
    asm volatile("s_waitcnt lgkmcnt(0)" ::: "memory");
    __builtin_amdgcn_sched_barrier(0);
    __builtin_amdgcn_s_barrier();
    if (t + 2 < nt) {
      const int k0 = (t + 2) << 6;
      #pragma unroll
      for (int g8 = 0; g8 < 4; ++g8) {
        const int r = (w << 5) + (g8 << 3);
        gload16(Ag + (long)(row0 + r + lr8) * lda + k0 + scol, &As[cur][r * 64]);
        gload16(Bg + (long)(col0 + r + lr8) * K  + k0 + scol, &Bs[cur][r * 64]);
      }
    }
    __builtin_amdgcn_s_setprio(1);
    #pragma unroll
    for (int ks = 0; ks < 2; ++ks)
      #pragma unroll
      for (int i = 0; i < 4; ++i)
        #pragma unroll
        for (int j = 0; j < 4; ++j)
          acc[i][j] = __builtin_amdgcn_mfma_f32_16x16x32_bf16(bfr[ks][j], af[ks][i], acc[i][j], 0, 0, 0);
    __builtin_amdgcn_s_setprio(0);
    cur ^= 1;
  }

  float s2[4] = {0.f, 0.f, 0.f, 0.f};
  #pragma unroll
  for (int j = 0; j < 4; ++j) {
    const float4 bj4 = *(const float4*)(biasg + col0 + ns + j*16 + (fg << 2));
    #pragma unroll
    for (int i = 0; i < 4; ++i) {
      const long row = row0 + ms + i*16 + fr;
      const long cb = row * ldc + (long)g * cgoff + col0 + ns + j*16 + (fg << 2);
      const float v0 = acc[i][j][0] + bj4.x, v1 = acc[i][j][1] + bj4.y;
      const float v2 = acc[i][j][2] + bj4.z, v3 = acc[i][j][3] + bj4.w;
      s2[i] += v0*v0 + v1*v1 + v2*v2 + v3*v3;
      if (Cbf) {
        uint2 pk; pk.x = cvtpk(v0, v1); pk.y = cvtpk(v2, v3);
        *(uint2*)(Cbf + cb) = pk;
      } else {
        f32x4 o = {v0, v1, v2, v3};
        __builtin_nontemporal_store(o, (f32x4*)(Cf + cb));
      }
    }
  }
  // fused q2/k2 (QKV only): n-range [col0+ns, col0+ns+64) = one head's d.
  if (q2g && col0 < 2048) {
    const int nsAbs = col0 + ns;
    const bool isQ = nsAbs < 1024;
    float* outp = isQ ? q2g : k2g;
    const int head = (isQ ? nsAbs : nsAbs - 1024) >> 6;
    #pragma unroll
    for (int i = 0; i < 4; ++i) {
      float s = s2[i];
      s += __shfl_xor(s, 16);
      s += __shfl_xor(s, 32);
      if (fg == 0) {
        const int gr = row0 + ms + i*16 + fr;          // s*4+b
        outp[((gr & 3) * 16 + head) * 1024 + (gr >> 2)] = s;
      }
    }
  }
}

// ---- bf16 MFMA GEMM, 128x64 tile, depth-2 pipeline (stage = 6 loads) ----
__global__ __launch_bounds__(256) void mfma_gemm64_kernel(
    const unsigned short* __restrict__ A, int lda, long agoff,
    const unsigned short* __restrict__ BT, long bgoff, int K,
    const float* __restrict__ bias, int biasoff,
    unsigned short* __restrict__ Cbf, float* __restrict__ Cf,
    int ldc, int cgoff)
{
  const int g = blockIdx.z;
  const unsigned short* Ag = A + (long)g * agoff;
  const unsigned short* Bg = BT + (long)g * bgoff;
  const float* biasg = bias + (long)g * biasoff;
  const int row0 = blockIdx.y * 128, col0 = blockIdx.x * 64;
  __shared__ __align__(16) unsigned short As[2][128 * 64];
  __shared__ __align__(16) unsigned short Bs[2][64 * 64];
  const int tid = threadIdx.x;
  const int w = tid >> 6, l = tid & 63;
  const int ms = (w & 1) << 6, ns = (w >> 1) << 5;
  const int fr = l & 15, fg = l >> 4;
  const int lr8 = l >> 3, ls8 = l & 7;
  const int scol = (ls8 ^ lr8) << 3;
  const int rsw = fr & 7;
  f32x4 acc[4][2];
  #pragma unroll
  for (int i = 0; i < 4; ++i)
    #pragma unroll
    for (int j = 0; j < 2; ++j) acc[i][j] = (f32x4)0.0f;

  const int nt = K >> 6;
  #pragma unroll
  for (int sidx = 0; sidx < 2; ++sidx) {
    const int k0 = sidx << 6;
    #pragma unroll
    for (int g8 = 0; g8 < 4; ++g8) {
      const int r = (w << 5) + (g8 << 3);
      gload16(Ag + (long)(row0 + r + lr8) * lda + k0 + scol, &As[sidx][r * 64]);
    }
    #pragma unroll
    for (int g8 = 0; g8 < 2; ++g8) {
      const int r = (w << 4) + (g8 << 3);
      gload16(Bg + (long)(col0 + r + lr8) * K + k0 + scol, &Bs[sidx][r * 64]);
    }
  }
  int cur = 0;
  for (int t = 0; t < nt; ++t) {
    if (t + 1 < nt) asm volatile("s_waitcnt vmcnt(6)" ::: "memory");
    else            asm volatile("s_waitcnt vmcnt(0)" ::: "memory");
    __builtin_amdgcn_s_barrier();
    __builtin_amdgcn_sched_barrier(0);
    short8 af[2][4], bfr[2][2];
    #pragma unroll
    for (int ks = 0; ks < 2; ++ks) {
      const int rslot = (((ks << 2) + fg) ^ rsw) << 3;
      #pragma unroll
      for (int i = 0; i < 4; ++i)
        af[ks][i] = *(const short8*)&As[cur][(ms + i*16 + fr) * 64 + rslot];
      #pragma unroll
      for (int j = 0; j < 2; ++j)
        bfr[ks][j] = *(const short8*)&Bs[cur][(ns + j*16 + fr) * 64 + rslot];
    }
    asm volatile("s_waitcnt lgkmcnt(0)" ::: "memory");
    __builtin_amdgcn_sched_barrier(0);
    __builtin_amdgcn_s_barrier();
    if (t + 2 < nt) {
      const int k0 = (t + 2) << 6;
      #pragma unroll
      for (int g8 = 0; g8 < 4; ++g8) {
        const int r = (w << 5) + (g8 << 3);
        gload16(Ag + (long)(row0 + r + lr8) * lda + k0 + scol, &As[cur][r * 64]);
      }
      #pragma unroll
      for (int g8 = 0; g8 < 2; ++g8) {
        const int r = (w << 4) + (g8 << 3);
        gload16(Bg + (long)(col0 + r + lr8) * K + k0 + scol, &Bs[cur][r * 64]);
      }
    }
    __builtin_amdgcn_s_setprio(1);
    #pragma unroll
    for (int ks = 0; ks < 2; ++ks)
      #pragma unroll
      for (int i = 0; i < 4; ++i)
        #pragma unroll
        for (int j = 0; j < 2; ++j)
          acc[i][j] = __builtin_amdgcn_mfma_f32_16x16x32_bf16(bfr[ks][j], af[ks][i], acc[i][j], 0, 0, 0);
    __builtin_amdgcn_s_setprio(0);
    cur ^= 1;
  }

  #pragma unroll
  for (int j = 0; j < 2; ++j) {
    const float4 bj4 = *(const float4*)(biasg + col0 + ns + j*16 + (fg << 2));
    #pragma unroll
    for (int i = 0; i < 4; ++i) {
      const long row = row0 + ms + i*16 + fr;
      const long cb = row * ldc + (long)g * cgoff + col0 + ns + j*16 + (fg << 2);
      const float v0 = acc[i][j][0] + bj4.x, v1 = acc[i][j][1] + bj4.y;
      const float v2 = acc[i][j][2] + bj4.z, v3 = acc[i][j][3] + bj4.w;
      if (Cbf) {
        uint2 pk; pk.x = cvtpk(v0, v1); pk.y = cvtpk(v2, v3);
        *(uint2*)(Cbf + cb) = pk;
      } else {
        f32x4 o = {v0, v1, v2, v3};
        __builtin_nontemporal_store(o, (f32x4*)(Cf + cb));
      }
    }
  }
}

// ---- grouped dense_in + GLU, 128x64 tile, depth-2 pipeline (stage=8) ----
__global__ __launch_bounds__(256) void mfma_glu_kernel(
    const unsigned short* __restrict__ A,   // ctx2 [4096][1024]
    const unsigned short* __restrict__ WT,  // [g][2048][256]
    const float* __restrict__ bin,          // [4][2048]
    unsigned short* __restrict__ H2)        // [4096][4096]
{
  const int g = blockIdx.z;
  const unsigned short* Ag = A + g * 256;
  const unsigned short* Wg = WT + (long)g * 2048 * 256;
  const float* bg = bin + g * 2048;
  const int row0 = blockIdx.y * 128, col0 = blockIdx.x * 64;
  __shared__ __align__(16) unsigned short As[2][128 * 64];
  __shared__ __align__(16) unsigned short Bxs[2][64 * 64];
  __shared__ __align__(16) unsigned short Bys[2][64 * 64];
  const int tid = threadIdx.x;
  const int w = tid >> 6, l = tid & 63;
  const int ms = (w & 1) << 6, ns = (w >> 1) << 5;
  const int fr = l & 15, fg = l >> 4;
  const int lr8 = l >> 3, ls8 = l & 7;
  const int scol = (ls8 ^ lr8) << 3;
  const int rsw = fr & 7;
  f32x4 ax[4][2], ay[4][2];
  #pragma unroll
  for (int i = 0; i < 4; ++i)
    #pragma unroll
    for (int j = 0; j < 2; ++j) { ax[i][j] = (f32x4)0.0f; ay[i][j] = (f32x4)0.0f; }

  #pragma unroll
  for (int sidx = 0; sidx < 2; ++sidx) {
    const int k0 = sidx << 6;
    #pragma unroll
    for (int g8 = 0; g8 < 4; ++g8) {
      const int r = (w << 5) + (g8 << 3);
      gload16(Ag + (long)(row0 + r + lr8) * 1024 + k0 + scol, &As[sidx][r * 64]);
    }
    #pragma unroll
    for (int g8 = 0; g8 < 2; ++g8) {
      const int r = (w << 4) + (g8 << 3);
      gload16(Wg + (long)(col0 + r + lr8) * 256 + k0 + scol,        &Bxs[sidx][r * 64]);
      gload16(Wg + (long)(1024 + col0 + r + lr8) * 256 + k0 + scol, &Bys[sidx][r * 64]);
    }
  }
  int cur = 0;
  for (int t = 0; t < 4; ++t) {
    if (t + 1 < 4) asm volatile("s_waitcnt vmcnt(8)" ::: "memory");
    else           asm volatile("s_waitcnt vmcnt(0)" ::: "memory");
    __builtin_amdgcn_s_barrier();
    __builtin_amdgcn_sched_barrier(0);
    short8 af[2][4], bx[2][2], by[2][2];
    #pragma unroll
    for (int ks = 0; ks < 2; ++ks) {
      const int rslot = (((ks << 2) + fg) ^ rsw) << 3;
      #pragma unroll
      for (int i = 0; i < 4; ++i)
        af[ks][i] = *(const short8*)&As[cur][(ms + i*16 + fr) * 64 + rslot];
      #pragma unroll
      for (int j = 0; j < 2; ++j) {
        bx[ks][j] = *(const short8*)&Bxs[cur][(ns + j*16 + fr) * 64 + rslot];
        by[ks][j] = *(const short8*)&Bys[cur][(ns + j*16 + fr) * 64 + rslot];
      }
    }
    asm volatile("s_waitcnt lgkmcnt(0)" ::: "memory");
    __builtin_amdgcn_sched_barrier(0);
    __builtin_amdgcn_s_barrier();
    if (t + 2 < 4) {
      const int k0 = (t + 2) << 6;
      #pragma unroll
      for (int g8 = 0; g8 < 4; ++g8) {
        const int r = (w << 5) + (g8 << 3);
        gload16(Ag + (long)(row0 + r + lr8) * 1024 + k0 + scol, &As[cur][r * 64]);
      }
      #pragma unroll
      for (int g8 = 0; g8 < 2; ++g8) {
        const int r = (w << 4) + (g8 << 3);
        gload16(Wg + (long)(col0 + r + lr8) * 256 + k0 + scol,        &Bxs[cur][r * 64]);
        gload16(Wg + (long)(1024 + col0 + r + lr8) * 256 + k0 + scol, &Bys[cur][r * 64]);
      }
    }
    __builtin_amdgcn_s_setprio(1);
    #pragma unroll
    for (int ks = 0; ks < 2; ++ks)
      #pragma unroll
      for (int i = 0; i < 4; ++i)
        #pragma unroll
        for (int j = 0; j < 2; ++j) {
          ax[i][j] = __builtin_amdgcn_mfma_f32_16x16x32_bf16(bx[ks][j], af[ks][i], ax[i][j], 0, 0, 0);
          ay[i][j] = __builtin_amdgcn_mfma_f32_16x16x32_bf16(by[ks][j], af[ks][i], ay[i][j], 0, 0, 0);
        }
    __builtin_amdgcn_s_setprio(0);
    cur ^= 1;
  }

  #pragma unroll
  for (int j = 0; j < 2; ++j) {
    const float4 bx4 = *(const float4*)(bg + col0 + ns + j*16 + (fg << 2));
    const float4 by4 = *(const float4*)(bg + 1024 + col0 + ns + j*16 + (fg << 2));
    #pragma unroll
    for (int i = 0; i < 4; ++i) {
      const long row = row0 + ms + i*16 + fr;
      const long cb = row * 4096 + g * 1024 + col0 + ns + j*16 + (fg << 2);
      float o4[4];
      const float* bxp = &bx4.x; const float* byp = &by4.x;
      #pragma unroll
      for (int r4 = 0; r4 < 4; ++r4) {
        const float xh = ax[i][j][r4] + bxp[r4];
        const float yh = ay[i][j][r4] + byp[r4];
        o4[r4] = xh * fmaxf(yh, 0.0f);
      }
      uint2 pk; pk.x = cvtpk(o4[0], o4[1]); pk.y = cvtpk(o4[2], o4[3]);
      *(uint2*)(H2 + cb) = pk;
    }
  }
}

// -------- V transpose only: qkv v-part [s*4+b][.] -> vt [n][d][s] ---------
__global__ __launch_bounds__(256) void vtrans_kernel(
    const unsigned short* __restrict__ qkv, unsigned short* __restrict__ vt)
{
  __shared__ unsigned short T[64][72];
  const int n = blockIdx.y, s0 = blockIdx.x * 64;
  const int b = n >> 4, hoff = (n & 15) * 64;
  const int tid = threadIdx.x;
  #pragma unroll
  for (int p = 0; p < 2; ++p) {
    const int r = (tid >> 3) + p * 32, c = (tid & 7) << 3;
    *(short8*)&T[r][c] = *(const short8*)(qkv + ((long)((s0 + r) * 4 + b)) * 3072 + 2048 + hoff + c);
  }
  __syncthreads();
  #pragma unroll
  for (int p = 0; p < 2; ++p) {
    const int d = (tid >> 3) + p * 32, sc = (tid & 7) << 3;
    short8 o;
    #pragma unroll
    for (int j = 0; j < 8; ++j) o[j] = (short)T[sc + j][d];
    *(short8*)(vt + ((long)n * 64 + d) * 1024 + s0 + sc) = o;
  }
}

// --- MFMA attention, counted-vmcnt K/V pipeline, fused residual+LN2 ------
// grid (16 s-tiles, 64 heads). Residual from bf16 xbf.
__global__ __launch_bounds__(256) void attn_kernel(
    const unsigned short* __restrict__ qkv, const unsigned short* __restrict__ vt,
    const float* __restrict__ q2g, const float* __restrict__ k2g,
    const unsigned short* __restrict__ xbf, const float* __restrict__ g2,
    const float* __restrict__ b2,
    unsigned short* __restrict__ ctx2, float* __restrict__ scores)
{
  const int n = blockIdx.y;
  const int s0 = blockIdx.x * 64;
  const int b = n >> 4, hoff = (n & 15) * 64;
  __shared__ __align__(16) unsigned short Qs[64 * 64];
  __shared__ __align__(16) unsigned short Ks[2][64 * 64];
  __shared__ __align__(16) unsigned short VTl[2][64 * 64];
  __shared__ __align__(16) unsigned short Ps[64 * 64];
  __shared__ float k2s[1024];
  const int tid = threadIdx.x, w = tid >> 6, l = tid & 63;
  const int fr = l & 15, fg = l >> 4;
  const int lr8 = l >> 3, ls8 = l & 7;
  const int sslot = ((ls8 ^ lr8) << 3);
  const int rsw = fr & 7;

  #pragma unroll
  for (int p = 0; p < 2; ++p) {
    const int r = (tid >> 3) + p * 32, cs = tid & 7;
    *(short8*)&Qs[r * 64 + ((cs ^ (r & 7)) << 3)] =
        *(const short8*)(qkv + ((long)((s0 + r) * 4 + b)) * 3072 + hoff + (cs << 3));
  }
  *(float4*)&k2s[tid << 2] = *(const float4*)(k2g + n * 1024 + (tid << 2));
  float q2m[4];
  #pragma unroll
  for (int i = 0; i < 4; ++i) q2m[i] = -0.0625f * q2g[n * 1024 + s0 + i*16 + fr];
  #pragma unroll
  for (int p = 0; p < 2; ++p) {
    const int rowb = p * 32 + w * 8;
    gload16(qkv + ((long)((rowb + lr8) * 4 + b)) * 3072 + 1024 + hoff + sslot, &Ks[0][rowb * 64]);
    gload16(vt + ((long)n * 64 + rowb + lr8) * 1024 + sslot,                   &VTl[0][rowb * 64]);
  }
  __syncthreads();

  f32x4 o[4];
  #pragma unroll
  for (int i = 0; i < 4; ++i) o[i] = (f32x4)0.0f;

  int cur = 0;
  for (int t0 = 0; t0 < 1024; t0 += 64) {
    if (t0 > 0) {
      asm volatile("s_waitcnt vmcnt(4)" ::: "memory");
      __builtin_amdgcn_sched_barrier(0);
      __builtin_amdgcn_s_barrier();
    }
    f32x4 c4[4];
    #pragma unroll
    for (int i = 0; i < 4; ++i) c4[i] = (f32x4)0.0f;
    #pragma unroll
    for (int ks = 0; ks < 2; ++ks) {
      const short8 kf = *(const short8*)&Ks[cur][((w << 4) + fr) * 64 + ((((ks << 2) + fg) ^ rsw) << 3)];
      #pragma unroll
      for (int i = 0; i < 4; ++i) {
        const short8 qf = *(const short8*)&Qs[(i*16 + fr) * 64 + ((((ks << 2) + fg) ^ rsw) << 3)];
        c4[i] = __builtin_amdgcn_mfma_f32_16x16x32_bf16(kf, qf, c4[i], 0, 0, 0);
      }
    }
    if (t0 + 64 < 1024) {
      #pragma unroll
      for (int p = 0; p < 2; ++p) {
        const int rowb = p * 32 + w * 8;
        gload16(qkv + ((long)((t0 + 64 + rowb + lr8) * 4 + b)) * 3072 + 1024 + hoff + sslot,
                &Ks[cur ^ 1][rowb * 64]);
        gload16(vt + ((long)n * 64 + rowb + lr8) * 1024 + t0 + 64 + sslot,
                &VTl[cur ^ 1][rowb * 64]);
      }
    }
    const float4 k2v4 = *(const float4*)&k2s[t0 + (w << 4) + (fg << 2)];
    const float k2m[4] = {-0.0625f*k2v4.x, -0.0625f*k2v4.y, -0.0625f*k2v4.z, -0.0625f*k2v4.w};
    #pragma unroll
    for (int i = 0; i < 4; ++i) {
      f32x4 sc;
      float pe[4];
      #pragma unroll
      for (int r4 = 0; r4 < 4; ++r4) {
        const float m = fmaf(c4[i][r4], 0.125f, q2m[i] + k2m[r4]);
        sc[r4] = m;
        pe[r4] = __expf(m);
      }
      __builtin_nontemporal_store(sc,
          (f32x4*)(scores + (long)n * 1048576 + (long)(s0 + i*16 + fr) * 1024 + t0 + (w << 4) + (fg << 2)));
      const int slot = (w << 1) + (fg >> 1);
      const int pc = ((slot ^ (fr & 7)) << 3) + ((fg & 1) << 2);
      uint2 pk; pk.x = cvtpk(pe[0], pe[1]); pk.y = cvtpk(pe[2], pe[3]);
      *(uint2*)&Ps[(i*16 + fr) * 64 + pc] = pk;
    }
    asm volatile("s_waitcnt lgkmcnt(0)" ::: "memory");
    __builtin_amdgcn_sched_barrier(0);
    __builtin_amdgcn_s_barrier();
    #pragma unroll
    for (int ks = 0; ks < 2; ++ks) {
      const short8 vb = *(const short8*)&VTl[cur][((w << 4) + fr) * 64 + ((((ks << 2) + fg) ^ rsw) << 3)];
      #pragma unroll
      for (int i = 0; i < 4; ++i) {
        const short8 pf = *(const short8*)&Ps[(i*16 + fr) * 64 + ((((ks << 2) + fg) ^ rsw) << 3)];
        o[i] = __builtin_amdgcn_mfma_f32_16x16x32_bf16(vb, pf, o[i], 0, 0, 0);
      }
    }
    asm volatile("s_waitcnt lgkmcnt(0)" ::: "memory");
    __builtin_amdgcn_sched_barrier(0);
    __builtin_amdgcn_s_barrier();
    cur ^= 1;
  }

  // ---- fused residual (bf16 x) + per-head LN2 -> ctx2 bf16 ----
  const int dbase = (w << 4) + (fg << 2);
  float xf[4][4];
  #pragma unroll
  for (int i = 0; i < 4; ++i) {
    const ushort4 xu = *(const ushort4*)(xbf + ((long)((s0 + i*16 + fr) * 4 + b)) * 1024 + hoff + dbase);
    xf[i][0] = bf2f(xu.x); xf[i][1] = bf2f(xu.y);
    xf[i][2] = bf2f(xu.z); xf[i][3] = bf2f(xu.w);
  }

  float* redbuf = (float*)&Ps[0];
  const int slot = (w << 2) + fg;
  #pragma unroll
  for (int i = 0; i < 4; ++i) {
    float s = 0.f, ss = 0.f;
    #pragma unroll
    for (int r4 = 0; r4 < 4; ++r4) {
      const float v = o[i][r4] + xf[i][r4];
      s += v; ss = fmaf(v, v, ss);
    }
    redbuf[(i*16 + fr) * 16 + slot] = s;
    redbuf[1024 + (i*16 + fr) * 16 + slot] = ss;
  }
  __syncthreads();
  float* statbuf = (float*)&Qs[0];
  {
    const int row = tid >> 2, q4 = tid & 3;
    float s = 0.f, ss = 0.f;
    #pragma unroll
    for (int k = 0; k < 4; ++k) {
      s  += redbuf[row * 16 + q4 * 4 + k];
      ss += redbuf[1024 + row * 16 + q4 * 4 + k];
    }
    s  += __shfl_xor(s, 1);  s  += __shfl_xor(s, 2);
    ss += __shfl_xor(ss, 1); ss += __shfl_xor(ss, 2);
    if (q4 == 0) {
      const float mean = s * (1.0f/64.0f);
      const float var  = ss * (1.0f/64.0f) - mean * mean;
      statbuf[row] = mean;
      statbuf[64 + row] = rsqrtf(var + 1e-6f);
    }
  }
  __syncthreads();
  const float4 g2v = *(const float4*)(g2 + dbase);
  const float4 b2v = *(const float4*)(b2 + dbase);
  const float* gp = &g2v.x; const float* bp = &b2v.x;
  #pragma unroll
  for (int i = 0; i < 4; ++i) {
    const float mean = statbuf[i*16 + fr];
    const float rs   = statbuf[64 + i*16 + fr];
    float vo[4];
    #pragma unroll
    for (int r4 = 0; r4 < 4; ++r4)
      vo[r4] = (o[i][r4] + xf[i][r4] - mean) * rs * gp[r4] + bp[r4];
    uint2 pk; pk.x = cvtpk(vo[0], vo[1]); pk.y = cvtpk(vo[2], vo[3]);
    *(uint2*)(ctx2 + ((long)((s0 + i*16 + fr) * 4 + b)) * 1024 + hoff + dbase) = pk;
  }
}

extern "C" void kernel_launch(void* const* d_in, const int* in_sizes, int n_in,
                              void* d_out, int out_size, void* d_ws, size_t ws_size,
                              hipStream_t stream) {
  const float* hs   = (const float*)d_in[0];
  const float* g1   = (const float*)d_in[1];
  const float* b1   = (const float*)d_in[2];
  const float* g2   = (const float*)d_in[3];
  const float* b2   = (const float*)d_in[4];
  const float* Wq   = (const float*)d_in[5];
  const float* bq   = (const float*)d_in[6];
  const float* Wk   = (const float*)d_in[7];
  const float* bk   = (const float*)d_in[8];
  const float* Wv   = (const float*)d_in[9];
  const float* bv   = (const float*)d_in[10];
  const float* Win  = (const float*)d_in[11];
  const float* bin  = (const float*)d_in[12];
  const float* Wout = (const float*)d_in[13];
  const float* bout = (const float*)d_in[14];
  const float* Wd   = (const float*)d_in[15];
  const float* bd   = (const float*)d_in[16];

  // ws layout (bytes), verified DISJOINT live ranges:
  //   qkv  [0,        25165824)   live: qkv-gemm .. attn end
  //   xbf  [25165824, 33554432)   live: prep .. attn end
  //   ctx2 [33554432, 41943040)   live: attn .. glu
  //   vt   [41943040, 50331648)   live: vtrans .. attn end
  //   weights/qkvb/q2g/k2g [50331648, 65548288)
  // Overlays (strictly after attn completes):
  //   h2 [0, 33554432) over qkv+xbf;  og [41943040, 50331648) over vt.
  char* ws = (char*)d_ws;
  unsigned short* qkv   = (unsigned short*)(ws + 0);
  unsigned short* xbf   = (unsigned short*)(ws + 25165824);
  unsigned short* ctx2  = (unsigned short*)(ws + 33554432);
  unsigned short* vt    = (unsigned short*)(ws + 41943040);
  unsigned short* wqkvT = (unsigned short*)(ws + 50331648);
  unsigned short* winT  = (unsigned short*)(ws + 56623104);
  unsigned short* woutT = (unsigned short*)(ws + 60817408);
  unsigned short* wdT   = (unsigned short*)(ws + 62914560);
  float*          qkvb  = (float*)(ws + 65011712);
  float*          q2g   = (float*)(ws + 65024000);
  float*          k2g   = (float*)(ws + 65286144);
  unsigned short* h2    = (unsigned short*)(ws + 0);
  unsigned short* og    = (unsigned short*)(ws + 41943040);

  float* out0 = (float*)d_out;           // [S,B,H]
  float* out1 = out0 + 4194304;          // [64,1024,1024]

  prep_all_kernel<<<11276, 256, 0, stream>>>(
      hs, g1, b1, xbf,
      Wq, Wk, Wv, Wd, Win, Wout, bq, bk, bv,
      wqkvT, wdT, winT, woutT, qkvb);

  // QKV: [4096,1024]@[1024,3072] -> qkv bf16 (+ fused q2/k2), proven kernel
  mfma_gemm_kernel<<<dim3(24,32,1), 256, 0, stream>>>(
      xbf, 1024, 0, wqkvT, 0, 1024, qkvb, 0, qkv, nullptr, 3072, 0, q2g, k2g);

  vtrans_kernel<<<dim3(16,64), 256, 0, stream>>>(qkv, vt);

  attn_kernel<<<dim3(16,64), 256, 0, stream>>>(qkv, vt, q2g, k2g, xbf, g2, b2, ctx2, out1);

  mfma_glu_kernel<<<dim3(16,32,4), 256, 0, stream>>>(ctx2, winT, bin, h2);

  // FFN-out: per group -> og bf16
  mfma_gemm64_kernel<<<dim3(4,32,4), 256, 0, stream>>>(
      h2, 4096, 1024, woutT, 262144, 1024, bout, 256, og, nullptr, 1024, 256);

  // dense: [4096,1024]@[1024,1024] -> out0 fp32 (NT store)
  mfma_gemm64_kernel<<<dim3(16,32,1), 256, 0, stream>>>(
      og, 1024, 0, wdT, 0, 1024, bd, 0, nullptr, out0, 1024, 0);
}

// Round 17
// 224.518 us; speedup vs baseline: 1.2132x; 1.0023x over previous
//
#include <hip/hip_runtime.h>

// TransformerLayer_Combined on gfx950 — bf16 MFMA pipeline.
// QKV: 256^2 / 8-wave depth-2 counted-vmcnt (split-ks). Other GEMMs:
// 128-tile depth-2 counted-vmcnt. attn fuses residual (bf16 x) + LN2.

typedef __attribute__((ext_vector_type(8))) short short8;
typedef __attribute__((ext_vector_type(4))) float f32x4;

__device__ __forceinline__ unsigned short f2bf(float f) {
  union { float f; unsigned u; } x; x.f = f;
  unsigned r = x.u + 0x7FFFu + ((x.u >> 16) & 1u);
  return (unsigned short)(r >> 16);
}
__device__ __forceinline__ float bf2f(unsigned short u) {
  union { float f; unsigned u; } x; x.u = ((unsigned)u) << 16;
  return x.f;
}
__device__ __forceinline__ unsigned cvtpk(float a, float b) {  // [lo=a, hi=b]
  unsigned r;
  asm("v_cvt_pk_bf16_f32 %0, %1, %2" : "=v"(r) : "v"(a), "v"(b));
  return r;
}
// async 16B global->LDS (dest = wave-uniform base + lane*16)
__device__ __forceinline__ void gload16(const unsigned short* g, unsigned short* l) {
  __builtin_amdgcn_global_load_lds(
      (const __attribute__((address_space(1))) unsigned int*)g,
      (__attribute__((address_space(3))) unsigned int*)l, 16, 0, 0);
}

// ---- merged LN1 + weight prep, one launch --------------------------------
__device__ __forceinline__ void ln1_body(
    const float* __restrict__ x, const float* __restrict__ g,
    const float* __restrict__ b,
    unsigned short* __restrict__ ybf, int row, int tid)
{
  const long base = (long)row * 1024;
  const int c = tid * 4;
  float4 v = *(const float4*)(x + base + c);
  float s = v.x + v.y + v.z + v.w;
  float ss = v.x*v.x + v.y*v.y + v.z*v.z + v.w*v.w;
  #pragma unroll
  for (int off = 32; off > 0; off >>= 1) {
    s  += __shfl_xor(s, off);
    ss += __shfl_xor(ss, off);
  }
  __shared__ float sw[4], ssw[4];
  const int wave = tid >> 6;
  if ((tid & 63) == 0) { sw[wave] = s; ssw[wave] = ss; }
  __syncthreads();
  s  = sw[0] + sw[1] + sw[2] + sw[3];
  ss = ssw[0] + ssw[1] + ssw[2] + ssw[3];
  const float mean = s * (1.0f/1024.0f);
  const float var  = ss * (1.0f/1024.0f) - mean*mean;
  const float rs   = rsqrtf(var + 1e-6f);
  const float4 gv = *(const float4*)(g + c);
  const float4 bv = *(const float4*)(b + c);
  const float o0 = (v.x - mean) * rs * gv.x + bv.x;
  const float o1 = (v.y - mean) * rs * gv.y + bv.y;
  const float o2 = (v.z - mean) * rs * gv.z + bv.z;
  const float o3 = (v.w - mean) * rs * gv.w + bv.w;
  uint2 pk; pk.x = cvtpk(o0, o1); pk.y = cvtpk(o2, o3);
  *(uint2*)(ybf + base + c) = pk;
}

__device__ __forceinline__ void transpose_body(
    const float* __restrict__ Wg, unsigned short* __restrict__ WTg,
    int K, int N, int bx, int by, int tid)
{
  __shared__ float T[32][33];
  const int n0 = bx * 32, k0 = by * 32;
  const int r = tid >> 3, c4 = (tid & 7) * 4;
  float4 v = *(const float4*)(Wg + (long)(k0 + r) * N + n0 + c4);
  T[r][c4+0] = v.x; T[r][c4+1] = v.y; T[r][c4+2] = v.z; T[r][c4+3] = v.w;
  __syncthreads();
  ushort4 o;
  o.x = f2bf(T[c4+0][r]); o.y = f2bf(T[c4+1][r]);
  o.z = f2bf(T[c4+2][r]); o.w = f2bf(T[c4+3][r]);
  *(ushort4*)(WTg + (long)(n0 + r) * K + k0 + c4) = o;
}

__global__ __launch_bounds__(256) void prep_all_kernel(
    const float* __restrict__ hs, const float* __restrict__ g1,
    const float* __restrict__ b1,
    unsigned short* __restrict__ xbf,
    const float* __restrict__ Wq, const float* __restrict__ Wk,
    const float* __restrict__ Wv, const float* __restrict__ Wd,
    const float* __restrict__ Win, const float* __restrict__ Wout,
    const float* __restrict__ bq, const float* __restrict__ bk,
    const float* __restrict__ bv,
    unsigned short* __restrict__ wqkvT, unsigned short* __restrict__ wdT,
    unsigned short* __restrict__ winT, unsigned short* __restrict__ woutT,
    float* __restrict__ qkvb)
{
  const int bid = blockIdx.x;
  const int tid = threadIdx.x;
  if (bid < 4096) {               // LN1 rows (bf16 out only)
    ln1_body(hs, g1, b1, xbf, bid, tid);
  } else if (bid < 8192) {        // Wq/Wk/Wv/Wd 1024x1024
    const int idx = bid - 4096;
    const int z = idx >> 10, rem = idx & 1023;
    const float* W = (z == 0) ? Wq : (z == 1) ? Wk : (z == 2) ? Wv : Wd;
    unsigned short* WT = (z == 3) ? wdT : wqkvT + (long)z * 1048576;
    transpose_body(W, WT, 1024, 1024, rem & 31, rem >> 5, tid);
  } else if (bid < 10240) {       // Win [4][256][2048]
    const int rem = bid - 8192;
    const int z = rem >> 9, r2 = rem & 511;
    transpose_body(Win + (long)z * 524288, winT + (long)z * 524288,
                   256, 2048, r2 & 63, r2 >> 6, tid);
  } else if (bid < 11264) {       // Wout [4][1024][256]
    const int rem = bid - 10240;
    const int z = rem >> 8, r2 = rem & 255;
    transpose_body(Wout + (long)z * 262144, woutT + (long)z * 262144,
                   1024, 256, r2 & 7, r2 >> 3, tid);
  } else {                        // packb (12 blocks x 256)
    const int i = (bid - 11264) * 256 + tid;
    qkvb[i] = (i < 1024) ? bq[i] : ((i < 2048) ? bk[i - 1024] : bv[i - 2048]);
  }
}

// ---- QKV GEMM: 256x256 tile, 8 waves, depth-2 counted-vmcnt, split-ks ---
__global__ __launch_bounds__(512) void qkv256_kernel(
    const unsigned short* __restrict__ A,
    const unsigned short* __restrict__ BT,
    const float* __restrict__ bias,
    unsigned short* __restrict__ C,
    float* __restrict__ q2g, float* __restrict__ k2g)
{
  const int row0 = blockIdx.y * 256, col0 = blockIdx.x * 256;
  __shared__ __align__(16) unsigned short As[2][256 * 64];
  __shared__ __align__(16) unsigned short Bs[2][256 * 64];
  const int tid = threadIdx.x;
  const int w = tid >> 6, l = tid & 63;
  const int ms = (w >> 2) << 7;   // wave M offset: 0/128
  const int ns = (w & 3) << 6;    // wave N offset: 0/64/128/192
  const int fr = l & 15, fg = l >> 4;
  const int lr8 = l >> 3, ls8 = l & 7;
  const int scol = (ls8 ^ lr8) << 3;
  const int rsw = fr & 7;
  f32x4 acc[8][4];
  #pragma unroll
  for (int i = 0; i < 8; ++i)
    #pragma unroll
    for (int j = 0; j < 4; ++j) acc[i][j] = (f32x4)0.0f;

  #pragma unroll
  for (int sidx = 0; sidx < 2; ++sidx) {   // stage K-tiles 0,1
    const int k0 = sidx << 6;
    #pragma unroll
    for (int g8 = 0; g8 < 4; ++g8) {
      const int rb = (g8 << 6) + (w << 3);
      gload16(A  + (long)(row0 + rb + lr8) * 1024 + k0 + scol, &As[sidx][rb * 64]);
      gload16(BT + (long)(col0 + rb + lr8) * 1024 + k0 + scol, &Bs[sidx][rb * 64]);
    }
  }
  int cur = 0;
  for (int t = 0; t < 16; ++t) {
    if (t < 15) asm volatile("s_waitcnt vmcnt(8)" ::: "memory");
    else        asm volatile("s_waitcnt vmcnt(0)" ::: "memory");
    __builtin_amdgcn_s_barrier();
    __builtin_amdgcn_sched_barrier(0);
    {  // ks = 0: reads + MFMA (compiler-managed lgkm)
      const int rslot = (fg ^ rsw) << 3;
      short8 af[8], b4[4];
      #pragma unroll
      for (int i = 0; i < 8; ++i)
        af[i] = *(const short8*)&As[cur][(ms + i*16 + fr) * 64 + rslot];
      #pragma unroll
      for (int j = 0; j < 4; ++j)
        b4[j] = *(const short8*)&Bs[cur][(ns + j*16 + fr) * 64 + rslot];
      #pragma unroll
      for (int i = 0; i < 8; ++i)
        #pragma unroll
        for (int j = 0; j < 4; ++j)
          acc[i][j] = __builtin_amdgcn_mfma_f32_16x16x32_bf16(b4[j], af[i], acc[i][j], 0, 0, 0);
    }
    // ks = 1: reads, then lgkm+barrier (buf free), refill, MFMA covers refill
    short8 af1[8], b41[4];
    {
      const int rslot = ((4 + fg) ^ rsw) << 3;
      #pragma unroll
      for (int i = 0; i < 8; ++i)
        af1[i] = *(const short8*)&As[cur][(ms + i*16 + fr) * 64 + rslot];
      #pragma unroll
      for (int j = 0; j < 4; ++j)
        b41[j] = *(const short8*)&Bs[cur][(ns + j*16 + fr) * 64 + rslot];
    }
    asm volatile("s_waitcnt lgkmcnt(0)" ::: "memory");
    __builtin_amdgcn_sched_barrier(0);
    __builtin_amdgcn_s_barrier();
    if (t + 2 < 16) {
      const int k0 = (t + 2) << 6;
      #pragma unroll
      for (int g8 = 0; g8 < 4; ++g8) {
        const int rb = (g8 << 6) + (w << 3);
        gload16(A  + (long)(row0 + rb + lr8) * 1024 + k0 + scol, &As[cur][rb * 64]);
        gload16(BT + (long)(col0 + rb + lr8) * 1024 + k0 + scol, &Bs[cur][rb * 64]);
      }
    }
    __builtin_amdgcn_s_setprio(1);
    #pragma unroll
    for (int i = 0; i < 8; ++i)
      #pragma unroll
      for (int j = 0; j < 4; ++j)
        acc[i][j] = __builtin_amdgcn_mfma_f32_16x16x32_bf16(b41[j], af1[i], acc[i][j], 0, 0, 0);
    __builtin_amdgcn_s_setprio(0);
    cur ^= 1;
  }

  // epilogue: lane n = col0+ns+16j+4fg+r4, m = row0+ms+16i+fr
  float s2[8];
  #pragma unroll
  for (int i = 0; i < 8; ++i) s2[i] = 0.f;
  #pragma unroll
  for (int j = 0; j < 4; ++j) {
    const float4 bj4 = *(const float4*)(bias + col0 + ns + j*16 + (fg << 2));
    #pragma unroll
    for (int i = 0; i < 8; ++i) {
      const long row = row0 + ms + i*16 + fr;
      const long cb = row * 3072 + col0 + ns + j*16 + (fg << 2);
      const float v0 = acc[i][j][0] + bj4.x, v1 = acc[i][j][1] + bj4.y;
      const float v2 = acc[i][j][2] + bj4.z, v3 = acc[i][j][3] + bj4.w;
      s2[i] += v0*v0 + v1*v1 + v2*v2 + v3*v3;
      uint2 pk; pk.x = cvtpk(v0, v1); pk.y = cvtpk(v2, v3);
      *(uint2*)(C + cb) = pk;
    }
  }
  const int nsAbs = col0 + ns;      // wave's 64-col span = one head's d-range
  if (nsAbs < 2048) {
    const bool isQ = nsAbs < 1024;
    float* outp = isQ ? q2g : k2g;
    const int head = (isQ ? nsAbs : nsAbs - 1024) >> 6;
    #pragma unroll
    for (int i = 0; i < 8; ++i) {
      float s = s2[i];
      s += __shfl_xor(s, 16);
      s += __shfl_xor(s, 32);
      if (fg == 0) {
        const int gr = row0 + ms + i*16 + fr;          // s*4+b
        outp[((gr & 3) * 16 + head) * 1024 + (gr >> 2)] = s;
      }
    }
  }
}

// ---- bf16 MFMA GEMM, 128x64 tile, depth-2 pipeline (stage = 6 loads) ----
__global__ __launch_bounds__(256) void mfma_gemm64_kernel(
    const unsigned short* __restrict__ A, int lda, long agoff,
    const unsigned short* __restrict__ BT, long bgoff, int K,
    const float* __restrict__ bias, int biasoff,
    unsigned short* __restrict__ Cbf, float* __restrict__ Cf,
    int ldc, int cgoff)
{
  const int g = blockIdx.z;
  const unsigned short* Ag = A + (long)g * agoff;
  const unsigned short* Bg = BT + (long)g * bgoff;
  const float* biasg = bias + (long)g * biasoff;
  const int row0 = blockIdx.y * 128, col0 = blockIdx.x * 64;
  __shared__ __align__(16) unsigned short As[2][128 * 64];
  __shared__ __align__(16) unsigned short Bs[2][64 * 64];
  const int tid = threadIdx.x;
  const int w = tid >> 6, l = tid & 63;
  const int ms = (w & 1) << 6, ns = (w >> 1) << 5;
  const int fr = l & 15, fg = l >> 4;
  const int lr8 = l >> 3, ls8 = l & 7;
  const int scol = (ls8 ^ lr8) << 3;
  const int rsw = fr & 7;
  f32x4 acc[4][2];
  #pragma unroll
  for (int i = 0; i < 4; ++i)
    #pragma unroll
    for (int j = 0; j < 2; ++j) acc[i][j] = (f32x4)0.0f;

  const int nt = K >> 6;
  #pragma unroll
  for (int sidx = 0; sidx < 2; ++sidx) {
    const int k0 = sidx << 6;
    #pragma unroll
    for (int g8 = 0; g8 < 4; ++g8) {
      const int r = (w << 5) + (g8 << 3);
      gload16(Ag + (long)(row0 + r + lr8) * lda + k0 + scol, &As[sidx][r * 64]);
    }
    #pragma unroll
    for (int g8 = 0; g8 < 2; ++g8) {
      const int r = (w << 4) + (g8 << 3);
      gload16(Bg + (long)(col0 + r + lr8) * K + k0 + scol, &Bs[sidx][r * 64]);
    }
  }
  int cur = 0;
  for (int t = 0; t < nt; ++t) {
    if (t + 1 < nt) asm volatile("s_waitcnt vmcnt(6)" ::: "memory");
    else            asm volatile("s_waitcnt vmcnt(0)" ::: "memory");
    __builtin_amdgcn_s_barrier();
    __builtin_amdgcn_sched_barrier(0);
    short8 af[2][4], bfr[2][2];
    #pragma unroll
    for (int ks = 0; ks < 2; ++ks) {
      const int rslot = (((ks << 2) + fg) ^ rsw) << 3;
      #pragma unroll
      for (int i = 0; i < 4; ++i)
        af[ks][i] = *(const short8*)&As[cur][(ms + i*16 + fr) * 64 + rslot];
      #pragma unroll
      for (int j = 0; j < 2; ++j)
        bfr[ks][j] = *(const short8*)&Bs[cur][(ns + j*16 + fr) * 64 + rslot];
    }
    asm volatile("s_waitcnt lgkmcnt(0)" ::: "memory");
    __builtin_amdgcn_sched_barrier(0);
    __builtin_amdgcn_s_barrier();
    if (t + 2 < nt) {
      const int k0 = (t + 2) << 6;
      #pragma unroll
      for (int g8 = 0; g8 < 4; ++g8) {
        const int r = (w << 5) + (g8 << 3);
        gload16(Ag + (long)(row0 + r + lr8) * lda + k0 + scol, &As[cur][r * 64]);
      }
      #pragma unroll
      for (int g8 = 0; g8 < 2; ++g8) {
        const int r = (w << 4) + (g8 << 3);
        gload16(Bg + (long)(col0 + r + lr8) * K + k0 + scol, &Bs[cur][r * 64]);
      }
    }
    __builtin_amdgcn_s_setprio(1);
    #pragma unroll
    for (int ks = 0; ks < 2; ++ks)
      #pragma unroll
      for (int i = 0; i < 4; ++i)
        #pragma unroll
        for (int j = 0; j < 2; ++j)
          acc[i][j] = __builtin_amdgcn_mfma_f32_16x16x32_bf16(bfr[ks][j], af[ks][i], acc[i][j], 0, 0, 0);
    __builtin_amdgcn_s_setprio(0);
    cur ^= 1;
  }

  #pragma unroll
  for (int j = 0; j < 2; ++j) {
    const float4 bj4 = *(const float4*)(biasg + col0 + ns + j*16 + (fg << 2));
    #pragma unroll
    for (int i = 0; i < 4; ++i) {
      const long row = row0 + ms + i*16 + fr;
      const long cb = row * ldc + (long)g * cgoff + col0 + ns + j*16 + (fg << 2);
      const float v0 = acc[i][j][0] + bj4.x, v1 = acc[i][j][1] + bj4.y;
      const float v2 = acc[i][j][2] + bj4.z, v3 = acc[i][j][3] + bj4.w;
      if (Cbf) {
        uint2 pk; pk.x = cvtpk(v0, v1); pk.y = cvtpk(v2, v3);
        *(uint2*)(Cbf + cb) = pk;
      } else {
        f32x4 o = {v0, v1, v2, v3};
        __builtin_nontemporal_store(o, (f32x4*)(Cf + cb));
      }
    }
  }
}

// ---- grouped dense_in + GLU, 128x64 tile, depth-2 pipeline (stage=8) ----
__global__ __launch_bounds__(256) void mfma_glu_kernel(
    const unsigned short* __restrict__ A,   // ctx2 [4096][1024]
    const unsigned short* __restrict__ WT,  // [g][2048][256]
    const float* __restrict__ bin,          // [4][2048]
    unsigned short* __restrict__ H2)        // [4096][4096]
{
  const int g = blockIdx.z;
  const unsigned short* Ag = A + g * 256;
  const unsigned short* Wg = WT + (long)g * 2048 * 256;
  const float* bg = bin + g * 2048;
  const int row0 = blockIdx.y * 128, col0 = blockIdx.x * 64;
  __shared__ __align__(16) unsigned short As[2][128 * 64];
  __shared__ __align__(16) unsigned short Bxs[2][64 * 64];
  __shared__ __align__(16) unsigned short Bys[2][64 * 64];
  const int tid = threadIdx.x;
  const int w = tid >> 6, l = tid & 63;
  const int ms = (w & 1) << 6, ns = (w >> 1) << 5;
  const int fr = l & 15, fg = l >> 4;
  const int lr8 = l >> 3, ls8 = l & 7;
  const int scol = (ls8 ^ lr8) << 3;
  const int rsw = fr & 7;
  f32x4 ax[4][2], ay[4][2];
  #pragma unroll
  for (int i = 0; i < 4; ++i)
    #pragma unroll
    for (int j = 0; j < 2; ++j) { ax[i][j] = (f32x4)0.0f; ay[i][j] = (f32x4)0.0f; }

  #pragma unroll
  for (int sidx = 0; sidx < 2; ++sidx) {
    const int k0 = sidx << 6;
    #pragma unroll
    for (int g8 = 0; g8 < 4; ++g8) {
      const int r = (w << 5) + (g8 << 3);
      gload16(Ag + (long)(row0 + r + lr8) * 1024 + k0 + scol, &As[sidx][r * 64]);
    }
    #pragma unroll
    for (int g8 = 0; g8 < 2; ++g8) {
      const int r = (w << 4) + (g8 << 3);
      gload16(Wg + (long)(col0 + r + lr8) * 256 + k0 + scol,        &Bxs[sidx][r * 64]);
      gload16(Wg + (long)(1024 + col0 + r + lr8) * 256 + k0 + scol, &Bys[sidx][r * 64]);
    }
  }
  int cur = 0;
  for (int t = 0; t < 4; ++t) {
    if (t + 1 < 4) asm volatile("s_waitcnt vmcnt(8)" ::: "memory");
    else           asm volatile("s_waitcnt vmcnt(0)" ::: "memory");
    __builtin_amdgcn_s_barrier();
    __builtin_amdgcn_sched_barrier(0);
    short8 af[2][4], bx[2][2], by[2][2];
    #pragma unroll
    for (int ks = 0; ks < 2; ++ks) {
      const int rslot = (((ks << 2) + fg) ^ rsw) << 3;
      #pragma unroll
      for (int i = 0; i < 4; ++i)
        af[ks][i] = *(const short8*)&As[cur][(ms + i*16 + fr) * 64 + rslot];
      #pragma unroll
      for (int j = 0; j < 2; ++j) {
        bx[ks][j] = *(const short8*)&Bxs[cur][(ns + j*16 + fr) * 64 + rslot];
        by[ks][j] = *(const short8*)&Bys[cur][(ns + j*16 + fr) * 64 + rslot];
      }
    }
    asm volatile("s_waitcnt lgkmcnt(0)" ::: "memory");
    __builtin_amdgcn_sched_barrier(0);
    __builtin_amdgcn_s_barrier();
    if (t + 2 < 4) {
      const int k0 = (t + 2) << 6;
      #pragma unroll
      for (int g8 = 0; g8 < 4; ++g8) {
        const int r = (w << 5) + (g8 << 3);
        gload16(Ag + (long)(row0 + r + lr8) * 1024 + k0 + scol, &As[cur][r * 64]);
      }
      #pragma unroll
      for (int g8 = 0; g8 < 2; ++g8) {
        const int r = (w << 4) + (g8 << 3);
        gload16(Wg + (long)(col0 + r + lr8) * 256 + k0 + scol,        &Bxs[cur][r * 64]);
        gload16(Wg + (long)(1024 + col0 + r + lr8) * 256 + k0 + scol, &Bys[cur][r * 64]);
      }
    }
    __builtin_amdgcn_s_setprio(1);
    #pragma unroll
    for (int ks = 0; ks < 2; ++ks)
      #pragma unroll
      for (int i = 0; i < 4; ++i)
        #pragma unroll
        for (int j = 0; j < 2; ++j) {
          ax[i][j] = __builtin_amdgcn_mfma_f32_16x16x32_bf16(bx[ks][j], af[ks][i], ax[i][j], 0, 0, 0);
          ay[i][j] = __builtin_amdgcn_mfma_f32_16x16x32_bf16(by[ks][j], af[ks][i], ay[i][j], 0, 0, 0);
        }
    __builtin_amdgcn_s_setprio(0);
    cur ^= 1;
  }

  #pragma unroll
  for (int j = 0; j < 2; ++j) {
    const float4 bx4 = *(const float4*)(bg + col0 + ns + j*16 + (fg << 2));
    const float4 by4 = *(const float4*)(bg + 1024 + col0 + ns + j*16 + (fg << 2));
    #pragma unroll
    for (int i = 0; i < 4; ++i) {
      const long row = row0 + ms + i*16 + fr;
      const long cb = row * 4096 + g * 1024 + col0 + ns + j*16 + (fg << 2);
      float o4[4];
      const float* bxp = &bx4.x; const float* byp = &by4.x;
      #pragma unroll
      for (int r4 = 0; r4 < 4; ++r4) {
        const float xh = ax[i][j][r4] + bxp[r4];
        const float yh = ay[i][j][r4] + byp[r4];
        o4[r4] = xh * fmaxf(yh, 0.0f);
      }
      uint2 pk; pk.x = cvtpk(o4[0], o4[1]); pk.y = cvtpk(o4[2], o4[3]);
      *(uint2*)(H2 + cb) = pk;
    }
  }
}

// -------- V transpose only: qkv v-part [s*4+b][.] -> vt [n][d][s] ---------
__global__ __launch_bounds__(256) void vtrans_kernel(
    const unsigned short* __restrict__ qkv, unsigned short* __restrict__ vt)
{
  __shared__ unsigned short T[64][72];
  const int n = blockIdx.y, s0 = blockIdx.x * 64;
  const int b = n >> 4, hoff = (n & 15) * 64;
  const int tid = threadIdx.x;
  #pragma unroll
  for (int p = 0; p < 2; ++p) {
    const int r = (tid >> 3) + p * 32, c = (tid & 7) << 3;
    *(short8*)&T[r][c] = *(const short8*)(qkv + ((long)((s0 + r) * 4 + b)) * 3072 + 2048 + hoff + c);
  }
  __syncthreads();
  #pragma unroll
  for (int p = 0; p < 2; ++p) {
    const int d = (tid >> 3) + p * 32, sc = (tid & 7) << 3;
    short8 o;
    #pragma unroll
    for (int j = 0; j < 8; ++j) o[j] = (short)T[sc + j][d];
    *(short8*)(vt + ((long)n * 64 + d) * 1024 + s0 + sc) = o;
  }
}

// --- MFMA attention, counted-vmcnt K/V pipeline, fused residual+LN2 ------
__global__ __launch_bounds__(256) void attn_kernel(
    const unsigned short* __restrict__ qkv, const unsigned short* __restrict__ vt,
    const float* __restrict__ q2g, const float* __restrict__ k2g,
    const unsigned short* __restrict__ xbf, const float* __restrict__ g2,
    const float* __restrict__ b2,
    unsigned short* __restrict__ ctx2, float* __restrict__ scores)
{
  const int n = blockIdx.y;
  const int s0 = blockIdx.x * 64;
  const int b = n >> 4, hoff = (n & 15) * 64;
  __shared__ __align__(16) unsigned short Qs[64 * 64];
  __shared__ __align__(16) unsigned short Ks[2][64 * 64];
  __shared__ __align__(16) unsigned short VTl[2][64 * 64];
  __shared__ __align__(16) unsigned short Ps[64 * 64];
  __shared__ float k2s[1024];
  const int tid = threadIdx.x, w = tid >> 6, l = tid & 63;
  const int fr = l & 15, fg = l >> 4;
  const int lr8 = l >> 3, ls8 = l & 7;
  const int sslot = ((ls8 ^ lr8) << 3);
  const int rsw = fr & 7;

  #pragma unroll
  for (int p = 0; p < 2; ++p) {
    const int r = (tid >> 3) + p * 32, cs = tid & 7;
    *(short8*)&Qs[r * 64 + ((cs ^ (r & 7)) << 3)] =
        *(const short8*)(qkv + ((long)((s0 + r) * 4 + b)) * 3072 + hoff + (cs << 3));
  }
  *(float4*)&k2s[tid << 2] = *(const float4*)(k2g + n * 1024 + (tid << 2));
  float q2m[4];
  #pragma unroll
  for (int i = 0; i < 4; ++i) q2m[i] = -0.0625f * q2g[n * 1024 + s0 + i*16 + fr];
  #pragma unroll
  for (int p = 0; p < 2; ++p) {
    const int rowb = p * 32 + w * 8;
    gload16(qkv + ((long)((rowb + lr8) * 4 + b)) * 3072 + 1024 + hoff + sslot, &Ks[0][rowb * 64]);
    gload16(vt + ((long)n * 64 + rowb + lr8) * 1024 + sslot,                   &VTl[0][rowb * 64]);
  }
  __syncthreads();

  f32x4 o[4];
  #pragma unroll
  for (int i = 0; i < 4; ++i) o[i] = (f32x4)0.0f;

  int cur = 0;
  for (int t0 = 0; t0 < 1024; t0 += 64) {
    if (t0 > 0) {
      asm volatile("s_waitcnt vmcnt(4)" ::: "memory");
      __builtin_amdgcn_sched_barrier(0);
      __builtin_amdgcn_s_barrier();
    }
    f32x4 c4[4];
    #pragma unroll
    for (int i = 0; i < 4; ++i) c4[i] = (f32x4)0.0f;
    #pragma unroll
    for (int ks = 0; ks < 2; ++ks) {
      const short8 kf = *(const short8*)&Ks[cur][((w << 4) + fr) * 64 + ((((ks << 2) + fg) ^ rsw) << 3)];
      #pragma unroll
      for (int i = 0; i < 4; ++i) {
        const short8 qf = *(const short8*)&Qs[(i*16 + fr) * 64 + ((((ks << 2) + fg) ^ rsw) << 3)];
        c4[i] = __builtin_amdgcn_mfma_f32_16x16x32_bf16(kf, qf, c4[i], 0, 0, 0);
      }
    }
    if (t0 + 64 < 1024) {
      #pragma unroll
      for (int p = 0; p < 2; ++p) {
        const int rowb = p * 32 + w * 8;
        gload16(qkv + ((long)((t0 + 64 + rowb + lr8) * 4 + b)) * 3072 + 1024 + hoff + sslot,
                &Ks[cur ^ 1][rowb * 64]);
        gload16(vt + ((long)n * 64 + rowb + lr8) * 1024 + t0 + 64 + sslot,
                &VTl[cur ^ 1][rowb * 64]);
      }
    }
    const float4 k2v4 = *(const float4*)&k2s[t0 + (w << 4) + (fg << 2)];
    const float k2m[4] = {-0.0625f*k2v4.x, -0.0625f*k2v4.y, -0.0625f*k2v4.z, -0.0625f*k2v4.w};
    #pragma unroll
    for (int i = 0; i < 4; ++i) {
      f32x4 sc;
      float pe[4];
      #pragma unroll
      for (int r4 = 0; r4 < 4; ++r4) {
        const float m = fmaf(c4[i][r4], 0.125f, q2m[i] + k2m[r4]);
        sc[r4] = m;
        pe[r4] = __expf(m);
      }
      __builtin_nontemporal_store(sc,
          (f32x4*)(scores + (long)n * 1048576 + (long)(s0 + i*16 + fr) * 1024 + t0 + (w << 4) + (fg << 2)));
      const int slot = (w << 1) + (fg >> 1);
      const int pc = ((slot ^ (fr & 7)) << 3) + ((fg & 1) << 2);
      uint2 pk; pk.x = cvtpk(pe[0], pe[1]); pk.y = cvtpk(pe[2], pe[3]);
      *(uint2*)&Ps[(i*16 + fr) * 64 + pc] = pk;
    }
    asm volatile("s_waitcnt lgkmcnt(0)" ::: "memory");
    __builtin_amdgcn_sched_barrier(0);
    __builtin_amdgcn_s_barrier();
    #pragma unroll
    for (int ks = 0; ks < 2; ++ks) {
      const short8 vb = *(const short8*)&VTl[cur][((w << 4) + fr) * 64 + ((((ks << 2) + fg) ^ rsw) << 3)];
      #pragma unroll
      for (int i = 0; i < 4; ++i) {
        const short8 pf = *(const short8*)&Ps[(i*16 + fr) * 64 + ((((ks << 2) + fg) ^ rsw) << 3)];
        o[i] = __builtin_amdgcn_mfma_f32_16x16x32_bf16(vb, pf, o[i], 0, 0, 0);
      }
    }
    asm volatile("s_waitcnt lgkmcnt(0)" ::: "memory");
    __builtin_amdgcn_sched_barrier(0);
    __builtin_amdgcn_s_barrier();
    cur ^= 1;
  }

  // ---- fused residual (bf16 x) + per-head LN2 -> ctx2 bf16 ----
  const int dbase = (w << 4) + (fg << 2);
  float xf[4][4];
  #pragma unroll
  for (int i = 0; i < 4; ++i) {
    const ushort4 xu = *(const ushort4*)(xbf + ((long)((s0 + i*16 + fr) * 4 + b)) * 1024 + hoff + dbase);
    xf[i][0] = bf2f(xu.x); xf[i][1] = bf2f(xu.y);
    xf[i][2] = bf2f(xu.z); xf[i][3] = bf2f(xu.w);
  }

  float* redbuf = (float*)&Ps[0];
  const int slot = (w << 2) + fg;
  #pragma unroll
  for (int i = 0; i < 4; ++i) {
    float s = 0.f, ss = 0.f;
    #pragma unroll
    for (int r4 = 0; r4 < 4; ++r4) {
      const float v = o[i][r4] + xf[i][r4];
      s += v; ss = fmaf(v, v, ss);
    }
    redbuf[(i*16 + fr) * 16 + slot] = s;
    redbuf[1024 + (i*16 + fr) * 16 + slot] = ss;
  }
  __syncthreads();
  float* statbuf = (float*)&Qs[0];
  {
    const int row = tid >> 2, q4 = tid & 3;
    float s = 0.f, ss = 0.f;
    #pragma unroll
    for (int k = 0; k < 4; ++k) {
      s  += redbuf[row * 16 + q4 * 4 + k];
      ss += redbuf[1024 + row * 16 + q4 * 4 + k];
    }
    s  += __shfl_xor(s, 1);  s  += __shfl_xor(s, 2);
    ss += __shfl_xor(ss, 1); ss += __shfl_xor(ss, 2);
    if (q4 == 0) {
      const float mean = s * (1.0f/64.0f);
      const float var  = ss * (1.0f/64.0f) - mean * mean;
      statbuf[row] = mean;
      statbuf[64 + row] = rsqrtf(var + 1e-6f);
    }
  }
  __syncthreads();
  const float4 g2v = *(const float4*)(g2 + dbase);
  const float4 b2v = *(const float4*)(b2 + dbase);
  const float* gp = &g2v.x; const float* bp = &b2v.x;
  #pragma unroll
  for (int i = 0; i < 4; ++i) {
    const float mean = statbuf[i*16 + fr];
    const float rs   = statbuf[64 + i*16 + fr];
    float vo[4];
    #pragma unroll
    for (int r4 = 0; r4 < 4; ++r4)
      vo[r4] = (o[i][r4] + xf[i][r4] - mean) * rs * gp[r4] + bp[r4];
    uint2 pk; pk.x = cvtpk(vo[0], vo[1]); pk.y = cvtpk(vo[2], vo[3]);
    *(uint2*)(ctx2 + ((long)((s0 + i*16 + fr) * 4 + b)) * 1024 + hoff + dbase) = pk;
  }
}

extern "C" void kernel_launch(void* const* d_in, const int* in_sizes, int n_in,
                              void* d_out, int out_size, void* d_ws, size_t ws_size,
                              hipStream_t stream) {
  const float* hs   = (const float*)d_in[0];
  const float* g1   = (const float*)d_in[1];
  const float* b1   = (const float*)d_in[2];
  const float* g2   = (const float*)d_in[3];
  const float* b2   = (const float*)d_in[4];
  const float* Wq   = (const float*)d_in[5];
  const float* bq   = (const float*)d_in[6];
  const float* Wk   = (const float*)d_in[7];
  const float* bk   = (const float*)d_in[8];
  const float* Wv   = (const float*)d_in[9];
  const float* bv   = (const float*)d_in[10];
  const float* Win  = (const float*)d_in[11];
  const float* bin  = (const float*)d_in[12];
  const float* Wout = (const float*)d_in[13];
  const float* bout = (const float*)d_in[14];
  const float* Wd   = (const float*)d_in[15];
  const float* bd   = (const float*)d_in[16];

  // ws layout (bytes), verified DISJOINT live ranges (as round 16):
  //   qkv  [0,        25165824)   live: qkv-gemm .. attn end
  //   xbf  [25165824, 33554432)   live: prep .. attn end
  //   ctx2 [33554432, 41943040)   live: attn .. glu
  //   vt   [41943040, 50331648)   live: vtrans .. attn end
  //   weights/qkvb/q2g/k2g [50331648, 65548288)
  // Overlays (strictly after attn completes):
  //   h2 [0, 33554432) over qkv+xbf;  og [41943040, 50331648) over vt.
  char* ws = (char*)d_ws;
  unsigned short* qkv   = (unsigned short*)(ws + 0);
  unsigned short* xbf   = (unsigned short*)(ws + 25165824);
  unsigned short* ctx2  = (unsigned short*)(ws + 33554432);
  unsigned short* vt    = (unsigned short*)(ws + 41943040);
  unsigned short* wqkvT = (unsigned short*)(ws + 50331648);
  unsigned short* winT  = (unsigned short*)(ws + 56623104);
  unsigned short* woutT = (unsigned short*)(ws + 60817408);
  unsigned short* wdT   = (unsigned short*)(ws + 62914560);
  float*          qkvb  = (float*)(ws + 65011712);
  float*          q2g   = (float*)(ws + 65024000);
  float*          k2g   = (float*)(ws + 65286144);
  unsigned short* h2    = (unsigned short*)(ws + 0);
  unsigned short* og    = (unsigned short*)(ws + 41943040);

  float* out0 = (float*)d_out;           // [S,B,H]
  float* out1 = out0 + 4194304;          // [64,1024,1024]

  prep_all_kernel<<<11276, 256, 0, stream>>>(
      hs, g1, b1, xbf,
      Wq, Wk, Wv, Wd, Win, Wout, bq, bk, bv,
      wqkvT, wdT, winT, woutT, qkvb);

  // QKV: 256^2 8-wave counted-vmcnt pipeline (+ fused q2/k2)
  qkv256_kernel<<<dim3(12,16,1), 512, 0, stream>>>(
      xbf, wqkvT, qkvb, qkv, q2g, k2g);

  vtrans_kernel<<<dim3(16,64), 256, 0, stream>>>(qkv, vt);

  attn_kernel<<<dim3(16,64), 256, 0, stream>>>(qkv, vt, q2g, k2g, xbf, g2, b2, ctx2, out1);

  mfma_glu_kernel<<<dim3(16,32,4), 256, 0, stream>>>(ctx2, winT, bin, h2);

  // FFN-out: per group -> og bf16
  mfma_gemm64_kernel<<<dim3(4,32,4), 256, 0, stream>>>(
      h2, 4096, 1024, woutT, 262144, 1024, bout, 256, og, nullptr, 1024, 256);

  // dense: [4096,1024]@[1024,1024] -> out0 fp32 (NT store)
  mfma_gemm64_kernel<<<dim3(16,32,1), 256, 0, stream>>>(
      og, 1024, 0, wdT, 0, 1024, bd, 0, nullptr, out0, 1024, 0);
}

// Round 18
// 217.747 us; speedup vs baseline: 1.2509x; 1.0311x over previous
//
#include <hip/hip_runtime.h>

// TransformerLayer_Combined on gfx950 — bf16 MFMA pipeline.
// QKV: 256^2 / 8-wave depth-2 counted-vmcnt. Other GEMMs: 128-tile depth-2
// counted-vmcnt. attn fuses residual (bf16 x) + LN2. XCD-chunked block
// swizzle (T1) on all large grids for per-XCD L2 locality.

typedef __attribute__((ext_vector_type(8))) short short8;
typedef __attribute__((ext_vector_type(4))) float f32x4;

__device__ __forceinline__ unsigned short f2bf(float f) {
  union { float f; unsigned u; } x; x.f = f;
  unsigned r = x.u + 0x7FFFu + ((x.u >> 16) & 1u);
  return (unsigned short)(r >> 16);
}
__device__ __forceinline__ float bf2f(unsigned short u) {
  union { float f; unsigned u; } x; x.u = ((unsigned)u) << 16;
  return x.f;
}
__device__ __forceinline__ unsigned cvtpk(float a, float b) {  // [lo=a, hi=b]
  unsigned r;
  asm("v_cvt_pk_bf16_f32 %0, %1, %2" : "=v"(r) : "v"(a), "v"(b));
  return r;
}
// async 16B global->LDS (dest = wave-uniform base + lane*16)
__device__ __forceinline__ void gload16(const unsigned short* g, unsigned short* l) {
  __builtin_amdgcn_global_load_lds(
      (const __attribute__((address_space(1))) unsigned int*)g,
      (__attribute__((address_space(3))) unsigned int*)l, 16, 0, 0);
}
// XCD-chunked bijective swizzle over the 2D (x,y) grid; requires total%8==0.
__device__ __forceinline__ void xcd_swizzle(int& bx, int& by) {
  const int nx = gridDim.x, total = nx * gridDim.y;
  const int wg = by * nx + bx;
  const int cpx = total >> 3;
  const int swz = (wg & 7) * cpx + (wg >> 3);
  bx = swz % nx; by = swz / nx;
}

// ---- merged LN1 + weight prep, one launch --------------------------------
__device__ __forceinline__ void ln1_body(
    const float* __restrict__ x, const float* __restrict__ g,
    const float* __restrict__ b,
    unsigned short* __restrict__ ybf, int row, int tid)
{
  const long base = (long)row * 1024;
  const int c = tid * 4;
  float4 v = *(const float4*)(x + base + c);
  float s = v.x + v.y + v.z + v.w;
  float ss = v.x*v.x + v.y*v.y + v.z*v.z + v.w*v.w;
  #pragma unroll
  for (int off = 32; off > 0; off >>= 1) {
    s  += __shfl_xor(s, off);
    ss += __shfl_xor(ss, off);
  }
  __shared__ float sw[4], ssw[4];
  const int wave = tid >> 6;
  if ((tid & 63) == 0) { sw[wave] = s; ssw[wave] = ss; }
  __syncthreads();
  s  = sw[0] + sw[1] + sw[2] + sw[3];
  ss = ssw[0] + ssw[1] + ssw[2] + ssw[3];
  const float mean = s * (1.0f/1024.0f);
  const float var  = ss * (1.0f/1024.0f) - mean*mean;
  const float rs   = rsqrtf(var + 1e-6f);
  const float4 gv = *(const float4*)(g + c);
  const float4 bv = *(const float4*)(b + c);
  const float o0 = (v.x - mean) * rs * gv.x + bv.x;
  const float o1 = (v.y - mean) * rs * gv.y + bv.y;
  const float o2 = (v.z - mean) * rs * gv.z + bv.z;
  const float o3 = (v.w - mean) * rs * gv.w + bv.w;
  uint2 pk; pk.x = cvtpk(o0, o1); pk.y = cvtpk(o2, o3);
  *(uint2*)(ybf + base + c) = pk;
}

__device__ __forceinline__ void transpose_body(
    const float* __restrict__ Wg, unsigned short* __restrict__ WTg,
    int K, int N, int bx, int by, int tid)
{
  __shared__ float T[32][33];
  const int n0 = bx * 32, k0 = by * 32;
  const int r = tid >> 3, c4 = (tid & 7) * 4;
  float4 v = *(const float4*)(Wg + (long)(k0 + r) * N + n0 + c4);
  T[r][c4+0] = v.x; T[r][c4+1] = v.y; T[r][c4+2] = v.z; T[r][c4+3] = v.w;
  __syncthreads();
  ushort4 o;
  o.x = f2bf(T[c4+0][r]); o.y = f2bf(T[c4+1][r]);
  o.z = f2bf(T[c4+2][r]); o.w = f2bf(T[c4+3][r]);
  *(ushort4*)(WTg + (long)(n0 + r) * K + k0 + c4) = o;
}

__global__ __launch_bounds__(256) void prep_all_kernel(
    const float* __restrict__ hs, const float* __restrict__ g1,
    const float* __restrict__ b1,
    unsigned short* __restrict__ xbf,
    const float* __restrict__ Wq, const float* __restrict__ Wk,
    const float* __restrict__ Wv, const float* __restrict__ Wd,
    const float* __restrict__ Win, const float* __restrict__ Wout,
    const float* __restrict__ bq, const float* __restrict__ bk,
    const float* __restrict__ bv,
    unsigned short* __restrict__ wqkvT, unsigned short* __restrict__ wdT,
    unsigned short* __restrict__ winT, unsigned short* __restrict__ woutT,
    float* __restrict__ qkvb)
{
  const int bid = blockIdx.x;
  const int tid = threadIdx.x;
  if (bid < 4096) {               // LN1 rows (bf16 out only)
    ln1_body(hs, g1, b1, xbf, bid, tid);
  } else if (bid < 8192) {        // Wq/Wk/Wv/Wd 1024x1024
    const int idx = bid - 4096;
    const int z = idx >> 10, rem = idx & 1023;
    const float* W = (z == 0) ? Wq : (z == 1) ? Wk : (z == 2) ? Wv : Wd;
    unsigned short* WT = (z == 3) ? wdT : wqkvT + (long)z * 1048576;
    transpose_body(W, WT, 1024, 1024, rem & 31, rem >> 5, tid);
  } else if (bid < 10240) {       // Win [4][256][2048]
    const int rem = bid - 8192;
    const int z = rem >> 9, r2 = rem & 511;
    transpose_body(Win + (long)z * 524288, winT + (long)z * 524288,
                   256, 2048, r2 & 63, r2 >> 6, tid);
  } else if (bid < 11264) {       // Wout [4][1024][256]
    const int rem = bid - 10240;
    const int z = rem >> 8, r2 = rem & 255;
    transpose_body(Wout + (long)z * 262144, woutT + (long)z * 262144,
                   1024, 256, r2 & 7, r2 >> 3, tid);
  } else {                        // packb (12 blocks x 256)
    const int i = (bid - 11264) * 256 + tid;
    qkvb[i] = (i < 1024) ? bq[i] : ((i < 2048) ? bk[i - 1024] : bv[i - 2048]);
  }
}

// ---- QKV GEMM: 256x256 tile, 8 waves, depth-2 counted-vmcnt, split-ks ---
__global__ __launch_bounds__(512) void qkv256_kernel(
    const unsigned short* __restrict__ A,
    const unsigned short* __restrict__ BT,
    const float* __restrict__ bias,
    unsigned short* __restrict__ C,
    float* __restrict__ q2g, float* __restrict__ k2g)
{
  int bx = blockIdx.x, by = blockIdx.y;
  xcd_swizzle(bx, by);
  const int row0 = by * 256, col0 = bx * 256;
  __shared__ __align__(16) unsigned short As[2][256 * 64];
  __shared__ __align__(16) unsigned short Bs[2][256 * 64];
  const int tid = threadIdx.x;
  const int w = tid >> 6, l = tid & 63;
  const int ms = (w >> 2) << 7;   // wave M offset: 0/128
  const int ns = (w & 3) << 6;    // wave N offset: 0/64/128/192
  const int fr = l & 15, fg = l >> 4;
  const int lr8 = l >> 3, ls8 = l & 7;
  const int scol = (ls8 ^ lr8) << 3;
  const int rsw = fr & 7;
  f32x4 acc[8][4];
  #pragma unroll
  for (int i = 0; i < 8; ++i)
    #pragma unroll
    for (int j = 0; j < 4; ++j) acc[i][j] = (f32x4)0.0f;

  #pragma unroll
  for (int sidx = 0; sidx < 2; ++sidx) {   // stage K-tiles 0,1
    const int k0 = sidx << 6;
    #pragma unroll
    for (int g8 = 0; g8 < 4; ++g8) {
      const int rb = (g8 << 6) + (w << 3);
      gload16(A  + (long)(row0 + rb + lr8) * 1024 + k0 + scol, &As[sidx][rb * 64]);
      gload16(BT + (long)(col0 + rb + lr8) * 1024 + k0 + scol, &Bs[sidx][rb * 64]);
    }
  }
  int cur = 0;
  for (int t = 0; t < 16; ++t) {
    if (t < 15) asm volatile("s_waitcnt vmcnt(8)" ::: "memory");
    else        asm volatile("s_waitcnt vmcnt(0)" ::: "memory");
    __builtin_amdgcn_s_barrier();
    __builtin_amdgcn_sched_barrier(0);
    {  // ks = 0
      const int rslot = (fg ^ rsw) << 3;
      short8 af[8], b4[4];
      #pragma unroll
      for (int i = 0; i < 8; ++i)
        af[i] = *(const short8*)&As[cur][(ms + i*16 + fr) * 64 + rslot];
      #pragma unroll
      for (int j = 0; j < 4; ++j)
        b4[j] = *(const short8*)&Bs[cur][(ns + j*16 + fr) * 64 + rslot];
      #pragma unroll
      for (int i = 0; i < 8; ++i)
        #pragma unroll
        for (int j = 0; j < 4; ++j)
          acc[i][j] = __builtin_amdgcn_mfma_f32_16x16x32_bf16(b4[j], af[i], acc[i][j], 0, 0, 0);
    }
    short8 af1[8], b41[4];
    {
      const int rslot = ((4 + fg) ^ rsw) << 3;
      #pragma unroll
      for (int i = 0; i < 8; ++i)
        af1[i] = *(const short8*)&As[cur][(ms + i*16 + fr) * 64 + rslot];
      #pragma unroll
      for (int j = 0; j < 4; ++j)
        b41[j] = *(const short8*)&Bs[cur][(ns + j*16 + fr) * 64 + rslot];
    }
    asm volatile("s_waitcnt lgkmcnt(0)" ::: "memory");
    __builtin_amdgcn_sched_barrier(0);
    __builtin_amdgcn_s_barrier();
    if (t + 2 < 16) {
      const int k0 = (t + 2) << 6;
      #pragma unroll
      for (int g8 = 0; g8 < 4; ++g8) {
        const int rb = (g8 << 6) + (w << 3);
        gload16(A  + (long)(row0 + rb + lr8) * 1024 + k0 + scol, &As[cur][rb * 64]);
        gload16(BT + (long)(col0 + rb + lr8) * 1024 + k0 + scol, &Bs[cur][rb * 64]);
      }
    }
    __builtin_amdgcn_s_setprio(1);
    #pragma unroll
    for (int i = 0; i < 8; ++i)
      #pragma unroll
      for (int j = 0; j < 4; ++j)
        acc[i][j] = __builtin_amdgcn_mfma_f32_16x16x32_bf16(b41[j], af1[i], acc[i][j], 0, 0, 0);
    __builtin_amdgcn_s_setprio(0);
    cur ^= 1;
  }

  float s2[8];
  #pragma unroll
  for (int i = 0; i < 8; ++i) s2[i] = 0.f;
  #pragma unroll
  for (int j = 0; j < 4; ++j) {
    const float4 bj4 = *(const float4*)(bias + col0 + ns + j*16 + (fg << 2));
    #pragma unroll
    for (int i = 0; i < 8; ++i) {
      const long row = row0 + ms + i*16 + fr;
      const long cb = row * 3072 + col0 + ns + j*16 + (fg << 2);
      const float v0 = acc[i][j][0] + bj4.x, v1 = acc[i][j][1] + bj4.y;
      const float v2 = acc[i][j][2] + bj4.z, v3 = acc[i][j][3] + bj4.w;
      s2[i] += v0*v0 + v1*v1 + v2*v2 + v3*v3;
      uint2 pk; pk.x = cvtpk(v0, v1); pk.y = cvtpk(v2, v3);
      *(uint2*)(C + cb) = pk;
    }
  }
  const int nsAbs = col0 + ns;
  if (nsAbs < 2048) {
    const bool isQ = nsAbs < 1024;
    float* outp = isQ ? q2g : k2g;
    const int head = (isQ ? nsAbs : nsAbs - 1024) >> 6;
    #pragma unroll
    for (int i = 0; i < 8; ++i) {
      float s = s2[i];
      s += __shfl_xor(s, 16);
      s += __shfl_xor(s, 32);
      if (fg == 0) {
        const int gr = row0 + ms + i*16 + fr;          // s*4+b
        outp[((gr & 3) * 16 + head) * 1024 + (gr >> 2)] = s;
      }
    }
  }
}

// ---- bf16 MFMA GEMM, 128x64 tile, depth-2 pipeline (stage = 6 loads) ----
__global__ __launch_bounds__(256) void mfma_gemm64_kernel(
    const unsigned short* __restrict__ A, int lda, long agoff,
    const unsigned short* __restrict__ BT, long bgoff, int K,
    const float* __restrict__ bias, int biasoff,
    unsigned short* __restrict__ Cbf, float* __restrict__ Cf,
    int ldc, int cgoff)
{
  const int g = blockIdx.z;
  int bx = blockIdx.x, by = blockIdx.y;
  xcd_swizzle(bx, by);
  const unsigned short* Ag = A + (long)g * agoff;
  const unsigned short* Bg = BT + (long)g * bgoff;
  const float* biasg = bias + (long)g * biasoff;
  const int row0 = by * 128, col0 = bx * 64;
  __shared__ __align__(16) unsigned short As[2][128 * 64];
  __shared__ __align__(16) unsigned short Bs[2][64 * 64];
  const int tid = threadIdx.x;
  const int w = tid >> 6, l = tid & 63;
  const int ms = (w & 1) << 6, ns = (w >> 1) << 5;
  const int fr = l & 15, fg = l >> 4;
  const int lr8 = l >> 3, ls8 = l & 7;
  const int scol = (ls8 ^ lr8) << 3;
  const int rsw = fr & 7;
  f32x4 acc[4][2];
  #pragma unroll
  for (int i = 0; i < 4; ++i)
    #pragma unroll
    for (int j = 0; j < 2; ++j) acc[i][j] = (f32x4)0.0f;

  const int nt = K >> 6;
  #pragma unroll
  for (int sidx = 0; sidx < 2; ++sidx) {
    const int k0 = sidx << 6;
    #pragma unroll
    for (int g8 = 0; g8 < 4; ++g8) {
      const int r = (w << 5) + (g8 << 3);
      gload16(Ag + (long)(row0 + r + lr8) * lda + k0 + scol, &As[sidx][r * 64]);
    }
    #pragma unroll
    for (int g8 = 0; g8 < 2; ++g8) {
      const int r = (w << 4) + (g8 << 3);
      gload16(Bg + (long)(col0 + r + lr8) * K + k0 + scol, &Bs[sidx][r * 64]);
    }
  }
  int cur = 0;
  for (int t = 0; t < nt; ++t) {
    if (t + 1 < nt) asm volatile("s_waitcnt vmcnt(6)" ::: "memory");
    else            asm volatile("s_waitcnt vmcnt(0)" ::: "memory");
    __builtin_amdgcn_s_barrier();
    __builtin_amdgcn_sched_barrier(0);
    short8 af[2][4], bfr[2][2];
    #pragma unroll
    for (int ks = 0; ks < 2; ++ks) {
      const int rslot = (((ks << 2) + fg) ^ rsw) << 3;
      #pragma unroll
      for (int i = 0; i < 4; ++i)
        af[ks][i] = *(const short8*)&As[cur][(ms + i*16 + fr) * 64 + rslot];
      #pragma unroll
      for (int j = 0; j < 2; ++j)
        bfr[ks][j] = *(const short8*)&Bs[cur][(ns + j*16 + fr) * 64 + rslot];
    }
    asm volatile("s_waitcnt lgkmcnt(0)" ::: "memory");
    __builtin_amdgcn_sched_barrier(0);
    __builtin_amdgcn_s_barrier();
    if (t + 2 < nt) {
      const int k0 = (t + 2) << 6;
      #pragma unroll
      for (int g8 = 0; g8 < 4; ++g8) {
        const int r = (w << 5) + (g8 << 3);
        gload16(Ag + (long)(row0 + r + lr8) * lda + k0 + scol, &As[cur][r * 64]);
      }
      #pragma unroll
      for (int g8 = 0; g8 < 2; ++g8) {
        const int r = (w << 4) + (g8 << 3);
        gload16(Bg + (long)(col0 + r + lr8) * K + k0 + scol, &Bs[cur][r * 64]);
      }
    }
    __builtin_amdgcn_s_setprio(1);
    #pragma unroll
    for (int ks = 0; ks < 2; ++ks)
      #pragma unroll
      for (int i = 0; i < 4; ++i)
        #pragma unroll
        for (int j = 0; j < 2; ++j)
          acc[i][j] = __builtin_amdgcn_mfma_f32_16x16x32_bf16(bfr[ks][j], af[ks][i], acc[i][j], 0, 0, 0);
    __builtin_amdgcn_s_setprio(0);
    cur ^= 1;
  }

  #pragma unroll
  for (int j = 0; j < 2; ++j) {
    const float4 bj4 = *(const float4*)(biasg + col0 + ns + j*16 + (fg << 2));
    #pragma unroll
    for (int i = 0; i < 4; ++i) {
      const long row = row0 + ms + i*16 + fr;
      const long cb = row * ldc + (long)g * cgoff + col0 + ns + j*16 + (fg << 2);
      const float v0 = acc[i][j][0] + bj4.x, v1 = acc[i][j][1] + bj4.y;
      const float v2 = acc[i][j][2] + bj4.z, v3 = acc[i][j][3] + bj4.w;
      if (Cbf) {
        uint2 pk; pk.x = cvtpk(v0, v1); pk.y = cvtpk(v2, v3);
        *(uint2*)(Cbf + cb) = pk;
      } else {
        f32x4 o = {v0, v1, v2, v3};
        __builtin_nontemporal_store(o, (f32x4*)(Cf + cb));
      }
    }
  }
}

// ---- grouped dense_in + GLU, 128x64 tile, depth-2 pipeline (stage=8) ----
__global__ __launch_bounds__(256) void mfma_glu_kernel(
    const unsigned short* __restrict__ A,   // ctx2 [4096][1024]
    const unsigned short* __restrict__ WT,  // [g][2048][256]
    const float* __restrict__ bin,          // [4][2048]
    unsigned short* __restrict__ H2)        // [4096][4096]
{
  const int g = blockIdx.z;
  int bx = blockIdx.x, by = blockIdx.y;
  xcd_swizzle(bx, by);
  const unsigned short* Ag = A + g * 256;
  const unsigned short* Wg = WT + (long)g * 2048 * 256;
  const float* bg = bin + g * 2048;
  const int row0 = by * 128, col0 = bx * 64;
  __shared__ __align__(16) unsigned short As[2][128 * 64];
  __shared__ __align__(16) unsigned short Bxs[2][64 * 64];
  __shared__ __align__(16) unsigned short Bys[2][64 * 64];
  const int tid = threadIdx.x;
  const int w = tid >> 6, l = tid & 63;
  const int ms = (w & 1) << 6, ns = (w >> 1) << 5;
  const int fr = l & 15, fg = l >> 4;
  const int lr8 = l >> 3, ls8 = l & 7;
  const int scol = (ls8 ^ lr8) << 3;
  const int rsw = fr & 7;
  f32x4 ax[4][2], ay[4][2];
  #pragma unroll
  for (int i = 0; i < 4; ++i)
    #pragma unroll
    for (int j = 0; j < 2; ++j) { ax[i][j] = (f32x4)0.0f; ay[i][j] = (f32x4)0.0f; }

  #pragma unroll
  for (int sidx = 0; sidx < 2; ++sidx) {
    const int k0 = sidx << 6;
    #pragma unroll
    for (int g8 = 0; g8 < 4; ++g8) {
      const int r = (w << 5) + (g8 << 3);
      gload16(Ag + (long)(row0 + r + lr8) * 1024 + k0 + scol, &As[sidx][r * 64]);
    }
    #pragma unroll
    for (int g8 = 0; g8 < 2; ++g8) {
      const int r = (w << 4) + (g8 << 3);
      gload16(Wg + (long)(col0 + r + lr8) * 256 + k0 + scol,        &Bxs[sidx][r * 64]);
      gload16(Wg + (long)(1024 + col0 + r + lr8) * 256 + k0 + scol, &Bys[sidx][r * 64]);
    }
  }
  int cur = 0;
  for (int t = 0; t < 4; ++t) {
    if (t + 1 < 4) asm volatile("s_waitcnt vmcnt(8)" ::: "memory");
    else           asm volatile("s_waitcnt vmcnt(0)" ::: "memory");
    __builtin_amdgcn_s_barrier();
    __builtin_amdgcn_sched_barrier(0);
    short8 af[2][4], bx2[2][2], by2[2][2];
    #pragma unroll
    for (int ks = 0; ks < 2; ++ks) {
      const int rslot = (((ks << 2) + fg) ^ rsw) << 3;
      #pragma unroll
      for (int i = 0; i < 4; ++i)
        af[ks][i] = *(const short8*)&As[cur][(ms + i*16 + fr) * 64 + rslot];
      #pragma unroll
      for (int j = 0; j < 2; ++j) {
        bx2[ks][j] = *(const short8*)&Bxs[cur][(ns + j*16 + fr) * 64 + rslot];
        by2[ks][j] = *(const short8*)&Bys[cur][(ns + j*16 + fr) * 64 + rslot];
      }
    }
    asm volatile("s_waitcnt lgkmcnt(0)" ::: "memory");
    __builtin_amdgcn_sched_barrier(0);
    __builtin_amdgcn_s_barrier();
    if (t + 2 < 4) {
      const int k0 = (t + 2) << 6;
      #pragma unroll
      for (int g8 = 0; g8 < 4; ++g8) {
        const int r = (w << 5) + (g8 << 3);
        gload16(Ag + (long)(row0 + r + lr8) * 1024 + k0 + scol, &As[cur][r * 64]);
      }
      #pragma unroll
      for (int g8 = 0; g8 < 2; ++g8) {
        const int r = (w << 4) + (g8 << 3);
        gload16(Wg + (long)(col0 + r + lr8) * 256 + k0 + scol,        &Bxs[cur][r * 64]);
        gload16(Wg + (long)(1024 + col0 + r + lr8) * 256 + k0 + scol, &Bys[cur][r * 64]);
      }
    }
    __builtin_amdgcn_s_setprio(1);
    #pragma unroll
    for (int ks = 0; ks < 2; ++ks)
      #pragma unroll
      for (int i = 0; i < 4; ++i)
        #pragma unroll
        for (int j = 0; j < 2; ++j) {
          ax[i][j] = __builtin_amdgcn_mfma_f32_16x16x32_bf16(bx2[ks][j], af[ks][i], ax[i][j], 0, 0, 0);
          ay[i][j] = __builtin_amdgcn_mfma_f32_16x16x32_bf16(by2[ks][j], af[ks][i], ay[i][j], 0, 0, 0);
        }
    __builtin_amdgcn_s_setprio(0);
    cur ^= 1;
  }

  #pragma unroll
  for (int j = 0; j < 2; ++j) {
    const float4 bx4 = *(const float4*)(bg + col0 + ns + j*16 + (fg << 2));
    const float4 by4 = *(const float4*)(bg + 1024 + col0 + ns + j*16 + (fg << 2));
    #pragma unroll
    for (int i = 0; i < 4; ++i) {
      const long row = row0 + ms + i*16 + fr;
      const long cb = row * 4096 + g * 1024 + col0 + ns + j*16 + (fg << 2);
      float o4[4];
      const float* bxp = &bx4.x; const float* byp = &by4.x;
      #pragma unroll
      for (int r4 = 0; r4 < 4; ++r4) {
        const float xh = ax[i][j][r4] + bxp[r4];
        const float yh = ay[i][j][r4] + byp[r4];
        o4[r4] = xh * fmaxf(yh, 0.0f);
      }
      uint2 pk; pk.x = cvtpk(o4[0], o4[1]); pk.y = cvtpk(o4[2], o4[3]);
      *(uint2*)(H2 + cb) = pk;
    }
  }
}

// -------- V transpose only: qkv v-part [s*4+b][.] -> vt [n][d][s] ---------
__global__ __launch_bounds__(256) void vtrans_kernel(
    const unsigned short* __restrict__ qkv, unsigned short* __restrict__ vt)
{
  __shared__ unsigned short T[64][72];
  const int n = blockIdx.y, s0 = blockIdx.x * 64;
  const int b = n >> 4, hoff = (n & 15) * 64;
  const int tid = threadIdx.x;
  #pragma unroll
  for (int p = 0; p < 2; ++p) {
    const int r = (tid >> 3) + p * 32, c = (tid & 7) << 3;
    *(short8*)&T[r][c] = *(const short8*)(qkv + ((long)((s0 + r) * 4 + b)) * 3072 + 2048 + hoff + c);
  }
  __syncthreads();
  #pragma unroll
  for (int p = 0; p < 2; ++p) {
    const int d = (tid >> 3) + p * 32, sc = (tid & 7) << 3;
    short8 o;
    #pragma unroll
    for (int j = 0; j < 8; ++j) o[j] = (short)T[sc + j][d];
    *(short8*)(vt + ((long)n * 64 + d) * 1024 + s0 + sc) = o;
  }
}

// --- MFMA attention, counted-vmcnt K/V pipeline, fused residual+LN2 ------
// XCD-chunked swizzle: each XCD owns 8 consecutive heads (K/V L2-resident).
__global__ __launch_bounds__(256) void attn_kernel(
    const unsigned short* __restrict__ qkv, const unsigned short* __restrict__ vt,
    const float* __restrict__ q2g, const float* __restrict__ k2g,
    const unsigned short* __restrict__ xbf, const float* __restrict__ g2,
    const float* __restrict__ b2,
    unsigned short* __restrict__ ctx2, float* __restrict__ scores)
{
  int bx = blockIdx.x, by = blockIdx.y;
  xcd_swizzle(bx, by);
  const int n = by;
  const int s0 = bx * 64;
  const int b = n >> 4, hoff = (n & 15) * 64;
  __shared__ __align__(16) unsigned short Qs[64 * 64];
  __shared__ __align__(16) unsigned short Ks[2][64 * 64];
  __shared__ __align__(16) unsigned short VTl[2][64 * 64];
  __shared__ __align__(16) unsigned short Ps[64 * 64];
  __shared__ float k2s[1024];
  const int tid = threadIdx.x, w = tid >> 6, l = tid & 63;
  const int fr = l & 15, fg = l >> 4;
  const int lr8 = l >> 3, ls8 = l & 7;
  const int sslot = ((ls8 ^ lr8) << 3);
  const int rsw = fr & 7;

  #pragma unroll
  for (int p = 0; p < 2; ++p) {
    const int r = (tid >> 3) + p * 32, cs = tid & 7;
    *(short8*)&Qs[r * 64 + ((cs ^ (r & 7)) << 3)] =
        *(const short8*)(qkv + ((long)((s0 + r) * 4 + b)) * 3072 + hoff + (cs << 3));
  }
  *(float4*)&k2s[tid << 2] = *(const float4*)(k2g + n * 1024 + (tid << 2));
  float q2m[4];
  #pragma unroll
  for (int i = 0; i < 4; ++i) q2m[i] = -0.0625f * q2g[n * 1024 + s0 + i*16 + fr];
  #pragma unroll
  for (int p = 0; p < 2; ++p) {
    const int rowb = p * 32 + w * 8;
    gload16(qkv + ((long)((rowb + lr8) * 4 + b)) * 3072 + 1024 + hoff + sslot, &Ks[0][rowb * 64]);
    gload16(vt + ((long)n * 64 + rowb + lr8) * 1024 + sslot,                   &VTl[0][rowb * 64]);
  }
  __syncthreads();

  f32x4 o[4];
  #pragma unroll
  for (int i = 0; i < 4; ++i) o[i] = (f32x4)0.0f;

  int cur = 0;
  for (int t0 = 0; t0 < 1024; t0 += 64) {
    if (t0 > 0) {
      asm volatile("s_waitcnt vmcnt(4)" ::: "memory");
      __builtin_amdgcn_sched_barrier(0);
      __builtin_amdgcn_s_barrier();
    }
    f32x4 c4[4];
    #pragma unroll
    for (int i = 0; i < 4; ++i) c4[i] = (f32x4)0.0f;
    #pragma unroll
    for (int ks = 0; ks < 2; ++ks) {
      const short8 kf = *(const short8*)&Ks[cur][((w << 4) + fr) * 64 + ((((ks << 2) + fg) ^ rsw) << 3)];
      #pragma unroll
      for (int i = 0; i < 4; ++i) {
        const short8 qf = *(const short8*)&Qs[(i*16 + fr) * 64 + ((((ks << 2) + fg) ^ rsw) << 3)];
        c4[i] = __builtin_amdgcn_mfma_f32_16x16x32_bf16(kf, qf, c4[i], 0, 0, 0);
      }
    }
    if (t0 + 64 < 1024) {
      #pragma unroll
      for (int p = 0; p < 2; ++p) {
        const int rowb = p * 32 + w * 8;
        gload16(qkv + ((long)((t0 + 64 + rowb + lr8) * 4 + b)) * 3072 + 1024 + hoff + sslot,
                &Ks[cur ^ 1][rowb * 64]);
        gload16(vt + ((long)n * 64 + rowb + lr8) * 1024 + t0 + 64 + sslot,
                &VTl[cur ^ 1][rowb * 64]);
      }
    }
    const float4 k2v4 = *(const float4*)&k2s[t0 + (w << 4) + (fg << 2)];
    const float k2m[4] = {-0.0625f*k2v4.x, -0.0625f*k2v4.y, -0.0625f*k2v4.z, -0.0625f*k2v4.w};
    #pragma unroll
    for (int i = 0; i < 4; ++i) {
      f32x4 sc;
      float pe[4];
      #pragma unroll
      for (int r4 = 0; r4 < 4; ++r4) {
        const float m = fmaf(c4[i][r4], 0.125f, q2m[i] + k2m[r4]);
        sc[r4] = m;
        pe[r4] = __expf(m);
      }
      __builtin_nontemporal_store(sc,
          (f32x4*)(scores + (long)n * 1048576 + (long)(s0 + i*16 + fr) * 1024 + t0 + (w << 4) + (fg << 2)));
      const int slot = (w << 1) + (fg >> 1);
      const int pc = ((slot ^ (fr & 7)) << 3) + ((fg & 1) << 2);
      uint2 pk; pk.x = cvtpk(pe[0], pe[1]); pk.y = cvtpk(pe[2], pe[3]);
      *(uint2*)&Ps[(i*16 + fr) * 64 + pc] = pk;
    }
    asm volatile("s_waitcnt lgkmcnt(0)" ::: "memory");
    __builtin_amdgcn_sched_barrier(0);
    __builtin_amdgcn_s_barrier();
    #pragma unroll
    for (int ks = 0; ks < 2; ++ks) {
      const short8 vb = *(const short8*)&VTl[cur][((w << 4) + fr) * 64 + ((((ks << 2) + fg) ^ rsw) << 3)];
      #pragma unroll
      for (int i = 0; i < 4; ++i) {
        const short8 pf = *(const short8*)&Ps[(i*16 + fr) * 64 + ((((ks << 2) + fg) ^ rsw) << 3)];
        o[i] = __builtin_amdgcn_mfma_f32_16x16x32_bf16(vb, pf, o[i], 0, 0, 0);
      }
    }
    asm volatile("s_waitcnt lgkmcnt(0)" ::: "memory");
    __builtin_amdgcn_sched_barrier(0);
    __builtin_amdgcn_s_barrier();
    cur ^= 1;
  }

  // ---- fused residual (bf16 x) + per-head LN2 -> ctx2 bf16 ----
  const int dbase = (w << 4) + (fg << 2);
  float xf[4][4];
  #pragma unroll
  for (int i = 0; i < 4; ++i) {
    const ushort4 xu = *(const ushort4*)(xbf + ((long)((s0 + i*16 + fr) * 4 + b)) * 1024 + hoff + dbase);
    xf[i][0] = bf2f(xu.x); xf[i][1] = bf2f(xu.y);
    xf[i][2] = bf2f(xu.z); xf[i][3] = bf2f(xu.w);
  }

  float* redbuf = (float*)&Ps[0];
  const int slot = (w << 2) + fg;
  #pragma unroll
  for (int i = 0; i < 4; ++i) {
    float s = 0.f, ss = 0.f;
    #pragma unroll
    for (int r4 = 0; r4 < 4; ++r4) {
      const float v = o[i][r4] + xf[i][r4];
      s += v; ss = fmaf(v, v, ss);
    }
    redbuf[(i*16 + fr) * 16 + slot] = s;
    redbuf[1024 + (i*16 + fr) * 16 + slot] = ss;
  }
  __syncthreads();
  float* statbuf = (float*)&Qs[0];
  {
    const int row = tid >> 2, q4 = tid & 3;
    float s = 0.f, ss = 0.f;
    #pragma unroll
    for (int k = 0; k < 4; ++k) {
      s  += redbuf[row * 16 + q4 * 4 + k];
      ss += redbuf[1024 + row * 16 + q4 * 4 + k];
    }
    s  += __shfl_xor(s, 1);  s  += __shfl_xor(s, 2);
    ss += __shfl_xor(ss, 1); ss += __shfl_xor(ss, 2);
    if (q4 == 0) {
      const float mean = s * (1.0f/64.0f);
      const float var  = ss * (1.0f/64.0f) - mean * mean;
      statbuf[row] = mean;
      statbuf[64 + row] = rsqrtf(var + 1e-6f);
    }
  }
  __syncthreads();
  const float4 g2v = *(const float4*)(g2 + dbase);
  const float4 b2v = *(const float4*)(b2 + dbase);
  const float* gp = &g2v.x; const float* bp = &b2v.x;
  #pragma unroll
  for (int i = 0; i < 4; ++i) {
    const float mean = statbuf[i*16 + fr];
    const float rs   = statbuf[64 + i*16 + fr];
    float vo[4];
    #pragma unroll
    for (int r4 = 0; r4 < 4; ++r4)
      vo[r4] = (o[i][r4] + xf[i][r4] - mean) * rs * gp[r4] + bp[r4];
    uint2 pk; pk.x = cvtpk(vo[0], vo[1]); pk.y = cvtpk(vo[2], vo[3]);
    *(uint2*)(ctx2 + ((long)((s0 + i*16 + fr) * 4 + b)) * 1024 + hoff + dbase) = pk;
  }
}

extern "C" void kernel_launch(void* const* d_in, const int* in_sizes, int n_in,
                              void* d_out, int out_size, void* d_ws, size_t ws_size,
                              hipStream_t stream) {
  const float* hs   = (const float*)d_in[0];
  const float* g1   = (const float*)d_in[1];
  const float* b1   = (const float*)d_in[2];
  const float* g2   = (const float*)d_in[3];
  const float* b2   = (const float*)d_in[4];
  const float* Wq   = (const float*)d_in[5];
  const float* bq   = (const float*)d_in[6];
  const float* Wk   = (const float*)d_in[7];
  const float* bk   = (const float*)d_in[8];
  const float* Wv   = (const float*)d_in[9];
  const float* bv   = (const float*)d_in[10];
  const float* Win  = (const float*)d_in[11];
  const float* bin  = (const float*)d_in[12];
  const float* Wout = (const float*)d_in[13];
  const float* bout = (const float*)d_in[14];
  const float* Wd   = (const float*)d_in[15];
  const float* bd   = (const float*)d_in[16];

  // ws layout (bytes), verified DISJOINT live ranges (as round 16):
  //   qkv  [0,        25165824)   live: qkv-gemm .. attn end
  //   xbf  [25165824, 33554432)   live: prep .. attn end
  //   ctx2 [33554432, 41943040)   live: attn .. glu
  //   vt   [41943040, 50331648)   live: vtrans .. attn end
  //   weights/qkvb/q2g/k2g [50331648, 65548288)
  // Overlays (strictly after attn completes):
  //   h2 [0, 33554432) over qkv+xbf;  og [41943040, 50331648) over vt.
  char* ws = (char*)d_ws;
  unsigned short* qkv   = (unsigned short*)(ws + 0);
  unsigned short* xbf   = (unsigned short*)(ws + 25165824);
  unsigned short* ctx2  = (unsigned short*)(ws + 33554432);
  unsigned short* vt    = (unsigned short*)(ws + 41943040);
  unsigned short* wqkvT = (unsigned short*)(ws + 50331648);
  unsigned short* winT  = (unsigned short*)(ws + 56623104);
  unsigned short* woutT = (unsigned short*)(ws + 60817408);
  unsigned short* wdT   = (unsigned short*)(ws + 62914560);
  float*          qkvb  = (float*)(ws + 65011712);
  float*          q2g   = (float*)(ws + 65024000);
  float*          k2g   = (float*)(ws + 65286144);
  unsigned short* h2    = (unsigned short*)(ws + 0);
  unsigned short* og    = (unsigned short*)(ws + 41943040);

  float* out0 = (float*)d_out;           // [S,B,H]
  float* out1 = out0 + 4194304;          // [64,1024,1024]

  prep_all_kernel<<<11276, 256, 0, stream>>>(
      hs, g1, b1, xbf,
      Wq, Wk, Wv, Wd, Win, Wout, bq, bk, bv,
      wqkvT, wdT, winT, woutT, qkvb);

  // QKV: 256^2 8-wave counted-vmcnt pipeline (+ fused q2/k2)
  qkv256_kernel<<<dim3(12,16,1), 512, 0, stream>>>(
      xbf, wqkvT, qkvb, qkv, q2g, k2g);

  vtrans_kernel<<<dim3(16,64), 256, 0, stream>>>(qkv, vt);

  attn_kernel<<<dim3(16,64), 256, 0, stream>>>(qkv, vt, q2g, k2g, xbf, g2, b2, ctx2, out1);

  mfma_glu_kernel<<<dim3(16,32,4), 256, 0, stream>>>(ctx2, winT, bin, h2);

  // FFN-out: per group -> og bf16
  mfma_gemm64_kernel<<<dim3(4,32,4), 256, 0, stream>>>(
      h2, 4096, 1024, woutT, 262144, 1024, bout, 256, og, nullptr, 1024, 256);

  // dense: [4096,1024]@[1024,1024] -> out0 fp32 (NT store)
  mfma_gemm64_kernel<<<dim3(16,32,1), 256, 0, stream>>>(
      og, 1024, 0, wdT, 0, 1024, bd, 0, nullptr, out0, 1024, 0);
}